// Round 10
// baseline (263.733 us; speedup 1.0000x reference)
//
#include <hip/hip_runtime.h>
#include <hip/hip_fp16.h>
#include <math.h>

#define B_ 4
#define T_ 1024
#define D_ 512
#define H_ 8
#define HD_ 64
#define KN 30
#define ED_ 128
#define DFF_ 2048
#define M_ 4096   // B*T
#define BH_ 32

typedef _Float16 f16;
typedef __attribute__((ext_vector_type(8))) _Float16 f16x8;
typedef __attribute__((ext_vector_type(4))) _Float16 f16x4;
typedef __attribute__((ext_vector_type(4))) float f32x4;

#define MFMA16 __builtin_amdgcn_mfma_f32_16x16x32_f16
#define LOG2E 1.44269504088896f

__device__ __forceinline__ f16x8 ld8(const f16* p){ return *reinterpret_cast<const f16x8*>(p); }

__device__ __forceinline__ void gld16(const void* g, void* l){
  __builtin_amdgcn_global_load_lds((const __attribute__((address_space(1))) void*)g,
                                   (__attribute__((address_space(3))) void*)l, 16, 0, 0);
}

// ---------------- combined fp32 -> fp16 convert (9 tensors, 1 launch) -------
struct CvtJobs {
  const float* s[9];
  f16* d[9];
  int start[10];   // cumulative block starts; each block = 256 float4s
};

__global__ __launch_bounds__(256) void cvt9_kernel(CvtJobs J){
  const int blk = blockIdx.x;
  int j = 0;
  while (j < 8 && blk >= J.start[j+1]) ++j;
  const int i = (blk - J.start[j])*256 + threadIdx.x;
  float4 v = reinterpret_cast<const float4*>(J.s[j])[i];
  union { f16 h[4]; ushort4 u; } o;
  o.h[0]=(f16)v.x; o.h[1]=(f16)v.y; o.h[2]=(f16)v.z; o.h[3]=(f16)v.w;
  reinterpret_cast<ushort4*>(J.d[j])[i] = o.u;
}

// ---------------- bias prep: f16((bias + mask*-6e4) * rtemp * log2e) --------
__global__ __launch_bounds__(256) void biasprep_kernel(
    const float* __restrict__ bias, const int* __restrict__ mask,
    const float* __restrict__ tsc, f16* __restrict__ biasP)
{
  const int gid = blockIdx.x*256 + threadIdx.x;      // 524288 threads, 8 elems each
  const float s = exp2f(-2.0f*tanhf(tsc[0]))*LOG2E;  // log2e / 4^tanh(t)
  const int b = gid >> 17;                            // T*T/8 = 131072 per batch
  const int rem = gid & 131071;
  const int idx8 = rem*8;
  const int s0 = idx8 & 1023;
  const size_t gbase = (size_t)b*T_*T_ + idx8;
  float4 v0 = *reinterpret_cast<const float4*>(bias + gbase);
  float4 v1 = *reinterpret_cast<const float4*>(bias + gbase + 4);
  int4 m0 = *reinterpret_cast<const int4*>(mask + b*T_ + s0);
  int4 m1 = *reinterpret_cast<const int4*>(mask + b*T_ + s0 + 4);
  float x[8] = {v0.x,v0.y,v0.z,v0.w,v1.x,v1.y,v1.z,v1.w};
  int  mm[8] = {m0.x,m0.y,m0.z,m0.w,m1.x,m1.y,m1.z,m1.w};
  union { f16 h[8]; ushort4 u[2]; } o;
#pragma unroll
  for (int i = 0; i < 8; ++i){
    float t = (x[i] + (mm[i] ? 0.f : -60000.f))*s;
    o.h[i] = (f16)fmaxf(t, -60000.f);
  }
  reinterpret_cast<ushort4*>(biasP + gbase)[0] = o.u[0];
  reinterpret_cast<ushort4*>(biasP + gbase)[1] = o.u[1];
}

// =============== staged MFMA GEMM (m97 structure): C = X @ W.T ==============
// 128x128 tile. EPI 1: f16 gelu(acc+bias). EPI 2: f32 acc+bias.
template<int EPI>
__global__ __launch_bounds__(256,2) void gemm_tile(
    const f16* __restrict__ X, const f16* __restrict__ W,
    const float* __restrict__ bias, void* __restrict__ outp,
    int Kd, int ldo, int nbN)
{
  __shared__ f16 As[128*32];
  __shared__ f16 Bs[128*32];
  const int nwg = gridDim.x;
  const int bid = blockIdx.x;
  const int swz = (bid & 7)*(nwg >> 3) + (bid >> 3);
  const int mb = swz / nbN, nb = swz - mb*nbN;
  const int rb = mb*128, cb = nb*128;
  const int tid = threadIdx.x;
  const int w = tid >> 6, lane = tid & 63;
  const int l16 = lane & 15, l4 = lane >> 4;
  const int wr = w >> 1, wc = w & 1;
  const int sr = lane >> 2, sc = (lane & 3)*8;
  const f16* Ax0 = X + (size_t)(rb + w*16 + sr)*Kd + sc;
  const f16* Ax1 = X + (size_t)(rb + 64 + w*16 + sr)*Kd + sc;
  const f16* Bx0 = W + (size_t)(cb + w*16 + sr)*Kd + sc;
  const f16* Bx1 = W + (size_t)(cb + 64 + w*16 + sr)*Kd + sc;
  f16* Ad0 = &As[(w*16)*32];
  f16* Ad1 = &As[(64 + w*16)*32];
  f16* Bd0 = &Bs[(w*16)*32];
  f16* Bd1 = &Bs[(64 + w*16)*32];

  f32x4 acc[4][4];
#pragma unroll
  for (int m = 0; m < 4; ++m)
#pragma unroll
    for (int n = 0; n < 4; ++n) acc[m][n] = (f32x4){0.f,0.f,0.f,0.f};

  for (int k0 = 0; k0 < Kd; k0 += 32){
    gld16(Ax0 + k0, Ad0);
    gld16(Ax1 + k0, Ad1);
    gld16(Bx0 + k0, Bd0);
    gld16(Bx1 + k0, Bd1);
    __syncthreads();
    f16x8 a[4], b[4];
#pragma unroll
    for (int m = 0; m < 4; ++m) a[m] = ld8(&As[(wr*64 + m*16 + l16)*32 + l4*8]);
#pragma unroll
    for (int n = 0; n < 4; ++n) b[n] = ld8(&Bs[(wc*64 + n*16 + l16)*32 + l4*8]);
#pragma unroll
    for (int m = 0; m < 4; ++m)
#pragma unroll
      for (int n = 0; n < 4; ++n)
        acc[m][n] = MFMA16(a[m], b[n], acc[m][n], 0,0,0);
    __syncthreads();
  }

#pragma unroll
  for (int n = 0; n < 4; ++n){
    const int col = cb + wc*64 + n*16 + l16;
    const float bv = bias[col];
#pragma unroll
    for (int m = 0; m < 4; ++m){
#pragma unroll
      for (int j = 0; j < 4; ++j){
        const int row = rb + wr*64 + m*16 + l4*4 + j;
        float v = acc[m][n][j] + bv;
        if (EPI == 1){
          v = 0.5f*v*(1.0f + erff(v*0.70710678118654752f));
          ((f16*)outp)[(size_t)row*ldo + col] = (f16)v;
        } else {
          ((float*)outp)[(size_t)row*ldo + col] = v;
        }
      }
    }
  }
}

// =============== 128x64-tile GEMM (2x CU coverage for N=512 outputs) ========
template<int EPI>
__global__ __launch_bounds__(256,2) void gemm_n64(
    const f16* __restrict__ X, const f16* __restrict__ W,
    const float* __restrict__ bias, void* __restrict__ outp,
    int Kd, int ldo, int nbN)
{
  __shared__ f16 As[128*32];
  __shared__ f16 Bs[64*32];
  const int nwg = gridDim.x;
  const int bid = blockIdx.x;
  const int swz = (bid & 7)*(nwg >> 3) + (bid >> 3);
  const int mb = swz / nbN, nb = swz - mb*nbN;
  const int rb = mb*128, cb = nb*64;
  const int tid = threadIdx.x;
  const int w = tid >> 6, lane = tid & 63;
  const int l16 = lane & 15, l4 = lane >> 4;
  const int wr = w >> 1, wc = w & 1;
  const int sr = lane >> 2, sc = (lane & 3)*8;
  const f16* Ax0 = X + (size_t)(rb + w*16 + sr)*Kd + sc;
  const f16* Ax1 = X + (size_t)(rb + 64 + w*16 + sr)*Kd + sc;
  const f16* Bx0 = W + (size_t)(cb + w*16 + sr)*Kd + sc;
  f16* Ad0 = &As[(w*16)*32];
  f16* Ad1 = &As[(64 + w*16)*32];
  f16* Bd0 = &Bs[(w*16)*32];

  f32x4 acc[4][2];
#pragma unroll
  for (int m = 0; m < 4; ++m)
#pragma unroll
    for (int n = 0; n < 2; ++n) acc[m][n] = (f32x4){0.f,0.f,0.f,0.f};

  for (int k0 = 0; k0 < Kd; k0 += 32){
    gld16(Ax0 + k0, Ad0);
    gld16(Ax1 + k0, Ad1);
    gld16(Bx0 + k0, Bd0);
    __syncthreads();
    f16x8 a[4], b[2];
#pragma unroll
    for (int m = 0; m < 4; ++m) a[m] = ld8(&As[(wr*64 + m*16 + l16)*32 + l4*8]);
#pragma unroll
    for (int n = 0; n < 2; ++n) b[n] = ld8(&Bs[(wc*32 + n*16 + l16)*32 + l4*8]);
#pragma unroll
    for (int m = 0; m < 4; ++m)
#pragma unroll
      for (int n = 0; n < 2; ++n)
        acc[m][n] = MFMA16(a[m], b[n], acc[m][n], 0,0,0);
    __syncthreads();
  }

#pragma unroll
  for (int n = 0; n < 2; ++n){
    const int col = cb + wc*32 + n*16 + l16;
    const float bv = bias[col];
#pragma unroll
    for (int m = 0; m < 4; ++m){
#pragma unroll
      for (int j = 0; j < 4; ++j){
        const int row = rb + wr*64 + m*16 + l4*4 + j;
        float v = acc[m][n][j] + bv;
        if (EPI == 1){
          v = 0.5f*v*(1.0f + erff(v*0.70710678118654752f));
          ((f16*)outp)[(size_t)row*ldo + col] = (f16)v;
        } else {
          ((float*)outp)[(size_t)row*ldo + col] = v;
        }
      }
    }
  }
}

// =============== batched QKV projection (one launch, 3 GEMMs) ===============
__global__ __launch_bounds__(256,2) void qkv_tile(
    const f16* __restrict__ hV, const f16* __restrict__ kI, const f16* __restrict__ vI,
    const f16* __restrict__ Wq, const f16* __restrict__ Wk, const f16* __restrict__ Wv,
    const float* __restrict__ bq, const float* __restrict__ bk, const float* __restrict__ bv,
    const float* __restrict__ tsc,
    f16* __restrict__ qo, f16* __restrict__ ko, f16* __restrict__ vT)
{
  __shared__ f16 As[128*32];
  __shared__ f16 Bs[128*32];
  const int bid = blockIdx.x;
  const int swz = (bid & 7)*48 + (bid >> 3);
  const int g = swz >> 7;
  const int r = swz & 127;
  const int mb = r >> 2, nb = r & 3;
  const f16* X  = (g == 0) ? hV : ((g == 1) ? kI : vI);
  const f16* W  = (g == 0) ? Wq : ((g == 1) ? Wk : Wv);
  const float* bias = (g == 0) ? bq : ((g == 1) ? bk : bv);
  const int rb = mb*128, cb = nb*128;
  const int tid = threadIdx.x;
  const int w = tid >> 6, lane = tid & 63;
  const int l16 = lane & 15, l4 = lane >> 4;
  const int wr = w >> 1, wc = w & 1;
  const int sr = lane >> 2, sc = (lane & 3)*8;
  const f16* Ax0 = X + (size_t)(rb + w*16 + sr)*D_ + sc;
  const f16* Ax1 = X + (size_t)(rb + 64 + w*16 + sr)*D_ + sc;
  const f16* Bx0 = W + (size_t)(cb + w*16 + sr)*D_ + sc;
  const f16* Bx1 = W + (size_t)(cb + 64 + w*16 + sr)*D_ + sc;
  f16* Ad0 = &As[(w*16)*32];
  f16* Ad1 = &As[(64 + w*16)*32];
  f16* Bd0 = &Bs[(w*16)*32];
  f16* Bd1 = &Bs[(64 + w*16)*32];

  f32x4 acc[4][4];
#pragma unroll
  for (int m = 0; m < 4; ++m)
#pragma unroll
    for (int n = 0; n < 4; ++n) acc[m][n] = (f32x4){0.f,0.f,0.f,0.f};

  for (int k0 = 0; k0 < D_; k0 += 32){
    gld16(Ax0 + k0, Ad0);
    gld16(Ax1 + k0, Ad1);
    gld16(Bx0 + k0, Bd0);
    gld16(Bx1 + k0, Bd1);
    __syncthreads();
    f16x8 a[4], b[4];
#pragma unroll
    for (int m = 0; m < 4; ++m) a[m] = ld8(&As[(wr*64 + m*16 + l16)*32 + l4*8]);
#pragma unroll
    for (int n = 0; n < 4; ++n) b[n] = ld8(&Bs[(wc*64 + n*16 + l16)*32 + l4*8]);
#pragma unroll
    for (int m = 0; m < 4; ++m)
#pragma unroll
      for (int n = 0; n < 4; ++n)
        acc[m][n] = MFMA16(a[m], b[n], acc[m][n], 0,0,0);
    __syncthreads();
  }

  const float qs = exp2f(-2.0f*tanhf(tsc[0]))*LOG2E*0.125f;
  const float scale = (g == 0) ? qs : 1.0f;
  f16* out = (g == 0) ? qo : ko;
#pragma unroll
  for (int n = 0; n < 4; ++n){
    const int col = cb + wc*64 + n*16 + l16;
    const float bv = bias[col];
#pragma unroll
    for (int m = 0; m < 4; ++m){
#pragma unroll
      for (int j = 0; j < 4; ++j){
        const int row = rb + wr*64 + m*16 + l4*4 + j;
        const float v = (acc[m][n][j] + bv)*scale;
        if (g < 2){
          out[(size_t)row*D_ + col] = (f16)v;
        } else {
          const int b = row >> 10, t = row & (T_-1);
          const int h = col >> 6,  dl = col & (HD_-1);
          vT[(((size_t)b*H_ + h)*HD_ + dl)*T_ + t] = (f16)v;
        }
      }
    }
  }
}

// =============== fused attention (QBLK=32, chunked, no atomics) =============
// block = 32 q-rows x one (b,h); 4 waves, each handling 2 q-column-groups.
// s in 8 chunks of 128: QK stages K(16KB)+bias(8KB) -> 8 MFMA/wave;
// softmax in-register per qg; PV stages V(16KB), P written from regs (8KB),
// 8 MFMA/wave per chunk. Edge gather -> plain per-head store (no atomics).
// LDS buffers XOR-swizzled (16B chunk ^= row&7, pre-swizzled global source).
__global__ __launch_bounds__(256,4) void attn_fused(
    const f16* __restrict__ q, const f16* __restrict__ k, const f16* __restrict__ vT,
    const f16* __restrict__ biasP, const int* __restrict__ eidx,
    f16* __restrict__ X2, float* __restrict__ gpart)
{
  __shared__ f16 Sb[8192];        // 16 KB: K chunk [128 s][64 d] / V chunk [64 d][128 s]
  __shared__ f16 Pc[32*128];      // 8 KB: bias chunk / P chunk [32 q][128 s]
  __shared__ float red[2][2][4][16];  // [max/sum][qg][wave][qcol]
  const int bid = blockIdx.x;
  const int swz = (bid & 7)*128 + (bid >> 3);   // XCD gets 4 contiguous bh
  const int bh = swz >> 5, tb = swz & 31;
  const int bi = bh >> 3, h = bh & 7;
  const int t0 = tb*32;
  const int tid = threadIdx.x, w = tid >> 6, lane = tid & 63;
  const int l16 = lane & 15, l4 = lane >> 4;
  const int key = l16 & 7;        // XOR-swizzle key for frag reads

  // ---- Q fragments (2 column groups) + gather tuples ----
  f16x8 q0[2], q1[2];
#pragma unroll
  for (int qg = 0; qg < 2; ++qg){
    const f16* qp = q + (size_t)(bi*T_ + t0 + qg*16 + l16)*D_ + h*HD_ + l4*8;
    q0[qg] = ld8(qp); q1[qg] = ld8(qp + 32);
  }
  int g_id[4], g_rk[4];
#pragma unroll
  for (int i = 0; i < 4; ++i){
    const int jj = tid + i*256;
    if (jj < 32*KN){
      const int r = jj/KN, kk = jj - r*KN;
      g_id[i] = eidx[((size_t)(bi*T_ + t0 + r))*KN + kk];
      g_rk[i] = (r << 5) | kk;
    } else { g_id[i] = -1; g_rk[i] = 0; }
  }

  const f16* kg = k + (size_t)(bi*T_)*D_ + h*HD_;
  const f16* bg = biasP + ((size_t)(bi*T_ + t0))*T_;
  const f16* vg = vT + (size_t)bh*HD_*T_;

  // ---- QK^T: 8 chunks of 128 s ----
  f32x4 acc[2][16];
#pragma unroll
  for (int c = 0; c < 8; ++c){
    if (c) __syncthreads();                       // prev chunk's LDS reads done
    // stage K chunk: 1024x16B; rows 128B = 8 chunks, src col pre-swizzled
#pragma unroll
    for (int i = 0; i < 4; ++i){
      const int cidx = i*256 + w*64 + lane;
      const int r = cidx >> 3, p = cidx & 7;
      gld16(kg + (size_t)(c*128 + r)*D_ + ((p ^ (r & 7)) << 3),
            &Sb[(i*256 + w*64)*8]);
    }
    // stage bias chunk: 32 rows x 256B = 512x16B chunks
#pragma unroll
    for (int i = 0; i < 2; ++i){
      const int cidx = i*256 + w*64 + lane;
      const int r = cidx >> 4, p = cidx & 15;
      gld16(bg + (size_t)r*T_ + c*128 + ((p ^ (r & 7)) << 3),
            &Pc[(i*256 + w*64)*8]);
    }
    __syncthreads();                              // stage visible
#pragma unroll
    for (int step = 0; step < 2; ++step){
      const int r = w*32 + step*16 + l16;         // local s row (r&7 == key)
      const f16x8 kf0 = ld8(&Sb[r*64 + ((l4 ^ key) << 3)]);
      const f16x8 kf1 = ld8(&Sb[r*64 + (((4 + l4) ^ key) << 3)]);
      const int slb = w*32 + step*16 + l4*4;
#pragma unroll
      for (int qg = 0; qg < 2; ++qg){
        f32x4 a = {0.f,0.f,0.f,0.f};
        a = MFMA16(kf0, q0[qg], a, 0,0,0);
        a = MFMA16(kf1, q1[qg], a, 0,0,0);
        const f16x4 bf = *reinterpret_cast<const f16x4*>(
            &Pc[(qg*16 + l16)*128 + (((slb >> 3) ^ key) << 3) + (slb & 7)]);
#pragma unroll
        for (int j = 0; j < 4; ++j) a[j] += (float)bf[j];
        acc[qg][c*2 + step] = a;
      }
    }
  }

  // ---- softmax: per qg, in-lane 64 values + shfl + cross-wave ----
#pragma unroll
  for (int qg = 0; qg < 2; ++qg){
    float m = -3.4e38f;
#pragma unroll
    for (int c = 0; c < 16; ++c)
#pragma unroll
      for (int j = 0; j < 4; ++j) m = fmaxf(m, acc[qg][c][j]);
    m = fmaxf(m, __shfl_xor(m, 16));
    m = fmaxf(m, __shfl_xor(m, 32));
    if (lane < 16) red[0][qg][w][lane] = m;
  }
  __syncthreads();
#pragma unroll
  for (int qg = 0; qg < 2; ++qg){
    const float m = fmaxf(fmaxf(red[0][qg][0][l16], red[0][qg][1][l16]),
                          fmaxf(red[0][qg][2][l16], red[0][qg][3][l16]));
    float l = 0.f;
#pragma unroll
    for (int c = 0; c < 16; ++c)
#pragma unroll
      for (int j = 0; j < 4; ++j){
        const float e = exp2f(acc[qg][c][j] - m);
        l += e;
        acc[qg][c][j] = e;                        // acc now holds unnormalized P
      }
    l += __shfl_xor(l, 16);
    l += __shfl_xor(l, 32);
    if (lane < 16) red[1][qg][w][lane] = l;
  }

  // ---- PV: 8 chunks of 128 s; P regs -> Pc, V staged -> Sb ----
  f32x4 oo[2][4];
#pragma unroll
  for (int qg = 0; qg < 2; ++qg)
#pragma unroll
    for (int grp = 0; grp < 4; ++grp) oo[qg][grp] = (f32x4){0.f,0.f,0.f,0.f};
#pragma unroll
  for (int sc = 0; sc < 8; ++sc){
    __syncthreads();                              // prev reads done (+red[1] for sc=0)
    // write this wave's P slice (s-local [w*32,+32)) for both q-groups
#pragma unroll
    for (int step = 0; step < 2; ++step){
      const int slb = w*32 + step*16 + l4*4;
#pragma unroll
      for (int qg = 0; qg < 2; ++qg){
        f16x4 pp;
#pragma unroll
        for (int j = 0; j < 4; ++j) pp[j] = (f16)acc[qg][sc*2 + step][j];
        *reinterpret_cast<f16x4*>(
            &Pc[(qg*16 + l16)*128 + (((slb >> 3) ^ key) << 3) + (slb & 7)]) = pp;
      }
    }
    // stage V chunk: 1024x16B; rows 256B = 16 chunks
#pragma unroll
    for (int i = 0; i < 4; ++i){
      const int cidx = i*256 + w*64 + lane;
      const int r = cidx >> 4, p = cidx & 15;
      gld16(vg + (size_t)r*T_ + sc*128 + ((p ^ (r & 7)) << 3),
            &Sb[(i*256 + w*64)*8]);
    }
    __syncthreads();                              // P + V visible
    const int vrow = (w*16 + l16)*128;
#pragma unroll
    for (int grp = 0; grp < 4; ++grp){
      const int ch = (grp*4 + l4) ^ key;
      const f16x8 vb = ld8(&Sb[vrow + (ch << 3)]);
#pragma unroll
      for (int qg = 0; qg < 2; ++qg){
        const f16x8 pa = ld8(&Pc[(qg*16 + l16)*128 + (ch << 3)]);
        oo[qg][grp] = MFMA16(pa, vb, oo[qg][grp], 0,0,0);
      }
    }
    // edge gather for ids in this s-chunk: plain per-head store, no atomics
#pragma unroll
    for (int i = 0; i < 4; ++i){
      if (g_id[i] >= 0 && (g_id[i] >> 7) == sc){
        const int r = g_rk[i] >> 5, kk = g_rk[i] & 31;
        const float lr = red[1][r >> 4][0][r & 15] + red[1][r >> 4][1][r & 15]
                       + red[1][r >> 4][2][r & 15] + red[1][r >> 4][3][r & 15];
        const int sl = g_id[i] & 127;
        const float pv = (float)Pc[r*128 + ((((sl >> 3) ^ (r & 7)) << 3) | (sl & 7))];
        gpart[((size_t)bh*T_ + t0 + r)*KN + kk] = pv/lr*0.125f;
      }
    }
  }

#pragma unroll
  for (int qg = 0; qg < 2; ++qg){
    const f32x4 o = (oo[qg][0] + oo[qg][1]) + (oo[qg][2] + oo[qg][3]);
#pragma unroll
    for (int j = 0; j < 4; ++j){
      const int qcol = l4*4 + j;
      const float lr = red[1][qg][0][qcol] + red[1][qg][1][qcol]
                     + red[1][qg][2][qcol] + red[1][qg][3][qcol];
      const int t = t0 + qg*16 + qcol;
      X2[((size_t)(bi*T_ + t))*640 + h*HD_ + w*16 + l16] = (f16)(o[j]/lr);
    }
  }
}

// ---------------- edge: weighted neighbor-embedding mean -------------------
// g[b,t,kk] = sum_h gpart[(b*H+h), t, kk]
__global__ __launch_bounds__(128) void edge_kernel(
    const float* __restrict__ gpart, const float* __restrict__ E, f16* __restrict__ X2)
{
  __shared__ float gl[KN];
  __shared__ float ginv;
  const int bt = blockIdx.x;          // b*T + t
  const int bi = bt >> 10, tt = bt & 1023;
  const int t = threadIdx.x;
  if (t < KN){
    float s = 0.f;
#pragma unroll
    for (int hh = 0; hh < H_; ++hh)
      s += gpart[((size_t)(bi*H_ + hh)*T_ + tt)*KN + t];
    gl[t] = s;
  }
  __syncthreads();
  if (t == 0){
    float s = 0.f;
#pragma unroll
    for (int i = 0; i < KN; ++i) s += gl[i];
    ginv = 1.0f/(s + 1e-6f);
  }
  __syncthreads();
  float acc = 0.f;
  const float* Ep = E + (size_t)bt*KN*ED_ + t;
#pragma unroll 5
  for (int kk = 0; kk < KN; ++kk) acc += gl[kk]*Ep[(size_t)kk*ED_];
  X2[(size_t)bt*640 + 512 + t] = (f16)(acc*ginv);
}

// ---------------- LayerNorm helpers ----------------------------------------
__device__ __forceinline__ float block_sum(float v, float* sbuf){
  for (int o = 32; o; o >>= 1) v += __shfl_down(v, o);
  __syncthreads();
  if ((threadIdx.x & 63) == 0) sbuf[threadIdx.x >> 6] = v;
  __syncthreads();
  return sbuf[0]+sbuf[1]+sbuf[2]+sbuf[3];
}

__global__ __launch_bounds__(256) void ln1_kernel(
    const float* __restrict__ hV, const float* __restrict__ hraw,
    const float* __restrict__ gn, const float* __restrict__ bn,
    float* __restrict__ hf, f16* __restrict__ hh)
{
  __shared__ float sbuf[4];
  const int r = blockIdx.x, t = threadIdx.x;
  const size_t base = (size_t)r*D_;
  float x0 = hV[base+t]     + hraw[base+t];
  float x1 = hV[base+t+256] + hraw[base+t+256];
  float s = block_sum(x0+x1, sbuf);
  const float mean = s*(1.f/512.f);
  float d0 = x0-mean, d1 = x1-mean;
  float vs = block_sum(d0*d0+d1*d1, sbuf);
  const float rstd = rsqrtf(vs*(1.f/512.f) + 1e-5f);
  float y0 = d0*rstd*gn[t]     + bn[t];
  float y1 = d1*rstd*gn[t+256] + bn[t+256];
  hf[base+t]     = y0;  hh[base+t]     = (f16)y0;
  hf[base+t+256] = y1;  hh[base+t+256] = (f16)y1;
}

__global__ __launch_bounds__(256) void final_kernel(
    const float* __restrict__ hf, const float* __restrict__ ffr,
    const float* __restrict__ gf, const float* __restrict__ bfv,
    const float* __restrict__ g2, const float* __restrict__ b2,
    float* __restrict__ out)
{
  __shared__ float sbuf[4];
  const int r = blockIdx.x, t = threadIdx.x;
  const size_t base = (size_t)r*D_;
  const float h0 = hf[base+t], h1 = hf[base+t+256];
  float x0 = h0 + ffr[base+t], x1 = h1 + ffr[base+t+256];
  float s = block_sum(x0+x1, sbuf);
  float mean = s*(1.f/512.f);
  float d0 = x0-mean, d1 = x1-mean;
  float vs = block_sum(d0*d0+d1*d1, sbuf);
  float rstd = rsqrtf(vs*(1.f/512.f) + 1e-6f);
  const float dh0 = d0*rstd*gf[t]     + bfv[t];
  const float dh1 = d1*rstd*gf[t+256] + bfv[t+256];
  const float y0 = h0 + dh0, y1 = h1 + dh1;
  s = block_sum(y0+y1, sbuf);
  mean = s*(1.f/512.f);
  d0 = y0-mean; d1 = y1-mean;
  vs = block_sum(d0*d0+d1*d1, sbuf);
  rstd = rsqrtf(vs*(1.f/512.f) + 1e-5f);
  out[base+t]     = d0*rstd*g2[t]     + b2[t];
  out[base+t+256] = d1*rstd*g2[t+256] + b2[t+256];
}

// ---------------------------------------------------------------------------
extern "C" void kernel_launch(void* const* d_in, const int* in_sizes, int n_in,
                              void* d_out, int out_size, void* d_ws, size_t ws_size,
                              hipStream_t stream)
{
  (void)in_sizes; (void)n_in; (void)out_size;
  const float* h_V  = (const float*)d_in[0];
  const float* kin  = (const float*)d_in[1];
  const float* vin  = (const float*)d_in[2];
  const float* E    = (const float*)d_in[3];
  const float* bias = (const float*)d_in[4];
  const float* Wq   = (const float*)d_in[5];
  const float* bq   = (const float*)d_in[6];
  const float* Wk   = (const float*)d_in[7];
  const float* bk   = (const float*)d_in[8];
  const float* Wv   = (const float*)d_in[9];
  const float* bv   = (const float*)d_in[10];
  const float* Wo   = (const float*)d_in[11];
  const float* bo   = (const float*)d_in[12];
  const float* tsc  = (const float*)d_in[13];
  const float* gn   = (const float*)d_in[14];
  const float* bn   = (const float*)d_in[15];
  const float* w1   = (const float*)d_in[16];
  const float* bw1  = (const float*)d_in[17];
  const float* w2   = (const float*)d_in[18];
  const float* bw2  = (const float*)d_in[19];
  const float* gf   = (const float*)d_in[20];
  const float* bfv  = (const float*)d_in[21];
  const float* g2   = (const float*)d_in[22];
  const float* b2   = (const float*)d_in[23];
  const int*   Eidx = (const int*)d_in[24];
  const int*   mask = (const int*)d_in[25];
  float* out = (float*)d_out;

  char* wsb = (char*)d_ws;
  size_t off = 0;
  auto alloc = [&](size_t bytes) -> void* {
    void* pp = wsb + off; off += (bytes + 255) & ~(size_t)255; return pp;
  };
  f16* hVb  = (f16*)alloc((size_t)M_*D_*2);
  f16* kbI  = (f16*)alloc((size_t)M_*D_*2);
  f16* vbI  = (f16*)alloc((size_t)M_*D_*2);
  f16* Wqb  = (f16*)alloc((size_t)D_*D_*2);
  f16* Wkb  = (f16*)alloc((size_t)D_*D_*2);
  f16* Wvb  = (f16*)alloc((size_t)D_*D_*2);
  f16* Wob  = (f16*)alloc((size_t)D_*(D_+ED_)*2);
  f16* w1b  = (f16*)alloc((size_t)DFF_*D_*2);
  f16* w2b  = (f16*)alloc((size_t)D_*DFF_*2);
  f16* qb   = (f16*)alloc((size_t)M_*D_*2);
  f16* kb   = (f16*)alloc((size_t)M_*D_*2);
  f16* vT   = (f16*)alloc((size_t)M_*D_*2);
  f16* biasP= (f16*)alloc((size_t)B_*T_*T_*2);
  f16* X2   = (f16*)alloc((size_t)M_*640*2);
  float* gpart = (float*)alloc((size_t)BH_*T_*KN*4);
  float* hraw = (float*)alloc((size_t)M_*D_*4);   // reused as ffraw
  float* hf   = (float*)alloc((size_t)M_*D_*4);
  f16*   hh   = (f16*)alloc((size_t)M_*D_*2);
  f16*   ff1  = (f16*)alloc((size_t)M_*DFF_*2);
  if (ws_size < off) return;  // scratch insufficient -> loud validation failure
  float* ffraw = hraw;

  // 1) converts fp32 -> f16 (one launch) + bias prep
  {
    CvtJobs J;
    const float* srcs[9] = {h_V, kin, vin, Wq, Wk, Wv, Wo, w1, w2};
    f16* dsts[9] = {hVb, kbI, vbI, Wqb, Wkb, Wvb, Wob, w1b, w2b};
    const int n4s[9] = {M_*D_/4, M_*D_/4, M_*D_/4, D_*D_/4, D_*D_/4, D_*D_/4,
                        D_*(D_+ED_)/4, DFF_*D_/4, D_*DFF_/4};
    int cum = 0;
    for (int i = 0; i < 9; ++i){
      J.s[i] = srcs[i]; J.d[i] = dsts[i]; J.start[i] = cum;
      cum += n4s[i]/256;
    }
    J.start[9] = cum;
    cvt9_kernel<<<cum,256,0,stream>>>(J);
  }
  biasprep_kernel<<<B_*T_*T_/8/256,256,0,stream>>>(bias, mask, tsc, biasP);

  // 2) batched q/k/v projections (q pre-scaled for exp2 softmax; v -> vT)
  qkv_tile<<<384,256,0,stream>>>(hVb, kbI, vbI, Wqb, Wkb, Wvb, bq, bk, bv, tsc, qb, kb, vT);

  // 3) fused attention (QK^T + softmax + PV + edge gather), QBLK=32
  attn_fused<<<1024,256,0,stream>>>(qb, kb, vT, biasP, Eidx, X2, gpart);

  // 4) edge embedding (sums 8 per-head partials)
  edge_kernel<<<M_,128,0,stream>>>(gpart, E, X2);

  // 5) out-proj (128x64 tiles, 256 blocks) + residual LN
  gemm_n64<2><<<256,256,0,stream>>>(X2, Wob, bo, hraw, D_+ED_, D_, 8);
  ln1_kernel<<<M_,256,0,stream>>>(h_V, hraw, gn, bn, hf, hh);

  // 6) FFN: FF1 128x128 (512 blocks), FF2 128x64 (256 blocks)
  gemm_tile<1><<<512,256,0,stream>>>(hh, w1b, bw1, ff1, D_, DFF_, 16);
  gemm_n64<2><<<256,256,0,stream>>>(ff1, w2b, bw2, ffraw, DFF_, D_, 8);

  // 7) final double-LN
  final_kernel<<<M_,256,0,stream>>>(hf, ffraw, gf, bfv, g2, b2, out);
}

// Round 11
// 185.747 us; speedup vs baseline: 1.4199x; 1.4199x over previous
//
#include <hip/hip_runtime.h>
#include <hip/hip_fp16.h>
#include <math.h>

#define B_ 4
#define T_ 1024
#define D_ 512
#define H_ 8
#define HD_ 64
#define KN 30
#define ED_ 128
#define DFF_ 2048
#define M_ 4096   // B*T
#define BH_ 32

typedef _Float16 f16;
typedef __attribute__((ext_vector_type(8))) _Float16 f16x8;
typedef __attribute__((ext_vector_type(4))) _Float16 f16x4;
typedef __attribute__((ext_vector_type(4))) float f32x4;

#define MFMA16 __builtin_amdgcn_mfma_f32_16x16x32_f16
#define LOG2E 1.44269504088896f

__device__ __forceinline__ f16x8 ld8(const f16* p){ return *reinterpret_cast<const f16x8*>(p); }

__device__ __forceinline__ void gld16(const void* g, void* l){
  __builtin_amdgcn_global_load_lds((const __attribute__((address_space(1))) void*)g,
                                   (__attribute__((address_space(3))) void*)l, 16, 0, 0);
}

// ---------------- combined fp32 -> fp16 convert (9 tensors, 1 launch) -------
struct CvtJobs {
  const float* s[9];
  f16* d[9];
  int start[10];   // cumulative block starts; each block = 256 float4s
};

__global__ __launch_bounds__(256) void cvt9_kernel(CvtJobs J){
  const int blk = blockIdx.x;
  int j = 0;
  while (j < 8 && blk >= J.start[j+1]) ++j;
  const int i = (blk - J.start[j])*256 + threadIdx.x;
  float4 v = reinterpret_cast<const float4*>(J.s[j])[i];
  union { f16 h[4]; ushort4 u; } o;
  o.h[0]=(f16)v.x; o.h[1]=(f16)v.y; o.h[2]=(f16)v.z; o.h[3]=(f16)v.w;
  reinterpret_cast<ushort4*>(J.d[j])[i] = o.u;
}

// ---------------- bias prep: f16((bias + mask*-6e4) * rtemp * log2e) --------
__global__ __launch_bounds__(256) void biasprep_kernel(
    const float* __restrict__ bias, const int* __restrict__ mask,
    const float* __restrict__ tsc, f16* __restrict__ biasP)
{
  const int gid = blockIdx.x*256 + threadIdx.x;      // 524288 threads, 8 elems each
  const float s = exp2f(-2.0f*tanhf(tsc[0]))*LOG2E;  // log2e / 4^tanh(t)
  const int b = gid >> 17;                            // T*T/8 = 131072 per batch
  const int rem = gid & 131071;
  const int idx8 = rem*8;
  const int s0 = idx8 & 1023;
  const size_t gbase = (size_t)b*T_*T_ + idx8;
  float4 v0 = *reinterpret_cast<const float4*>(bias + gbase);
  float4 v1 = *reinterpret_cast<const float4*>(bias + gbase + 4);
  int4 m0 = *reinterpret_cast<const int4*>(mask + b*T_ + s0);
  int4 m1 = *reinterpret_cast<const int4*>(mask + b*T_ + s0 + 4);
  float x[8] = {v0.x,v0.y,v0.z,v0.w,v1.x,v1.y,v1.z,v1.w};
  int  mm[8] = {m0.x,m0.y,m0.z,m0.w,m1.x,m1.y,m1.z,m1.w};
  union { f16 h[8]; ushort4 u[2]; } o;
#pragma unroll
  for (int i = 0; i < 8; ++i){
    float t = (x[i] + (mm[i] ? 0.f : -60000.f))*s;
    o.h[i] = (f16)fmaxf(t, -60000.f);
  }
  reinterpret_cast<ushort4*>(biasP + gbase)[0] = o.u[0];
  reinterpret_cast<ushort4*>(biasP + gbase)[1] = o.u[1];
}

// =============== staged MFMA GEMM (m97 structure): C = X @ W.T ==============
// 128x128 tile. EPI 1: f16 gelu(acc+bias). EPI 2: f32 acc+bias.
template<int EPI>
__global__ __launch_bounds__(256,2) void gemm_tile(
    const f16* __restrict__ X, const f16* __restrict__ W,
    const float* __restrict__ bias, void* __restrict__ outp,
    int Kd, int ldo, int nbN)
{
  __shared__ f16 As[128*32];
  __shared__ f16 Bs[128*32];
  const int nwg = gridDim.x;
  const int bid = blockIdx.x;
  const int swz = (bid & 7)*(nwg >> 3) + (bid >> 3);
  const int mb = swz / nbN, nb = swz - mb*nbN;
  const int rb = mb*128, cb = nb*128;
  const int tid = threadIdx.x;
  const int w = tid >> 6, lane = tid & 63;
  const int l16 = lane & 15, l4 = lane >> 4;
  const int wr = w >> 1, wc = w & 1;
  const int sr = lane >> 2, sc = (lane & 3)*8;
  const f16* Ax0 = X + (size_t)(rb + w*16 + sr)*Kd + sc;
  const f16* Ax1 = X + (size_t)(rb + 64 + w*16 + sr)*Kd + sc;
  const f16* Bx0 = W + (size_t)(cb + w*16 + sr)*Kd + sc;
  const f16* Bx1 = W + (size_t)(cb + 64 + w*16 + sr)*Kd + sc;
  f16* Ad0 = &As[(w*16)*32];
  f16* Ad1 = &As[(64 + w*16)*32];
  f16* Bd0 = &Bs[(w*16)*32];
  f16* Bd1 = &Bs[(64 + w*16)*32];

  f32x4 acc[4][4];
#pragma unroll
  for (int m = 0; m < 4; ++m)
#pragma unroll
    for (int n = 0; n < 4; ++n) acc[m][n] = (f32x4){0.f,0.f,0.f,0.f};

  for (int k0 = 0; k0 < Kd; k0 += 32){
    gld16(Ax0 + k0, Ad0);
    gld16(Ax1 + k0, Ad1);
    gld16(Bx0 + k0, Bd0);
    gld16(Bx1 + k0, Bd1);
    __syncthreads();
    f16x8 a[4], b[4];
#pragma unroll
    for (int m = 0; m < 4; ++m) a[m] = ld8(&As[(wr*64 + m*16 + l16)*32 + l4*8]);
#pragma unroll
    for (int n = 0; n < 4; ++n) b[n] = ld8(&Bs[(wc*64 + n*16 + l16)*32 + l4*8]);
#pragma unroll
    for (int m = 0; m < 4; ++m)
#pragma unroll
      for (int n = 0; n < 4; ++n)
        acc[m][n] = MFMA16(a[m], b[n], acc[m][n], 0,0,0);
    __syncthreads();
  }

#pragma unroll
  for (int n = 0; n < 4; ++n){
    const int col = cb + wc*64 + n*16 + l16;
    const float bv = bias[col];
#pragma unroll
    for (int m = 0; m < 4; ++m){
#pragma unroll
      for (int j = 0; j < 4; ++j){
        const int row = rb + wr*64 + m*16 + l4*4 + j;
        float v = acc[m][n][j] + bv;
        if (EPI == 1){
          v = 0.5f*v*(1.0f + erff(v*0.70710678118654752f));
          ((f16*)outp)[(size_t)row*ldo + col] = (f16)v;
        } else {
          ((float*)outp)[(size_t)row*ldo + col] = v;
        }
      }
    }
  }
}

// =============== 128x64-tile GEMM (2x CU coverage for N=512 outputs) ========
template<int EPI>
__global__ __launch_bounds__(256,2) void gemm_n64(
    const f16* __restrict__ X, const f16* __restrict__ W,
    const float* __restrict__ bias, void* __restrict__ outp,
    int Kd, int ldo, int nbN)
{
  __shared__ f16 As[128*32];
  __shared__ f16 Bs[64*32];
  const int nwg = gridDim.x;
  const int bid = blockIdx.x;
  const int swz = (bid & 7)*(nwg >> 3) + (bid >> 3);
  const int mb = swz / nbN, nb = swz - mb*nbN;
  const int rb = mb*128, cb = nb*64;
  const int tid = threadIdx.x;
  const int w = tid >> 6, lane = tid & 63;
  const int l16 = lane & 15, l4 = lane >> 4;
  const int wr = w >> 1, wc = w & 1;
  const int sr = lane >> 2, sc = (lane & 3)*8;
  const f16* Ax0 = X + (size_t)(rb + w*16 + sr)*Kd + sc;
  const f16* Ax1 = X + (size_t)(rb + 64 + w*16 + sr)*Kd + sc;
  const f16* Bx0 = W + (size_t)(cb + w*16 + sr)*Kd + sc;
  f16* Ad0 = &As[(w*16)*32];
  f16* Ad1 = &As[(64 + w*16)*32];
  f16* Bd0 = &Bs[(w*16)*32];

  f32x4 acc[4][2];
#pragma unroll
  for (int m = 0; m < 4; ++m)
#pragma unroll
    for (int n = 0; n < 2; ++n) acc[m][n] = (f32x4){0.f,0.f,0.f,0.f};

  for (int k0 = 0; k0 < Kd; k0 += 32){
    gld16(Ax0 + k0, Ad0);
    gld16(Ax1 + k0, Ad1);
    gld16(Bx0 + k0, Bd0);
    __syncthreads();
    f16x8 a[4], b[2];
#pragma unroll
    for (int m = 0; m < 4; ++m) a[m] = ld8(&As[(wr*64 + m*16 + l16)*32 + l4*8]);
#pragma unroll
    for (int n = 0; n < 2; ++n) b[n] = ld8(&Bs[(wc*32 + n*16 + l16)*32 + l4*8]);
#pragma unroll
    for (int m = 0; m < 4; ++m)
#pragma unroll
      for (int n = 0; n < 2; ++n)
        acc[m][n] = MFMA16(a[m], b[n], acc[m][n], 0,0,0);
    __syncthreads();
  }

#pragma unroll
  for (int n = 0; n < 2; ++n){
    const int col = cb + wc*32 + n*16 + l16;
    const float bv = bias[col];
#pragma unroll
    for (int m = 0; m < 4; ++m){
#pragma unroll
      for (int j = 0; j < 4; ++j){
        const int row = rb + wr*64 + m*16 + l4*4 + j;
        float v = acc[m][n][j] + bv;
        if (EPI == 1){
          v = 0.5f*v*(1.0f + erff(v*0.70710678118654752f));
          ((f16*)outp)[(size_t)row*ldo + col] = (f16)v;
        } else {
          ((float*)outp)[(size_t)row*ldo + col] = v;
        }
      }
    }
  }
}

// =============== batched QKV projection (one launch, 3 GEMMs) ===============
__global__ __launch_bounds__(256,2) void qkv_tile(
    const f16* __restrict__ hV, const f16* __restrict__ kI, const f16* __restrict__ vI,
    const f16* __restrict__ Wq, const f16* __restrict__ Wk, const f16* __restrict__ Wv,
    const float* __restrict__ bq, const float* __restrict__ bk, const float* __restrict__ bv,
    const float* __restrict__ tsc,
    f16* __restrict__ qo, f16* __restrict__ ko, f16* __restrict__ vT)
{
  __shared__ f16 As[128*32];
  __shared__ f16 Bs[128*32];
  const int bid = blockIdx.x;
  const int swz = (bid & 7)*48 + (bid >> 3);
  const int g = swz >> 7;
  const int r = swz & 127;
  const int mb = r >> 2, nb = r & 3;
  const f16* X  = (g == 0) ? hV : ((g == 1) ? kI : vI);
  const f16* W  = (g == 0) ? Wq : ((g == 1) ? Wk : Wv);
  const float* bias = (g == 0) ? bq : ((g == 1) ? bk : bv);
  const int rb = mb*128, cb = nb*128;
  const int tid = threadIdx.x;
  const int w = tid >> 6, lane = tid & 63;
  const int l16 = lane & 15, l4 = lane >> 4;
  const int wr = w >> 1, wc = w & 1;
  const int sr = lane >> 2, sc = (lane & 3)*8;
  const f16* Ax0 = X + (size_t)(rb + w*16 + sr)*D_ + sc;
  const f16* Ax1 = X + (size_t)(rb + 64 + w*16 + sr)*D_ + sc;
  const f16* Bx0 = W + (size_t)(cb + w*16 + sr)*D_ + sc;
  const f16* Bx1 = W + (size_t)(cb + 64 + w*16 + sr)*D_ + sc;
  f16* Ad0 = &As[(w*16)*32];
  f16* Ad1 = &As[(64 + w*16)*32];
  f16* Bd0 = &Bs[(w*16)*32];
  f16* Bd1 = &Bs[(64 + w*16)*32];

  f32x4 acc[4][4];
#pragma unroll
  for (int m = 0; m < 4; ++m)
#pragma unroll
    for (int n = 0; n < 4; ++n) acc[m][n] = (f32x4){0.f,0.f,0.f,0.f};

  for (int k0 = 0; k0 < D_; k0 += 32){
    gld16(Ax0 + k0, Ad0);
    gld16(Ax1 + k0, Ad1);
    gld16(Bx0 + k0, Bd0);
    gld16(Bx1 + k0, Bd1);
    __syncthreads();
    f16x8 a[4], b[4];
#pragma unroll
    for (int m = 0; m < 4; ++m) a[m] = ld8(&As[(wr*64 + m*16 + l16)*32 + l4*8]);
#pragma unroll
    for (int n = 0; n < 4; ++n) b[n] = ld8(&Bs[(wc*64 + n*16 + l16)*32 + l4*8]);
#pragma unroll
    for (int m = 0; m < 4; ++m)
#pragma unroll
      for (int n = 0; n < 4; ++n)
        acc[m][n] = MFMA16(a[m], b[n], acc[m][n], 0,0,0);
    __syncthreads();
  }

  const float qs = exp2f(-2.0f*tanhf(tsc[0]))*LOG2E*0.125f;
  const float scale = (g == 0) ? qs : 1.0f;
  f16* out = (g == 0) ? qo : ko;
#pragma unroll
  for (int n = 0; n < 4; ++n){
    const int col = cb + wc*64 + n*16 + l16;
    const float bv = bias[col];
#pragma unroll
    for (int m = 0; m < 4; ++m){
#pragma unroll
      for (int j = 0; j < 4; ++j){
        const int row = rb + wr*64 + m*16 + l4*4 + j;
        const float v = (acc[m][n][j] + bv)*scale;
        if (g < 2){
          out[(size_t)row*D_ + col] = (f16)v;
        } else {
          const int b = row >> 10, t = row & (T_-1);
          const int h = col >> 6,  dl = col & (HD_-1);
          vT[(((size_t)b*H_ + h)*HD_ + dl)*T_ + t] = (f16)v;
        }
      }
    }
  }
}

// =============== fused attention (QBLK=16, chunked, no atomics) =============
// block = 16 q-rows x one (b,h); 4 waves. s in 8 chunks of 128:
// QK stages K(16KB)+bias(4KB) -> 4 MFMA/wave (wave w owns s-local [w*32,+32));
// scores in acc[16] registers; softmax in-register. PV: per chunk waves write
// their P slice (4KB) + stage V(16KB) -> 4 MFMA/wave; edge gather -> plain
// per-head store into gpart (each (bh,t,kk) written exactly once; no atomics).
// LDS buffers XOR-swizzled (16B chunk ^= row&7, pre-swizzled global source).
__global__ __launch_bounds__(256,4) void attn_fused(
    const f16* __restrict__ q, const f16* __restrict__ k, const f16* __restrict__ vT,
    const f16* __restrict__ biasP, const int* __restrict__ eidx,
    f16* __restrict__ X2, float* __restrict__ gpart)
{
  __shared__ f16 Sb[8192];        // 16 KB: K chunk [128 s][64 d] / V chunk [64 d][128 s]
  __shared__ f16 Pc[16*128];      // 4 KB: bias chunk / P chunk [16 q][128 s]
  __shared__ float red[2][4][16];
  const int bid = blockIdx.x;
  const int swz = (bid & 7)*256 + (bid >> 3);   // XCD gets 4 contiguous bh
  const int bh = swz >> 6, tb = swz & 63;
  const int bi = bh >> 3, h = bh & 7;
  const int t0 = tb*16;
  const int tid = threadIdx.x, w = tid >> 6, lane = tid & 63;
  const int l16 = lane & 15, l4 = lane >> 4;
  const int key = l16 & 7;        // XOR-swizzle key for frag reads

  // ---- Q fragments + gather tuples (registers, loaded once) ----
  const f16* qp = q + (size_t)(bi*T_ + t0 + l16)*D_ + h*HD_ + l4*8;
  const f16x8 q0 = ld8(qp), q1 = ld8(qp + 32);
  int g_id0, g_r0, g_kk0, g_id1 = -1, g_r1 = 0, g_kk1 = 0;
  g_r0 = tid/KN; g_kk0 = tid - g_r0*KN;
  g_id0 = eidx[((size_t)(bi*T_ + t0 + g_r0))*KN + g_kk0];
  if (tid + 256 < 16*KN){
    g_r1 = (tid+256)/KN; g_kk1 = (tid+256) - g_r1*KN;
    g_id1 = eidx[((size_t)(bi*T_ + t0 + g_r1))*KN + g_kk1];
  }

  const f16* kg = k + (size_t)(bi*T_)*D_ + h*HD_;
  const f16* bg = biasP + ((size_t)(bi*T_ + t0))*T_;
  const f16* vg = vT + (size_t)bh*HD_*T_;

  // ---- QK^T: 8 chunks of 128 s ----
  f32x4 acc[16];
#pragma unroll
  for (int c = 0; c < 8; ++c){
    if (c) __syncthreads();                       // prev chunk's LDS reads done
    // stage K chunk: 1024x16B; rows 128B = 8 chunks, src col pre-swizzled
#pragma unroll
    for (int i = 0; i < 4; ++i){
      const int cidx = i*256 + w*64 + lane;
      const int r = cidx >> 3, p = cidx & 7;
      gld16(kg + (size_t)(c*128 + r)*D_ + ((p ^ (r & 7)) << 3),
            &Sb[(i*256 + w*64)*8]);
    }
    // stage bias chunk: 256x16B; rows 256B = 16 chunks
    {
      const int cidx = w*64 + lane;
      const int r = cidx >> 4, p = cidx & 15;
      gld16(bg + (size_t)r*T_ + c*128 + ((p ^ (r & 7)) << 3),
            &Pc[w*512]);
    }
    __syncthreads();                              // stage visible
#pragma unroll
    for (int step = 0; step < 2; ++step){
      const int r = w*32 + step*16 + l16;         // local s row (r&7 == key)
      f32x4 a = {0.f,0.f,0.f,0.f};
      a = MFMA16(ld8(&Sb[r*64 + ((l4 ^ key) << 3)]),       q0, a, 0,0,0);
      a = MFMA16(ld8(&Sb[r*64 + (((4 + l4) ^ key) << 3)]), q1, a, 0,0,0);
      const int slb = w*32 + step*16 + l4*4;
      const f16x4 bf = *reinterpret_cast<const f16x4*>(
          &Pc[l16*128 + (((slb >> 3) ^ key) << 3) + (slb & 7)]);
#pragma unroll
      for (int j = 0; j < 4; ++j) a[j] += (float)bf[j];
      acc[c*2 + step] = a;
    }
  }

  // ---- softmax: in-lane 64 values + shfl + cross-wave ----
  float m = -3.4e38f;
#pragma unroll
  for (int c = 0; c < 16; ++c)
#pragma unroll
    for (int j = 0; j < 4; ++j) m = fmaxf(m, acc[c][j]);
  m = fmaxf(m, __shfl_xor(m, 16));
  m = fmaxf(m, __shfl_xor(m, 32));
  if (lane < 16) red[0][w][lane] = m;
  __syncthreads();
  m = fmaxf(fmaxf(red[0][0][l16], red[0][1][l16]),
            fmaxf(red[0][2][l16], red[0][3][l16]));
  float l = 0.f;
#pragma unroll
  for (int c = 0; c < 16; ++c)
#pragma unroll
    for (int j = 0; j < 4; ++j){
      const float e = exp2f(acc[c][j] - m);
      l += e;
      acc[c][j] = e;                               // acc now holds unnormalized P
    }
  l += __shfl_xor(l, 16);
  l += __shfl_xor(l, 32);
  if (lane < 16) red[1][w][lane] = l;

  // ---- PV: 8 chunks of 128 s; P from regs -> Pc, V staged -> Sb ----
  f32x4 oo0 = {0.f,0.f,0.f,0.f}, oo1 = oo0, oo2 = oo0, oo3 = oo0;
#pragma unroll
  for (int sc = 0; sc < 8; ++sc){
    __syncthreads();                              // prev reads done (+red[1] for sc=0)
    // write this wave's P slice (s-local [w*32,+32))
#pragma unroll
    for (int step = 0; step < 2; ++step){
      const int slb = w*32 + step*16 + l4*4;
      f16x4 pp;
#pragma unroll
      for (int j = 0; j < 4; ++j) pp[j] = (f16)acc[sc*2 + step][j];
      *reinterpret_cast<f16x4*>(
          &Pc[l16*128 + (((slb >> 3) ^ key) << 3) + (slb & 7)]) = pp;
    }
    // stage V chunk: 1024x16B; rows 256B = 16 chunks
#pragma unroll
    for (int i = 0; i < 4; ++i){
      const int cidx = i*256 + w*64 + lane;
      const int r = cidx >> 4, p = cidx & 15;
      gld16(vg + (size_t)r*T_ + sc*128 + ((p ^ (r & 7)) << 3),
            &Sb[(i*256 + w*64)*8]);
    }
    __syncthreads();                              // P + V visible
    const int vrow = (w*16 + l16)*128;
#pragma unroll
    for (int grp = 0; grp < 4; ++grp){
      const int ch = (grp*4 + l4) ^ key;
      const f16x8 pa = ld8(&Pc[l16*128 + (ch << 3)]);
      const f16x8 vb = ld8(&Sb[vrow + (ch << 3)]);
      if (grp == 0)      oo0 = MFMA16(pa, vb, oo0, 0,0,0);
      else if (grp == 1) oo1 = MFMA16(pa, vb, oo1, 0,0,0);
      else if (grp == 2) oo2 = MFMA16(pa, vb, oo2, 0,0,0);
      else               oo3 = MFMA16(pa, vb, oo3, 0,0,0);
    }
    // edge gather for ids in this s-chunk: plain per-head store, no atomics
    if ((g_id0 >> 7) == sc){
      const float lr = red[1][0][g_r0] + red[1][1][g_r0] + red[1][2][g_r0] + red[1][3][g_r0];
      const int sl = g_id0 & 127;
      const float pv = (float)Pc[g_r0*128 + ((((sl >> 3) ^ (g_r0 & 7)) << 3) | (sl & 7))];
      gpart[((size_t)bh*T_ + t0 + g_r0)*KN + g_kk0] = pv/lr*0.125f;
    }
    if (g_id1 >= 0 && (g_id1 >> 7) == sc){
      const float lr = red[1][0][g_r1] + red[1][1][g_r1] + red[1][2][g_r1] + red[1][3][g_r1];
      const int sl = g_id1 & 127;
      const float pv = (float)Pc[g_r1*128 + ((((sl >> 3) ^ (g_r1 & 7)) << 3) | (sl & 7))];
      gpart[((size_t)bh*T_ + t0 + g_r1)*KN + g_kk1] = pv/lr*0.125f;
    }
  }
  const f32x4 o = (oo0 + oo1) + (oo2 + oo3);

#pragma unroll
  for (int j = 0; j < 4; ++j){
    const int row = l4*4 + j;
    const float lr = red[1][0][row] + red[1][1][row] + red[1][2][row] + red[1][3][row];
    const int t = t0 + row;
    X2[((size_t)(bi*T_ + t))*640 + h*HD_ + w*16 + l16] = (f16)(o[j]/lr);
  }
}

// ---------------- edge: weighted neighbor-embedding mean -------------------
// g[b,t,kk] = sum_h gpart[(b*H+h), t, kk]
__global__ __launch_bounds__(128) void edge_kernel(
    const float* __restrict__ gpart, const float* __restrict__ E, f16* __restrict__ X2)
{
  __shared__ float gl[KN];
  __shared__ float ginv;
  const int bt = blockIdx.x;          // b*T + t
  const int bi = bt >> 10, tt = bt & 1023;
  const int t = threadIdx.x;
  if (t < KN){
    float s = 0.f;
#pragma unroll
    for (int hh = 0; hh < H_; ++hh)
      s += gpart[((size_t)(bi*H_ + hh)*T_ + tt)*KN + t];
    gl[t] = s;
  }
  __syncthreads();
  if (t == 0){
    float s = 0.f;
#pragma unroll
    for (int i = 0; i < KN; ++i) s += gl[i];
    ginv = 1.0f/(s + 1e-6f);
  }
  __syncthreads();
  float acc = 0.f;
  const float* Ep = E + (size_t)bt*KN*ED_ + t;
#pragma unroll 5
  for (int kk = 0; kk < KN; ++kk) acc += gl[kk]*Ep[(size_t)kk*ED_];
  X2[(size_t)bt*640 + 512 + t] = (f16)(acc*ginv);
}

// ---------------- LayerNorm helpers ----------------------------------------
__device__ __forceinline__ float block_sum(float v, float* sbuf){
  for (int o = 32; o; o >>= 1) v += __shfl_down(v, o);
  __syncthreads();
  if ((threadIdx.x & 63) == 0) sbuf[threadIdx.x >> 6] = v;
  __syncthreads();
  return sbuf[0]+sbuf[1]+sbuf[2]+sbuf[3];
}

__global__ __launch_bounds__(256) void ln1_kernel(
    const float* __restrict__ hV, const float* __restrict__ hraw,
    const float* __restrict__ gn, const float* __restrict__ bn,
    float* __restrict__ hf, f16* __restrict__ hh)
{
  __shared__ float sbuf[4];
  const int r = blockIdx.x, t = threadIdx.x;
  const size_t base = (size_t)r*D_;
  float x0 = hV[base+t]     + hraw[base+t];
  float x1 = hV[base+t+256] + hraw[base+t+256];
  float s = block_sum(x0+x1, sbuf);
  const float mean = s*(1.f/512.f);
  float d0 = x0-mean, d1 = x1-mean;
  float vs = block_sum(d0*d0+d1*d1, sbuf);
  const float rstd = rsqrtf(vs*(1.f/512.f) + 1e-5f);
  float y0 = d0*rstd*gn[t]     + bn[t];
  float y1 = d1*rstd*gn[t+256] + bn[t+256];
  hf[base+t]     = y0;  hh[base+t]     = (f16)y0;
  hf[base+t+256] = y1;  hh[base+t+256] = (f16)y1;
}

__global__ __launch_bounds__(256) void final_kernel(
    const float* __restrict__ hf, const float* __restrict__ ffr,
    const float* __restrict__ gf, const float* __restrict__ bfv,
    const float* __restrict__ g2, const float* __restrict__ b2,
    float* __restrict__ out)
{
  __shared__ float sbuf[4];
  const int r = blockIdx.x, t = threadIdx.x;
  const size_t base = (size_t)r*D_;
  const float h0 = hf[base+t], h1 = hf[base+t+256];
  float x0 = h0 + ffr[base+t], x1 = h1 + ffr[base+t+256];
  float s = block_sum(x0+x1, sbuf);
  float mean = s*(1.f/512.f);
  float d0 = x0-mean, d1 = x1-mean;
  float vs = block_sum(d0*d0+d1*d1, sbuf);
  float rstd = rsqrtf(vs*(1.f/512.f) + 1e-6f);
  const float dh0 = d0*rstd*gf[t]     + bfv[t];
  const float dh1 = d1*rstd*gf[t+256] + bfv[t+256];
  const float y0 = h0 + dh0, y1 = h1 + dh1;
  s = block_sum(y0+y1, sbuf);
  mean = s*(1.f/512.f);
  d0 = y0-mean; d1 = y1-mean;
  vs = block_sum(d0*d0+d1*d1, sbuf);
  rstd = rsqrtf(vs*(1.f/512.f) + 1e-5f);
  out[base+t]     = d0*rstd*g2[t]     + b2[t];
  out[base+t+256] = d1*rstd*g2[t+256] + b2[t+256];
}

// ---------------------------------------------------------------------------
extern "C" void kernel_launch(void* const* d_in, const int* in_sizes, int n_in,
                              void* d_out, int out_size, void* d_ws, size_t ws_size,
                              hipStream_t stream)
{
  (void)in_sizes; (void)n_in; (void)out_size;
  const float* h_V  = (const float*)d_in[0];
  const float* kin  = (const float*)d_in[1];
  const float* vin  = (const float*)d_in[2];
  const float* E    = (const float*)d_in[3];
  const float* bias = (const float*)d_in[4];
  const float* Wq   = (const float*)d_in[5];
  const float* bq   = (const float*)d_in[6];
  const float* Wk   = (const float*)d_in[7];
  const float* bk   = (const float*)d_in[8];
  const float* Wv   = (const float*)d_in[9];
  const float* bv   = (const float*)d_in[10];
  const float* Wo   = (const float*)d_in[11];
  const float* bo   = (const float*)d_in[12];
  const float* tsc  = (const float*)d_in[13];
  const float* gn   = (const float*)d_in[14];
  const float* bn   = (const float*)d_in[15];
  const float* w1   = (const float*)d_in[16];
  const float* bw1  = (const float*)d_in[17];
  const float* w2   = (const float*)d_in[18];
  const float* bw2  = (const float*)d_in[19];
  const float* gf   = (const float*)d_in[20];
  const float* bfv  = (const float*)d_in[21];
  const float* g2   = (const float*)d_in[22];
  const float* b2   = (const float*)d_in[23];
  const int*   Eidx = (const int*)d_in[24];
  const int*   mask = (const int*)d_in[25];
  float* out = (float*)d_out;

  char* wsb = (char*)d_ws;
  size_t off = 0;
  auto alloc = [&](size_t bytes) -> void* {
    void* pp = wsb + off; off += (bytes + 255) & ~(size_t)255; return pp;
  };
  f16* hVb  = (f16*)alloc((size_t)M_*D_*2);
  f16* kbI  = (f16*)alloc((size_t)M_*D_*2);
  f16* vbI  = (f16*)alloc((size_t)M_*D_*2);
  f16* Wqb  = (f16*)alloc((size_t)D_*D_*2);
  f16* Wkb  = (f16*)alloc((size_t)D_*D_*2);
  f16* Wvb  = (f16*)alloc((size_t)D_*D_*2);
  f16* Wob  = (f16*)alloc((size_t)D_*(D_+ED_)*2);
  f16* w1b  = (f16*)alloc((size_t)DFF_*D_*2);
  f16* w2b  = (f16*)alloc((size_t)D_*DFF_*2);
  f16* qb   = (f16*)alloc((size_t)M_*D_*2);
  f16* kb   = (f16*)alloc((size_t)M_*D_*2);
  f16* vT   = (f16*)alloc((size_t)M_*D_*2);
  f16* biasP= (f16*)alloc((size_t)B_*T_*T_*2);
  f16* X2   = (f16*)alloc((size_t)M_*640*2);
  float* gpart = (float*)alloc((size_t)BH_*T_*KN*4);
  float* hraw = (float*)alloc((size_t)M_*D_*4);   // reused as ffraw
  float* hf   = (float*)alloc((size_t)M_*D_*4);
  f16*   hh   = (f16*)alloc((size_t)M_*D_*2);
  f16*   ff1  = (f16*)alloc((size_t)M_*DFF_*2);
  if (ws_size < off) return;  // scratch insufficient -> loud validation failure
  float* ffraw = hraw;

  // 1) converts fp32 -> f16 (one launch) + bias prep
  {
    CvtJobs J;
    const float* srcs[9] = {h_V, kin, vin, Wq, Wk, Wv, Wo, w1, w2};
    f16* dsts[9] = {hVb, kbI, vbI, Wqb, Wkb, Wvb, Wob, w1b, w2b};
    const int n4s[9] = {M_*D_/4, M_*D_/4, M_*D_/4, D_*D_/4, D_*D_/4, D_*D_/4,
                        D_*(D_+ED_)/4, DFF_*D_/4, D_*DFF_/4};
    int cum = 0;
    for (int i = 0; i < 9; ++i){
      J.s[i] = srcs[i]; J.d[i] = dsts[i]; J.start[i] = cum;
      cum += n4s[i]/256;
    }
    J.start[9] = cum;
    cvt9_kernel<<<cum,256,0,stream>>>(J);
  }
  biasprep_kernel<<<B_*T_*T_/8/256,256,0,stream>>>(bias, mask, tsc, biasP);

  // 2) batched q/k/v projections (q pre-scaled for exp2 softmax; v -> vT)
  qkv_tile<<<384,256,0,stream>>>(hVb, kbI, vbI, Wqb, Wkb, Wvb, bq, bk, bv, tsc, qb, kb, vT);

  // 3) fused attention (QK^T + softmax + PV + edge gather), QBLK=16
  attn_fused<<<2048,256,0,stream>>>(qb, kb, vT, biasP, Eidx, X2, gpart);

  // 4) edge embedding (sums 8 per-head partials)
  edge_kernel<<<M_,128,0,stream>>>(gpart, E, X2);

  // 5) out-proj (128x64 tiles, 256 blocks) + residual LN
  gemm_n64<2><<<256,256,0,stream>>>(X2, Wob, bo, hraw, D_+ED_, D_, 8);
  ln1_kernel<<<M_,256,0,stream>>>(h_V, hraw, gn, bn, hf, hh);

  // 6) FFN: FF1 128x128 (512 blocks), FF2 128x64 (256 blocks)
  gemm_tile<1><<<512,256,0,stream>>>(hh, w1b, bw1, ff1, D_, DFF_, 16);
  gemm_n64<2><<<256,256,0,stream>>>(ff1, w2b, bw2, ffraw, DFF_, D_, 8);

  // 7) final double-LN
  final_kernel<<<M_,256,0,stream>>>(hf, ffraw, gf, bfv, g2, b2, out);
}

// Round 12
// 169.979 us; speedup vs baseline: 1.5516x; 1.0928x over previous
//
#include <hip/hip_runtime.h>
#include <hip/hip_fp16.h>
#include <math.h>

#define B_ 4
#define T_ 1024
#define D_ 512
#define H_ 8
#define HD_ 64
#define KN 30
#define ED_ 128
#define DFF_ 2048
#define M_ 4096   // B*T
#define BH_ 32

typedef _Float16 f16;
typedef __attribute__((ext_vector_type(8))) _Float16 f16x8;
typedef __attribute__((ext_vector_type(4))) _Float16 f16x4;
typedef __attribute__((ext_vector_type(4))) float f32x4;

#define MFMA16 __builtin_amdgcn_mfma_f32_16x16x32_f16
#define LOG2E 1.44269504088896f

__device__ __forceinline__ f16x8 ld8(const f16* p){ return *reinterpret_cast<const f16x8*>(p); }

__device__ __forceinline__ void gld16(const void* g, void* l){
  __builtin_amdgcn_global_load_lds((const __attribute__((address_space(1))) void*)g,
                                   (__attribute__((address_space(3))) void*)l, 16, 0, 0);
}

// ---------------- combined fp32 -> fp16 convert (9 tensors, 1 launch) -------
struct CvtJobs {
  const float* s[9];
  f16* d[9];
  int start[10];   // cumulative block starts; each block = 256 float4s
};

__global__ __launch_bounds__(256) void cvt9_kernel(CvtJobs J){
  const int blk = blockIdx.x;
  int j = 0;
  while (j < 8 && blk >= J.start[j+1]) ++j;
  const int i = (blk - J.start[j])*256 + threadIdx.x;
  float4 v = reinterpret_cast<const float4*>(J.s[j])[i];
  union { f16 h[4]; ushort4 u; } o;
  o.h[0]=(f16)v.x; o.h[1]=(f16)v.y; o.h[2]=(f16)v.z; o.h[3]=(f16)v.w;
  reinterpret_cast<ushort4*>(J.d[j])[i] = o.u;
}

// ---------------- bias prep: f16((bias + mask*-6e4) * rtemp * log2e) --------
__global__ __launch_bounds__(256) void biasprep_kernel(
    const float* __restrict__ bias, const int* __restrict__ mask,
    const float* __restrict__ tsc, f16* __restrict__ biasP)
{
  const int gid = blockIdx.x*256 + threadIdx.x;      // 524288 threads, 8 elems each
  const float s = exp2f(-2.0f*tanhf(tsc[0]))*LOG2E;  // log2e / 4^tanh(t)
  const int b = gid >> 17;                            // T*T/8 = 131072 per batch
  const int rem = gid & 131071;
  const int idx8 = rem*8;
  const int s0 = idx8 & 1023;
  const size_t gbase = (size_t)b*T_*T_ + idx8;
  float4 v0 = *reinterpret_cast<const float4*>(bias + gbase);
  float4 v1 = *reinterpret_cast<const float4*>(bias + gbase + 4);
  int4 m0 = *reinterpret_cast<const int4*>(mask + b*T_ + s0);
  int4 m1 = *reinterpret_cast<const int4*>(mask + b*T_ + s0 + 4);
  float x[8] = {v0.x,v0.y,v0.z,v0.w,v1.x,v1.y,v1.z,v1.w};
  int  mm[8] = {m0.x,m0.y,m0.z,m0.w,m1.x,m1.y,m1.z,m1.w};
  union { f16 h[8]; ushort4 u[2]; } o;
#pragma unroll
  for (int i = 0; i < 8; ++i){
    float t = (x[i] + (mm[i] ? 0.f : -60000.f))*s;
    o.h[i] = (f16)fmaxf(t, -60000.f);
  }
  reinterpret_cast<ushort4*>(biasP + gbase)[0] = o.u[0];
  reinterpret_cast<ushort4*>(biasP + gbase)[1] = o.u[1];
}

// =============== staged MFMA GEMM: C = X @ W.T, BK=64, XOR-swizzled =========
// 128x128 tile, 32 MFMA/wave per K-step, 2 barriers per 64-K.
// EPI 1: f16 gelu(acc+bias). EPI 2: f32 acc+bias.
template<int EPI>
__global__ __launch_bounds__(256,2) void gemm_tile(
    const f16* __restrict__ X, const f16* __restrict__ W,
    const float* __restrict__ bias, void* __restrict__ outp,
    int Kd, int ldo, int nbN)
{
  __shared__ f16 As[128*64];
  __shared__ f16 Bs[128*64];
  const int nwg = gridDim.x;
  const int bid = blockIdx.x;
  const int swz = (bid & 7)*(nwg >> 3) + (bid >> 3);
  const int mb = swz / nbN, nb = swz - mb*nbN;
  const int rb = mb*128, cb = nb*128;
  const int tid = threadIdx.x;
  const int w = tid >> 6, lane = tid & 63;
  const int l16 = lane & 15, l4 = lane >> 4;
  const int wr = w >> 1, wc = w & 1;
  const int key = l16 & 7;

  f32x4 acc[4][4];
#pragma unroll
  for (int m = 0; m < 4; ++m)
#pragma unroll
    for (int n = 0; n < 4; ++n) acc[m][n] = (f32x4){0.f,0.f,0.f,0.f};

  for (int k0 = 0; k0 < Kd; k0 += 64){
    // stage A,B: 1024 16B-chunks each; rows 128B = 8 chunks; src pre-swizzled
#pragma unroll
    for (int i = 0; i < 4; ++i){
      const int cidx = i*256 + w*64 + lane;
      const int r = cidx >> 3, p = cidx & 7;
      gld16(X + (size_t)(rb + r)*Kd + k0 + ((p ^ (r & 7)) << 3),
            &As[(i*256 + w*64)*8]);
      gld16(W + (size_t)(cb + r)*Kd + k0 + ((p ^ (r & 7)) << 3),
            &Bs[(i*256 + w*64)*8]);
    }
    __syncthreads();
#pragma unroll
    for (int kk = 0; kk < 2; ++kk){
      f16x8 a[4], b[4];
#pragma unroll
      for (int m = 0; m < 4; ++m)
        a[m] = ld8(&As[(wr*64 + m*16 + l16)*64 + (((kk*4 + l4) ^ key) << 3)]);
#pragma unroll
      for (int n = 0; n < 4; ++n)
        b[n] = ld8(&Bs[(wc*64 + n*16 + l16)*64 + (((kk*4 + l4) ^ key) << 3)]);
#pragma unroll
      for (int m = 0; m < 4; ++m)
#pragma unroll
        for (int n = 0; n < 4; ++n)
          acc[m][n] = MFMA16(a[m], b[n], acc[m][n], 0,0,0);
    }
    __syncthreads();
  }

#pragma unroll
  for (int n = 0; n < 4; ++n){
    const int col = cb + wc*64 + n*16 + l16;
    const float bv = bias[col];
#pragma unroll
    for (int m = 0; m < 4; ++m){
#pragma unroll
      for (int j = 0; j < 4; ++j){
        const int row = rb + wr*64 + m*16 + l4*4 + j;
        float v = acc[m][n][j] + bv;
        if (EPI == 1){
          v = 0.5f*v*(1.0f + erff(v*0.70710678118654752f));
          ((f16*)outp)[(size_t)row*ldo + col] = (f16)v;
        } else {
          ((float*)outp)[(size_t)row*ldo + col] = v;
        }
      }
    }
  }
}

// =============== 128x64-tile GEMM, BK=64, XOR-swizzled ======================
template<int EPI>
__global__ __launch_bounds__(256,2) void gemm_n64(
    const f16* __restrict__ X, const f16* __restrict__ W,
    const float* __restrict__ bias, void* __restrict__ outp,
    int Kd, int ldo, int nbN)
{
  __shared__ f16 As[128*64];
  __shared__ f16 Bs[64*64];
  const int nwg = gridDim.x;
  const int bid = blockIdx.x;
  const int swz = (bid & 7)*(nwg >> 3) + (bid >> 3);
  const int mb = swz / nbN, nb = swz - mb*nbN;
  const int rb = mb*128, cb = nb*64;
  const int tid = threadIdx.x;
  const int w = tid >> 6, lane = tid & 63;
  const int l16 = lane & 15, l4 = lane >> 4;
  const int wr = w >> 1, wc = w & 1;
  const int key = l16 & 7;

  f32x4 acc[4][2];
#pragma unroll
  for (int m = 0; m < 4; ++m)
#pragma unroll
    for (int n = 0; n < 2; ++n) acc[m][n] = (f32x4){0.f,0.f,0.f,0.f};

  for (int k0 = 0; k0 < Kd; k0 += 64){
#pragma unroll
    for (int i = 0; i < 4; ++i){
      const int cidx = i*256 + w*64 + lane;
      const int r = cidx >> 3, p = cidx & 7;
      gld16(X + (size_t)(rb + r)*Kd + k0 + ((p ^ (r & 7)) << 3),
            &As[(i*256 + w*64)*8]);
    }
#pragma unroll
    for (int i = 0; i < 2; ++i){
      const int cidx = i*256 + w*64 + lane;
      const int r = cidx >> 3, p = cidx & 7;
      gld16(W + (size_t)(cb + r)*Kd + k0 + ((p ^ (r & 7)) << 3),
            &Bs[(i*256 + w*64)*8]);
    }
    __syncthreads();
#pragma unroll
    for (int kk = 0; kk < 2; ++kk){
      f16x8 a[4], b[2];
#pragma unroll
      for (int m = 0; m < 4; ++m)
        a[m] = ld8(&As[(wr*64 + m*16 + l16)*64 + (((kk*4 + l4) ^ key) << 3)]);
#pragma unroll
      for (int n = 0; n < 2; ++n)
        b[n] = ld8(&Bs[(wc*32 + n*16 + l16)*64 + (((kk*4 + l4) ^ key) << 3)]);
#pragma unroll
      for (int m = 0; m < 4; ++m)
#pragma unroll
        for (int n = 0; n < 2; ++n)
          acc[m][n] = MFMA16(a[m], b[n], acc[m][n], 0,0,0);
    }
    __syncthreads();
  }

#pragma unroll
  for (int n = 0; n < 2; ++n){
    const int col = cb + wc*32 + n*16 + l16;
    const float bv = bias[col];
#pragma unroll
    for (int m = 0; m < 4; ++m){
#pragma unroll
      for (int j = 0; j < 4; ++j){
        const int row = rb + wr*64 + m*16 + l4*4 + j;
        float v = acc[m][n][j] + bv;
        if (EPI == 1){
          v = 0.5f*v*(1.0f + erff(v*0.70710678118654752f));
          ((f16*)outp)[(size_t)row*ldo + col] = (f16)v;
        } else {
          ((float*)outp)[(size_t)row*ldo + col] = v;
        }
      }
    }
  }
}

// =============== batched QKV projection (one launch, 3 GEMMs) ===============
__global__ __launch_bounds__(256,2) void qkv_tile(
    const f16* __restrict__ hV, const f16* __restrict__ kI, const f16* __restrict__ vI,
    const f16* __restrict__ Wq, const f16* __restrict__ Wk, const f16* __restrict__ Wv,
    const float* __restrict__ bq, const float* __restrict__ bk, const float* __restrict__ bv,
    const float* __restrict__ tsc,
    f16* __restrict__ qo, f16* __restrict__ ko, f16* __restrict__ vT)
{
  __shared__ f16 As[128*32];
  __shared__ f16 Bs[128*32];
  const int bid = blockIdx.x;
  const int swz = (bid & 7)*48 + (bid >> 3);
  const int g = swz >> 7;
  const int r = swz & 127;
  const int mb = r >> 2, nb = r & 3;
  const f16* X  = (g == 0) ? hV : ((g == 1) ? kI : vI);
  const f16* W  = (g == 0) ? Wq : ((g == 1) ? Wk : Wv);
  const float* bias = (g == 0) ? bq : ((g == 1) ? bk : bv);
  const int rb = mb*128, cb = nb*128;
  const int tid = threadIdx.x;
  const int w = tid >> 6, lane = tid & 63;
  const int l16 = lane & 15, l4 = lane >> 4;
  const int wr = w >> 1, wc = w & 1;
  const int sr = lane >> 2, sc = (lane & 3)*8;
  const f16* Ax0 = X + (size_t)(rb + w*16 + sr)*D_ + sc;
  const f16* Ax1 = X + (size_t)(rb + 64 + w*16 + sr)*D_ + sc;
  const f16* Bx0 = W + (size_t)(cb + w*16 + sr)*D_ + sc;
  const f16* Bx1 = W + (size_t)(cb + 64 + w*16 + sr)*D_ + sc;
  f16* Ad0 = &As[(w*16)*32];
  f16* Ad1 = &As[(64 + w*16)*32];
  f16* Bd0 = &Bs[(w*16)*32];
  f16* Bd1 = &Bs[(64 + w*16)*32];

  f32x4 acc[4][4];
#pragma unroll
  for (int m = 0; m < 4; ++m)
#pragma unroll
    for (int n = 0; n < 4; ++n) acc[m][n] = (f32x4){0.f,0.f,0.f,0.f};

  for (int k0 = 0; k0 < D_; k0 += 32){
    gld16(Ax0 + k0, Ad0);
    gld16(Ax1 + k0, Ad1);
    gld16(Bx0 + k0, Bd0);
    gld16(Bx1 + k0, Bd1);
    __syncthreads();
    f16x8 a[4], b[4];
#pragma unroll
    for (int m = 0; m < 4; ++m) a[m] = ld8(&As[(wr*64 + m*16 + l16)*32 + l4*8]);
#pragma unroll
    for (int n = 0; n < 4; ++n) b[n] = ld8(&Bs[(wc*64 + n*16 + l16)*32 + l4*8]);
#pragma unroll
    for (int m = 0; m < 4; ++m)
#pragma unroll
      for (int n = 0; n < 4; ++n)
        acc[m][n] = MFMA16(a[m], b[n], acc[m][n], 0,0,0);
    __syncthreads();
  }

  const float qs = exp2f(-2.0f*tanhf(tsc[0]))*LOG2E*0.125f;
  const float scale = (g == 0) ? qs : 1.0f;
  f16* out = (g == 0) ? qo : ko;
#pragma unroll
  for (int n = 0; n < 4; ++n){
    const int col = cb + wc*64 + n*16 + l16;
    const float bv = bias[col];
#pragma unroll
    for (int m = 0; m < 4; ++m){
#pragma unroll
      for (int j = 0; j < 4; ++j){
        const int row = rb + wr*64 + m*16 + l4*4 + j;
        const float v = (acc[m][n][j] + bv)*scale;
        if (g < 2){
          out[(size_t)row*D_ + col] = (f16)v;
        } else {
          const int b = row >> 10, t = row & (T_-1);
          const int h = col >> 6,  dl = col & (HD_-1);
          vT[(((size_t)b*H_ + h)*HD_ + dl)*T_ + t] = (f16)v;
        }
      }
    }
  }
}

// =============== fused attention (QBLK=32, 512 threads, 8 waves) ============
// block = 32 q-rows x one (b,h). Wave w: qg=w>>2 owns q-group (16 rows),
// ws=w&3 owns s-subrange [ws*32,+32) per 128-s chunk (QK) and d-cols
// [ws*16,+16) (PV). Per-wave state identical to the QBLK=16 version
// (acc[16], oo[4]); K/V staged once per 32 q-rows (halved L2 traffic).
// Edge gather -> plain per-head store (no atomics). XOR-swizzled LDS.
__global__ __launch_bounds__(512,4) void attn_fused(
    const f16* __restrict__ q, const f16* __restrict__ k, const f16* __restrict__ vT,
    const f16* __restrict__ biasP, const int* __restrict__ eidx,
    f16* __restrict__ X2, float* __restrict__ gpart)
{
  __shared__ f16 Sb[8192];        // 16 KB: K chunk [128 s][64 d] / V chunk [64 d][128 s]
  __shared__ f16 Pc[32*128];      // 8 KB: bias chunk / P chunk [32 q][128 s]
  __shared__ float red[2][2][4][16];  // [stat][qg][ws][qcol]
  const int bid = blockIdx.x;
  const int swz = (bid & 7)*128 + (bid >> 3);   // 1024 blocks, XCD-contiguous
  const int bh = swz >> 5, tb = swz & 31;
  const int bi = bh >> 3, h = bh & 7;
  const int t0 = tb*32;
  const int tid = threadIdx.x, w = tid >> 6, lane = tid & 63;
  const int qg = w >> 2, ws = w & 3;
  const int l16 = lane & 15, l4 = lane >> 4;
  const int key = l16 & 7;        // XOR-swizzle key for frag reads

  // ---- Q fragments + gather tuples ----
  const f16* qp = q + (size_t)(bi*T_ + t0 + qg*16 + l16)*D_ + h*HD_ + l4*8;
  const f16x8 q0 = ld8(qp), q1 = ld8(qp + 32);
  int g_id0, g_r0, g_kk0, g_id1 = -1, g_r1 = 0, g_kk1 = 0;
  g_r0 = tid/KN; g_kk0 = tid - g_r0*KN;
  g_id0 = eidx[((size_t)(bi*T_ + t0 + g_r0))*KN + g_kk0];
  if (tid + 512 < 32*KN){
    g_r1 = (tid+512)/KN; g_kk1 = (tid+512) - g_r1*KN;
    g_id1 = eidx[((size_t)(bi*T_ + t0 + g_r1))*KN + g_kk1];
  }

  const f16* kg = k + (size_t)(bi*T_)*D_ + h*HD_;
  const f16* bg = biasP + ((size_t)(bi*T_ + t0))*T_;
  const f16* vg = vT + (size_t)bh*HD_*T_;

  // ---- QK^T: 8 chunks of 128 s ----
  f32x4 acc[16];
#pragma unroll
  for (int c = 0; c < 8; ++c){
    if (c) __syncthreads();
    // stage K chunk: 1024x16B (rows 128B = 8 chunks), src pre-swizzled
#pragma unroll
    for (int i = 0; i < 2; ++i){
      const int cidx = i*512 + w*64 + lane;
      const int r = cidx >> 3, p = cidx & 7;
      gld16(kg + (size_t)(c*128 + r)*D_ + ((p ^ (r & 7)) << 3),
            &Sb[(i*512 + w*64)*8]);
    }
    // stage bias chunk: 32 rows x 256B = 512x16B chunks
    {
      const int cidx = w*64 + lane;
      const int r = cidx >> 4, p = cidx & 15;
      gld16(bg + (size_t)r*T_ + c*128 + ((p ^ (r & 7)) << 3),
            &Pc[(w*64)*8]);
    }
    __syncthreads();
#pragma unroll
    for (int step = 0; step < 2; ++step){
      const int r = ws*32 + step*16 + l16;        // local s row (r&7 == key)
      f32x4 a = {0.f,0.f,0.f,0.f};
      a = MFMA16(ld8(&Sb[r*64 + ((l4 ^ key) << 3)]),       q0, a, 0,0,0);
      a = MFMA16(ld8(&Sb[r*64 + (((4 + l4) ^ key) << 3)]), q1, a, 0,0,0);
      const int slb = ws*32 + step*16 + l4*4;
      const f16x4 bf = *reinterpret_cast<const f16x4*>(
          &Pc[(qg*16 + l16)*128 + (((slb >> 3) ^ key) << 3) + (slb & 7)]);
#pragma unroll
      for (int j = 0; j < 4; ++j) a[j] += (float)bf[j];
      acc[c*2 + step] = a;
    }
  }

  // ---- softmax: per q-group, in-lane 64 values + shfl + cross-wave ----
  float m = -3.4e38f;
#pragma unroll
  for (int c = 0; c < 16; ++c)
#pragma unroll
    for (int j = 0; j < 4; ++j) m = fmaxf(m, acc[c][j]);
  m = fmaxf(m, __shfl_xor(m, 16));
  m = fmaxf(m, __shfl_xor(m, 32));
  if (lane < 16) red[0][qg][ws][lane] = m;
  __syncthreads();
  m = fmaxf(fmaxf(red[0][qg][0][l16], red[0][qg][1][l16]),
            fmaxf(red[0][qg][2][l16], red[0][qg][3][l16]));
  float l = 0.f;
#pragma unroll
  for (int c = 0; c < 16; ++c)
#pragma unroll
    for (int j = 0; j < 4; ++j){
      const float e = exp2f(acc[c][j] - m);
      l += e;
      acc[c][j] = e;                               // acc now holds unnormalized P
    }
  l += __shfl_xor(l, 16);
  l += __shfl_xor(l, 32);
  if (lane < 16) red[1][qg][ws][lane] = l;

  // ---- PV: 8 chunks of 128 s; P regs -> Pc, V staged -> Sb ----
  f32x4 oo0 = {0.f,0.f,0.f,0.f}, oo1 = oo0, oo2 = oo0, oo3 = oo0;
#pragma unroll
  for (int sc = 0; sc < 8; ++sc){
    __syncthreads();                              // prev reads done (+red[1] for sc=0)
    // write this wave's P slice (q-group qg, s-local [ws*32,+32))
#pragma unroll
    for (int step = 0; step < 2; ++step){
      const int slb = ws*32 + step*16 + l4*4;
      f16x4 pp;
#pragma unroll
      for (int j = 0; j < 4; ++j) pp[j] = (f16)acc[sc*2 + step][j];
      *reinterpret_cast<f16x4*>(
          &Pc[(qg*16 + l16)*128 + (((slb >> 3) ^ key) << 3) + (slb & 7)]) = pp;
    }
    // stage V chunk: 1024x16B (rows 256B = 16 chunks)
#pragma unroll
    for (int i = 0; i < 2; ++i){
      const int cidx = i*512 + w*64 + lane;
      const int r = cidx >> 4, p = cidx & 15;
      gld16(vg + (size_t)r*T_ + sc*128 + ((p ^ (r & 7)) << 3),
            &Sb[(i*512 + w*64)*8]);
    }
    __syncthreads();                              // P + V visible
    const int vrow = (ws*16 + l16)*128;
#pragma unroll
    for (int grp = 0; grp < 4; ++grp){
      const int ch = (grp*4 + l4) ^ key;
      const f16x8 pa = ld8(&Pc[(qg*16 + l16)*128 + (ch << 3)]);
      const f16x8 vb = ld8(&Sb[vrow + (ch << 3)]);
      if (grp == 0)      oo0 = MFMA16(pa, vb, oo0, 0,0,0);
      else if (grp == 1) oo1 = MFMA16(pa, vb, oo1, 0,0,0);
      else if (grp == 2) oo2 = MFMA16(pa, vb, oo2, 0,0,0);
      else               oo3 = MFMA16(pa, vb, oo3, 0,0,0);
    }
    // edge gather for ids in this s-chunk: plain per-head store
    if ((g_id0 >> 7) == sc){
      const int r = g_r0;
      const float lr = red[1][r >> 4][0][r & 15] + red[1][r >> 4][1][r & 15]
                     + red[1][r >> 4][2][r & 15] + red[1][r >> 4][3][r & 15];
      const int sl = g_id0 & 127;
      const float pv = (float)Pc[r*128 + ((((sl >> 3) ^ (r & 7)) << 3) | (sl & 7))];
      gpart[((size_t)bh*T_ + t0 + r)*KN + g_kk0] = pv/lr*0.125f;
    }
    if (g_id1 >= 0 && (g_id1 >> 7) == sc){
      const int r = g_r1;
      const float lr = red[1][r >> 4][0][r & 15] + red[1][r >> 4][1][r & 15]
                     + red[1][r >> 4][2][r & 15] + red[1][r >> 4][3][r & 15];
      const int sl = g_id1 & 127;
      const float pv = (float)Pc[r*128 + ((((sl >> 3) ^ (r & 7)) << 3) | (sl & 7))];
      gpart[((size_t)bh*T_ + t0 + r)*KN + g_kk1] = pv/lr*0.125f;
    }
  }
  const f32x4 o = (oo0 + oo1) + (oo2 + oo3);

#pragma unroll
  for (int j = 0; j < 4; ++j){
    const int row = l4*4 + j;
    const float lr = red[1][qg][0][row] + red[1][qg][1][row]
                   + red[1][qg][2][row] + red[1][qg][3][row];
    const int t = t0 + qg*16 + row;
    X2[((size_t)(bi*T_ + t))*640 + h*HD_ + ws*16 + l16] = (f16)(o[j]/lr);
  }
}

// ---------------- edge: weighted neighbor-embedding mean -------------------
// g[b,t,kk] = sum_h gpart[(b*H+h), t, kk]
__global__ __launch_bounds__(128) void edge_kernel(
    const float* __restrict__ gpart, const float* __restrict__ E, f16* __restrict__ X2)
{
  __shared__ float gl[KN];
  __shared__ float ginv;
  const int bt = blockIdx.x;          // b*T + t
  const int bi = bt >> 10, tt = bt & 1023;
  const int t = threadIdx.x;
  if (t < KN){
    float s = 0.f;
#pragma unroll
    for (int hh = 0; hh < H_; ++hh)
      s += gpart[((size_t)(bi*H_ + hh)*T_ + tt)*KN + t];
    gl[t] = s;
  }
  __syncthreads();
  if (t == 0){
    float s = 0.f;
#pragma unroll
    for (int i = 0; i < KN; ++i) s += gl[i];
    ginv = 1.0f/(s + 1e-6f);
  }
  __syncthreads();
  float acc = 0.f;
  const float* Ep = E + (size_t)bt*KN*ED_ + t;
#pragma unroll 5
  for (int kk = 0; kk < KN; ++kk) acc += gl[kk]*Ep[(size_t)kk*ED_];
  X2[(size_t)bt*640 + 512 + t] = (f16)(acc*ginv);
}

// ---------------- LayerNorm helpers ----------------------------------------
__device__ __forceinline__ float block_sum(float v, float* sbuf){
  for (int o = 32; o; o >>= 1) v += __shfl_down(v, o);
  __syncthreads();
  if ((threadIdx.x & 63) == 0) sbuf[threadIdx.x >> 6] = v;
  __syncthreads();
  return sbuf[0]+sbuf[1]+sbuf[2]+sbuf[3];
}

__global__ __launch_bounds__(256) void ln1_kernel(
    const float* __restrict__ hV, const float* __restrict__ hraw,
    const float* __restrict__ gn, const float* __restrict__ bn,
    float* __restrict__ hf, f16* __restrict__ hh)
{
  __shared__ float sbuf[4];
  const int r = blockIdx.x, t = threadIdx.x;
  const size_t base = (size_t)r*D_;
  float x0 = hV[base+t]     + hraw[base+t];
  float x1 = hV[base+t+256] + hraw[base+t+256];
  float s = block_sum(x0+x1, sbuf);
  const float mean = s*(1.f/512.f);
  float d0 = x0-mean, d1 = x1-mean;
  float vs = block_sum(d0*d0+d1*d1, sbuf);
  const float rstd = rsqrtf(vs*(1.f/512.f) + 1e-5f);
  float y0 = d0*rstd*gn[t]     + bn[t];
  float y1 = d1*rstd*gn[t+256] + bn[t+256];
  hf[base+t]     = y0;  hh[base+t]     = (f16)y0;
  hf[base+t+256] = y1;  hh[base+t+256] = (f16)y1;
}

__global__ __launch_bounds__(256) void final_kernel(
    const float* __restrict__ hf, const float* __restrict__ ffr,
    const float* __restrict__ gf, const float* __restrict__ bfv,
    const float* __restrict__ g2, const float* __restrict__ b2,
    float* __restrict__ out)
{
  __shared__ float sbuf[4];
  const int r = blockIdx.x, t = threadIdx.x;
  const size_t base = (size_t)r*D_;
  const float h0 = hf[base+t], h1 = hf[base+t+256];
  float x0 = h0 + ffr[base+t], x1 = h1 + ffr[base+t+256];
  float s = block_sum(x0+x1, sbuf);
  float mean = s*(1.f/512.f);
  float d0 = x0-mean, d1 = x1-mean;
  float vs = block_sum(d0*d0+d1*d1, sbuf);
  float rstd = rsqrtf(vs*(1.f/512.f) + 1e-6f);
  const float dh0 = d0*rstd*gf[t]     + bfv[t];
  const float dh1 = d1*rstd*gf[t+256] + bfv[t+256];
  const float y0 = h0 + dh0, y1 = h1 + dh1;
  s = block_sum(y0+y1, sbuf);
  mean = s*(1.f/512.f);
  d0 = y0-mean; d1 = y1-mean;
  vs = block_sum(d0*d0+d1*d1, sbuf);
  rstd = rsqrtf(vs*(1.f/512.f) + 1e-5f);
  out[base+t]     = d0*rstd*g2[t]     + b2[t];
  out[base+t+256] = d1*rstd*g2[t+256] + b2[t+256];
}

// ---------------------------------------------------------------------------
extern "C" void kernel_launch(void* const* d_in, const int* in_sizes, int n_in,
                              void* d_out, int out_size, void* d_ws, size_t ws_size,
                              hipStream_t stream)
{
  (void)in_sizes; (void)n_in; (void)out_size;
  const float* h_V  = (const float*)d_in[0];
  const float* kin  = (const float*)d_in[1];
  const float* vin  = (const float*)d_in[2];
  const float* E    = (const float*)d_in[3];
  const float* bias = (const float*)d_in[4];
  const float* Wq   = (const float*)d_in[5];
  const float* bq   = (const float*)d_in[6];
  const float* Wk   = (const float*)d_in[7];
  const float* bk   = (const float*)d_in[8];
  const float* Wv   = (const float*)d_in[9];
  const float* bv   = (const float*)d_in[10];
  const float* Wo   = (const float*)d_in[11];
  const float* bo   = (const float*)d_in[12];
  const float* tsc  = (const float*)d_in[13];
  const float* gn   = (const float*)d_in[14];
  const float* bn   = (const float*)d_in[15];
  const float* w1   = (const float*)d_in[16];
  const float* bw1  = (const float*)d_in[17];
  const float* w2   = (const float*)d_in[18];
  const float* bw2  = (const float*)d_in[19];
  const float* gf   = (const float*)d_in[20];
  const float* bfv  = (const float*)d_in[21];
  const float* g2   = (const float*)d_in[22];
  const float* b2   = (const float*)d_in[23];
  const int*   Eidx = (const int*)d_in[24];
  const int*   mask = (const int*)d_in[25];
  float* out = (float*)d_out;

  char* wsb = (char*)d_ws;
  size_t off = 0;
  auto alloc = [&](size_t bytes) -> void* {
    void* pp = wsb + off; off += (bytes + 255) & ~(size_t)255; return pp;
  };
  f16* hVb  = (f16*)alloc((size_t)M_*D_*2);
  f16* kbI  = (f16*)alloc((size_t)M_*D_*2);
  f16* vbI  = (f16*)alloc((size_t)M_*D_*2);
  f16* Wqb  = (f16*)alloc((size_t)D_*D_*2);
  f16* Wkb  = (f16*)alloc((size_t)D_*D_*2);
  f16* Wvb  = (f16*)alloc((size_t)D_*D_*2);
  f16* Wob  = (f16*)alloc((size_t)D_*(D_+ED_)*2);
  f16* w1b  = (f16*)alloc((size_t)DFF_*D_*2);
  f16* w2b  = (f16*)alloc((size_t)D_*DFF_*2);
  f16* qb   = (f16*)alloc((size_t)M_*D_*2);
  f16* kb   = (f16*)alloc((size_t)M_*D_*2);
  f16* vT   = (f16*)alloc((size_t)M_*D_*2);
  f16* biasP= (f16*)alloc((size_t)B_*T_*T_*2);
  f16* X2   = (f16*)alloc((size_t)M_*640*2);
  float* gpart = (float*)alloc((size_t)BH_*T_*KN*4);
  float* hraw = (float*)alloc((size_t)M_*D_*4);   // reused as ffraw
  float* hf   = (float*)alloc((size_t)M_*D_*4);
  f16*   hh   = (f16*)alloc((size_t)M_*D_*2);
  f16*   ff1  = (f16*)alloc((size_t)M_*DFF_*2);
  if (ws_size < off) return;  // scratch insufficient -> loud validation failure
  float* ffraw = hraw;

  // 1) converts fp32 -> f16 (one launch) + bias prep
  {
    CvtJobs J;
    const float* srcs[9] = {h_V, kin, vin, Wq, Wk, Wv, Wo, w1, w2};
    f16* dsts[9] = {hVb, kbI, vbI, Wqb, Wkb, Wvb, Wob, w1b, w2b};
    const int n4s[9] = {M_*D_/4, M_*D_/4, M_*D_/4, D_*D_/4, D_*D_/4, D_*D_/4,
                        D_*(D_+ED_)/4, DFF_*D_/4, D_*DFF_/4};
    int cum = 0;
    for (int i = 0; i < 9; ++i){
      J.s[i] = srcs[i]; J.d[i] = dsts[i]; J.start[i] = cum;
      cum += n4s[i]/256;
    }
    J.start[9] = cum;
    cvt9_kernel<<<cum,256,0,stream>>>(J);
  }
  biasprep_kernel<<<B_*T_*T_/8/256,256,0,stream>>>(bias, mask, tsc, biasP);

  // 2) batched q/k/v projections (q pre-scaled for exp2 softmax; v -> vT)
  qkv_tile<<<384,256,0,stream>>>(hVb, kbI, vbI, Wqb, Wkb, Wvb, bq, bk, bv, tsc, qb, kb, vT);

  // 3) fused attention (QK^T + softmax + PV + edge gather), QBLK=32, 512 thr
  attn_fused<<<1024,512,0,stream>>>(qb, kb, vT, biasP, Eidx, X2, gpart);

  // 4) edge embedding (sums 8 per-head partials)
  edge_kernel<<<M_,128,0,stream>>>(gpart, E, X2);

  // 5) out-proj (128x64 tiles, BK=64) + residual LN
  gemm_n64<2><<<256,256,0,stream>>>(X2, Wob, bo, hraw, D_+ED_, D_, 8);
  ln1_kernel<<<M_,256,0,stream>>>(h_V, hraw, gn, bn, hf, hh);

  // 6) FFN: FF1 128x128 BK=64 (512 blocks), FF2 128x64 BK=64 (256 blocks)
  gemm_tile<1><<<512,256,0,stream>>>(hh, w1b, bw1, ff1, D_, DFF_, 16);
  gemm_n64<2><<<256,256,0,stream>>>(ff1, w2b, bw2, ffraw, DFF_, D_, 8);

  // 7) final double-LN
  final_kernel<<<M_,256,0,stream>>>(hf, ffraw, gf, bfv, g2, b2, out);
}

// Round 13
// 168.052 us; speedup vs baseline: 1.5694x; 1.0115x over previous
//
#include <hip/hip_runtime.h>
#include <hip/hip_fp16.h>
#include <math.h>

#define B_ 4
#define T_ 1024
#define D_ 512
#define H_ 8
#define HD_ 64
#define KN 30
#define ED_ 128
#define DFF_ 2048
#define M_ 4096   // B*T
#define BH_ 32

typedef _Float16 f16;
typedef __attribute__((ext_vector_type(8))) _Float16 f16x8;
typedef __attribute__((ext_vector_type(4))) _Float16 f16x4;
typedef __attribute__((ext_vector_type(4))) float f32x4;

#define MFMA16 __builtin_amdgcn_mfma_f32_16x16x32_f16
#define LOG2E 1.44269504088896f

__device__ __forceinline__ f16x8 ld8(const f16* p){ return *reinterpret_cast<const f16x8*>(p); }

__device__ __forceinline__ void gld16(const void* g, void* l){
  __builtin_amdgcn_global_load_lds((const __attribute__((address_space(1))) void*)g,
                                   (__attribute__((address_space(3))) void*)l, 16, 0, 0);
}

// ---------------- combined fp32 -> fp16 convert (9 tensors, 1 launch) -------
struct CvtJobs {
  const float* s[9];
  f16* d[9];
  int start[10];   // cumulative block starts; each block = 256 float4s
};

__global__ __launch_bounds__(256) void cvt9_kernel(CvtJobs J){
  const int blk = blockIdx.x;
  int j = 0;
  while (j < 8 && blk >= J.start[j+1]) ++j;
  const int i = (blk - J.start[j])*256 + threadIdx.x;
  float4 v = reinterpret_cast<const float4*>(J.s[j])[i];
  union { f16 h[4]; ushort4 u; } o;
  o.h[0]=(f16)v.x; o.h[1]=(f16)v.y; o.h[2]=(f16)v.z; o.h[3]=(f16)v.w;
  reinterpret_cast<ushort4*>(J.d[j])[i] = o.u;
}

// ---------------- bias prep: wave-fragment-tiled biasT ---------------------
// biasT granule G = ((((bi*32+tb)*8+c)*4+ws)*2+step)*2+qg, 256 f16 each,
// inner layout [l16][l4][j]: lane (l4,l16) of wave (qg,ws) at (c,step) reads
// its f16x4 at G*256 + l16*16 + l4*4 -> 512B coalesced per wave, no LDS.
__global__ __launch_bounds__(256) void biasprep_kernel(
    const float* __restrict__ bias, const int* __restrict__ mask,
    const float* __restrict__ tsc, f16* __restrict__ biasT)
{
  const int TT = blockIdx.x*256 + threadIdx.x;   // 262144 threads
  const int G = TT >> 4, l16 = TT & 15;
  const int qg = G & 1, step = (G >> 1) & 1, ws = (G >> 2) & 3;
  const int c = (G >> 4) & 7, tb = (G >> 7) & 31, bi = G >> 12;
  const float s = exp2f(-2.0f*tanhf(tsc[0]))*LOG2E;  // log2e / 4^tanh(t)
  const int t  = tb*32 + qg*16 + l16;
  const int s0 = c*128 + ws*32 + step*16;
  const float* bp = bias + ((size_t)bi*T_ + t)*T_ + s0;
  const int*   mp = mask + bi*T_ + s0;
  union { f16 h[16]; f16x8 v8[2]; } o;
#pragma unroll
  for (int i = 0; i < 16; i += 4){
    float4 v = *reinterpret_cast<const float4*>(bp + i);
    int4  mm = *reinterpret_cast<const int4*>(mp + i);
    float x[4] = {v.x,v.y,v.z,v.w};
    int  m4[4] = {mm.x,mm.y,mm.z,mm.w};
#pragma unroll
    for (int j = 0; j < 4; ++j){
      float tv = (x[j] + (m4[j] ? 0.f : -60000.f))*s;
      o.h[i+j] = (f16)fmaxf(tv, -60000.f);
    }
  }
  f16* op = biasT + (size_t)G*256 + l16*16;
  reinterpret_cast<f16x8*>(op)[0] = o.v8[0];
  reinterpret_cast<f16x8*>(op)[1] = o.v8[1];
}

// =============== staged MFMA GEMM: C = X @ W.T, BK=64, XOR-swizzled =========
template<int EPI>
__global__ __launch_bounds__(256,2) void gemm_tile(
    const f16* __restrict__ X, const f16* __restrict__ W,
    const float* __restrict__ bias, void* __restrict__ outp,
    int Kd, int ldo, int nbN)
{
  __shared__ f16 As[128*64];
  __shared__ f16 Bs[128*64];
  const int nwg = gridDim.x;
  const int bid = blockIdx.x;
  const int swz = (bid & 7)*(nwg >> 3) + (bid >> 3);
  const int mb = swz / nbN, nb = swz - mb*nbN;
  const int rb = mb*128, cb = nb*128;
  const int tid = threadIdx.x;
  const int w = tid >> 6, lane = tid & 63;
  const int l16 = lane & 15, l4 = lane >> 4;
  const int wr = w >> 1, wc = w & 1;
  const int key = l16 & 7;

  f32x4 acc[4][4];
#pragma unroll
  for (int m = 0; m < 4; ++m)
#pragma unroll
    for (int n = 0; n < 4; ++n) acc[m][n] = (f32x4){0.f,0.f,0.f,0.f};

  for (int k0 = 0; k0 < Kd; k0 += 64){
#pragma unroll
    for (int i = 0; i < 4; ++i){
      const int cidx = i*256 + w*64 + lane;
      const int r = cidx >> 3, p = cidx & 7;
      gld16(X + (size_t)(rb + r)*Kd + k0 + ((p ^ (r & 7)) << 3),
            &As[(i*256 + w*64)*8]);
      gld16(W + (size_t)(cb + r)*Kd + k0 + ((p ^ (r & 7)) << 3),
            &Bs[(i*256 + w*64)*8]);
    }
    __syncthreads();
#pragma unroll
    for (int kk = 0; kk < 2; ++kk){
      f16x8 a[4], b[4];
#pragma unroll
      for (int m = 0; m < 4; ++m)
        a[m] = ld8(&As[(wr*64 + m*16 + l16)*64 + (((kk*4 + l4) ^ key) << 3)]);
#pragma unroll
      for (int n = 0; n < 4; ++n)
        b[n] = ld8(&Bs[(wc*64 + n*16 + l16)*64 + (((kk*4 + l4) ^ key) << 3)]);
#pragma unroll
      for (int m = 0; m < 4; ++m)
#pragma unroll
        for (int n = 0; n < 4; ++n)
          acc[m][n] = MFMA16(a[m], b[n], acc[m][n], 0,0,0);
    }
    __syncthreads();
  }

#pragma unroll
  for (int n = 0; n < 4; ++n){
    const int col = cb + wc*64 + n*16 + l16;
    const float bv = bias[col];
#pragma unroll
    for (int m = 0; m < 4; ++m){
#pragma unroll
      for (int j = 0; j < 4; ++j){
        const int row = rb + wr*64 + m*16 + l4*4 + j;
        float v = acc[m][n][j] + bv;
        if (EPI == 1){
          v = 0.5f*v*(1.0f + erff(v*0.70710678118654752f));
          ((f16*)outp)[(size_t)row*ldo + col] = (f16)v;
        } else {
          ((float*)outp)[(size_t)row*ldo + col] = v;
        }
      }
    }
  }
}

// =============== 128x64-tile GEMM, BK=64, XOR-swizzled ======================
template<int EPI>
__global__ __launch_bounds__(256,2) void gemm_n64(
    const f16* __restrict__ X, const f16* __restrict__ W,
    const float* __restrict__ bias, void* __restrict__ outp,
    int Kd, int ldo, int nbN)
{
  __shared__ f16 As[128*64];
  __shared__ f16 Bs[64*64];
  const int nwg = gridDim.x;
  const int bid = blockIdx.x;
  const int swz = (bid & 7)*(nwg >> 3) + (bid >> 3);
  const int mb = swz / nbN, nb = swz - mb*nbN;
  const int rb = mb*128, cb = nb*64;
  const int tid = threadIdx.x;
  const int w = tid >> 6, lane = tid & 63;
  const int l16 = lane & 15, l4 = lane >> 4;
  const int wr = w >> 1, wc = w & 1;
  const int key = l16 & 7;

  f32x4 acc[4][2];
#pragma unroll
  for (int m = 0; m < 4; ++m)
#pragma unroll
    for (int n = 0; n < 2; ++n) acc[m][n] = (f32x4){0.f,0.f,0.f,0.f};

  for (int k0 = 0; k0 < Kd; k0 += 64){
#pragma unroll
    for (int i = 0; i < 4; ++i){
      const int cidx = i*256 + w*64 + lane;
      const int r = cidx >> 3, p = cidx & 7;
      gld16(X + (size_t)(rb + r)*Kd + k0 + ((p ^ (r & 7)) << 3),
            &As[(i*256 + w*64)*8]);
    }
#pragma unroll
    for (int i = 0; i < 2; ++i){
      const int cidx = i*256 + w*64 + lane;
      const int r = cidx >> 3, p = cidx & 7;
      gld16(W + (size_t)(cb + r)*Kd + k0 + ((p ^ (r & 7)) << 3),
            &Bs[(i*256 + w*64)*8]);
    }
    __syncthreads();
#pragma unroll
    for (int kk = 0; kk < 2; ++kk){
      f16x8 a[4], b[2];
#pragma unroll
      for (int m = 0; m < 4; ++m)
        a[m] = ld8(&As[(wr*64 + m*16 + l16)*64 + (((kk*4 + l4) ^ key) << 3)]);
#pragma unroll
      for (int n = 0; n < 2; ++n)
        b[n] = ld8(&Bs[(wc*32 + n*16 + l16)*64 + (((kk*4 + l4) ^ key) << 3)]);
#pragma unroll
      for (int m = 0; m < 4; ++m)
#pragma unroll
        for (int n = 0; n < 2; ++n)
          acc[m][n] = MFMA16(a[m], b[n], acc[m][n], 0,0,0);
    }
    __syncthreads();
  }

#pragma unroll
  for (int n = 0; n < 2; ++n){
    const int col = cb + wc*32 + n*16 + l16;
    const float bv = bias[col];
#pragma unroll
    for (int m = 0; m < 4; ++m){
#pragma unroll
      for (int j = 0; j < 4; ++j){
        const int row = rb + wr*64 + m*16 + l4*4 + j;
        float v = acc[m][n][j] + bv;
        if (EPI == 1){
          v = 0.5f*v*(1.0f + erff(v*0.70710678118654752f));
          ((f16*)outp)[(size_t)row*ldo + col] = (f16)v;
        } else {
          ((float*)outp)[(size_t)row*ldo + col] = v;
        }
      }
    }
  }
}

// =============== batched QKV projection (one launch, 3 GEMMs) ===============
__global__ __launch_bounds__(256,2) void qkv_tile(
    const f16* __restrict__ hV, const f16* __restrict__ kI, const f16* __restrict__ vI,
    const f16* __restrict__ Wq, const f16* __restrict__ Wk, const f16* __restrict__ Wv,
    const float* __restrict__ bq, const float* __restrict__ bk, const float* __restrict__ bv,
    const float* __restrict__ tsc,
    f16* __restrict__ qo, f16* __restrict__ ko, f16* __restrict__ vT)
{
  __shared__ f16 As[128*32];
  __shared__ f16 Bs[128*32];
  const int bid = blockIdx.x;
  const int swz = (bid & 7)*48 + (bid >> 3);
  const int g = swz >> 7;
  const int r = swz & 127;
  const int mb = r >> 2, nb = r & 3;
  const f16* X  = (g == 0) ? hV : ((g == 1) ? kI : vI);
  const f16* W  = (g == 0) ? Wq : ((g == 1) ? Wk : Wv);
  const float* bias = (g == 0) ? bq : ((g == 1) ? bk : bv);
  const int rb = mb*128, cb = nb*128;
  const int tid = threadIdx.x;
  const int w = tid >> 6, lane = tid & 63;
  const int l16 = lane & 15, l4 = lane >> 4;
  const int wr = w >> 1, wc = w & 1;
  const int sr = lane >> 2, sc = (lane & 3)*8;
  const f16* Ax0 = X + (size_t)(rb + w*16 + sr)*D_ + sc;
  const f16* Ax1 = X + (size_t)(rb + 64 + w*16 + sr)*D_ + sc;
  const f16* Bx0 = W + (size_t)(cb + w*16 + sr)*D_ + sc;
  const f16* Bx1 = W + (size_t)(cb + 64 + w*16 + sr)*D_ + sc;
  f16* Ad0 = &As[(w*16)*32];
  f16* Ad1 = &As[(64 + w*16)*32];
  f16* Bd0 = &Bs[(w*16)*32];
  f16* Bd1 = &Bs[(64 + w*16)*32];

  f32x4 acc[4][4];
#pragma unroll
  for (int m = 0; m < 4; ++m)
#pragma unroll
    for (int n = 0; n < 4; ++n) acc[m][n] = (f32x4){0.f,0.f,0.f,0.f};

  for (int k0 = 0; k0 < D_; k0 += 32){
    gld16(Ax0 + k0, Ad0);
    gld16(Ax1 + k0, Ad1);
    gld16(Bx0 + k0, Bd0);
    gld16(Bx1 + k0, Bd1);
    __syncthreads();
    f16x8 a[4], b[4];
#pragma unroll
    for (int m = 0; m < 4; ++m) a[m] = ld8(&As[(wr*64 + m*16 + l16)*32 + l4*8]);
#pragma unroll
    for (int n = 0; n < 4; ++n) b[n] = ld8(&Bs[(wc*64 + n*16 + l16)*32 + l4*8]);
#pragma unroll
    for (int m = 0; m < 4; ++m)
#pragma unroll
      for (int n = 0; n < 4; ++n)
        acc[m][n] = MFMA16(a[m], b[n], acc[m][n], 0,0,0);
    __syncthreads();
  }

  const float qs = exp2f(-2.0f*tanhf(tsc[0]))*LOG2E*0.125f;
  const float scale = (g == 0) ? qs : 1.0f;
  f16* out = (g == 0) ? qo : ko;
#pragma unroll
  for (int n = 0; n < 4; ++n){
    const int col = cb + wc*64 + n*16 + l16;
    const float bv = bias[col];
#pragma unroll
    for (int m = 0; m < 4; ++m){
#pragma unroll
      for (int j = 0; j < 4; ++j){
        const int row = rb + wr*64 + m*16 + l4*4 + j;
        const float v = (acc[m][n][j] + bv)*scale;
        if (g < 2){
          out[(size_t)row*D_ + col] = (f16)v;
        } else {
          const int b = row >> 10, t = row & (T_-1);
          const int h = col >> 6,  dl = col & (HD_-1);
          vT[(((size_t)b*H_ + h)*HD_ + dl)*T_ + t] = (f16)v;
        }
      }
    }
  }
}

// =============== fused attention (QBLK=32, pipelined, counted vmcnt) ========
// 8 waves: qg=w>>2 owns q-group, ws=w&3 owns s-subrange / d-cols.
// K/V chunks double-buffered in one 32KB region; per phase: stage next chunk,
// s_waitcnt vmcnt(2) (never 0 mid-loop) + raw s_barrier -> loads stay in
// flight across barriers. Bias read directly from coalesced biasT (no LDS).
// Cross-wave softmax stats overlay idle Sb; row-sums redistributed via shfl.
// LDS = 32KB + 8KB P = 40960 B -> 4 blocks/CU.
__global__ __launch_bounds__(512,4) void attn_fused(
    const f16* __restrict__ q, const f16* __restrict__ k, const f16* __restrict__ vT,
    const f16* __restrict__ biasT, const int* __restrict__ eidx,
    f16* __restrict__ X2, float* __restrict__ gpart)
{
  __shared__ f16 Sb[16384];       // 32 KB: K/V chunk double buffer (2 x 8192)
  __shared__ f16 Pc[32*128];      // 8 KB: P chunk [32 q][128 s]
  const int bid = blockIdx.x;
  const int swz = (bid & 7)*128 + (bid >> 3);   // XCD-contiguous
  const int bh = swz >> 5, tb = swz & 31;
  const int bi = bh >> 3, h = bh & 7;
  const int t0 = tb*32;
  const int tid = threadIdx.x, w = tid >> 6, lane = tid & 63;
  const int qg = w >> 2, ws = w & 3;
  const int l16 = lane & 15, l4 = lane >> 4;
  const int key = l16 & 7;

  // ---- Q fragments ----
  const f16* qp = q + (size_t)(bi*T_ + t0 + qg*16 + l16)*D_ + h*HD_ + l4*8;
  const f16x8 q0 = ld8(qp), q1 = ld8(qp + 32);
  // ---- gather tuples: each tid handles items of its own qg half ----
  const int tl = tid & 255;
  int ga_r, ga_kk, ga_id, gb_r = 0, gb_kk = 0, gb_id = -1;
  ga_r = tl/KN; ga_kk = tl - ga_r*KN;
  ga_id = eidx[((size_t)(bi*T_ + t0 + qg*16 + ga_r))*KN + ga_kk];
  if (tl + 256 < 16*KN){
    gb_r = (tl+256)/KN; gb_kk = (tl+256) - gb_r*KN;
    gb_id = eidx[((size_t)(bi*T_ + t0 + qg*16 + gb_r))*KN + gb_kk];
  }

  const f16* kg = k + (size_t)(bi*T_)*D_ + h*HD_;
  const f16* vg = vT + (size_t)bh*HD_*T_;
  const f16* bb = biasT + (size_t)(bi*32 + tb)*32768 + ws*1024 + qg*256 + l16*16 + l4*4;

  auto stageK = [&](int c, int slot){
#pragma unroll
    for (int i = 0; i < 2; ++i){
      const int cidx = i*512 + w*64 + lane;
      const int r = cidx >> 3, p = cidx & 7;
      gld16(kg + (size_t)(c*128 + r)*D_ + ((p ^ (r & 7)) << 3),
            &Sb[slot*8192 + (i*512 + w*64)*8]);
    }
  };
  auto stageV = [&](int sc, int slot){
#pragma unroll
    for (int i = 0; i < 2; ++i){
      const int cidx = i*512 + w*64 + lane;
      const int r = cidx >> 4, p = cidx & 15;
      gld16(vg + (size_t)r*T_ + sc*128 + ((p ^ (r & 7)) << 3),
            &Sb[slot*8192 + (i*512 + w*64)*8]);
    }
  };

  // ---- QK^T: 8 chunks of 128 s, ping-pong + counted vmcnt ----
  f32x4 acc[16];
  stageK(0, 0);
#pragma unroll
  for (int c = 0; c < 8; ++c){
    if (c < 7) stageK(c+1, (c+1)&1);
    if (c < 7) asm volatile("s_waitcnt vmcnt(2)" ::: "memory");
    else       asm volatile("s_waitcnt vmcnt(0)" ::: "memory");
    __builtin_amdgcn_sched_barrier(0);
    __builtin_amdgcn_s_barrier();
    __builtin_amdgcn_sched_barrier(0);
    const int base = (c&1)*8192;
#pragma unroll
    for (int step = 0; step < 2; ++step){
      const int rr = ws*32 + step*16 + l16;
      f32x4 a = {0.f,0.f,0.f,0.f};
      a = MFMA16(ld8(&Sb[base + rr*64 + ((l4 ^ key) << 3)]),       q0, a, 0,0,0);
      a = MFMA16(ld8(&Sb[base + rr*64 + (((4 + l4) ^ key) << 3)]), q1, a, 0,0,0);
      const f16x4 bf = *reinterpret_cast<const f16x4*>(bb + c*4096 + step*512);
#pragma unroll
      for (int j = 0; j < 4; ++j) a[j] += (float)bf[j];
      acc[c*2 + step] = a;
    }
    __builtin_amdgcn_s_barrier();   // readers of slot (c&1) done
  }

  // ---- softmax (stats overlay on idle Sb; sums redistributed via shfl) ----
  float* redf = (float*)Sb;         // [0..127]=max, [128..255]=sum
  float m = -3.4e38f;
#pragma unroll
  for (int c = 0; c < 16; ++c)
#pragma unroll
    for (int j = 0; j < 4; ++j) m = fmaxf(m, acc[c][j]);
  m = fmaxf(m, __shfl_xor(m, 16));
  m = fmaxf(m, __shfl_xor(m, 32));
  if (lane < 16) redf[(qg*4 + ws)*16 + lane] = m;
  __syncthreads();
  m = fmaxf(fmaxf(redf[(qg*4+0)*16 + l16], redf[(qg*4+1)*16 + l16]),
            fmaxf(redf[(qg*4+2)*16 + l16], redf[(qg*4+3)*16 + l16]));
  float l = 0.f;
#pragma unroll
  for (int c = 0; c < 16; ++c)
#pragma unroll
    for (int j = 0; j < 4; ++j){
      const float e = exp2f(acc[c][j] - m);
      l += e;
      acc[c][j] = e;                // acc now holds unnormalized P
    }
  l += __shfl_xor(l, 16);
  l += __shfl_xor(l, 32);
  if (lane < 16) redf[128 + (qg*4 + ws)*16 + lane] = l;
  __syncthreads();
  const float lrq = redf[128 + (qg*4+0)*16 + l16] + redf[128 + (qg*4+1)*16 + l16]
                  + redf[128 + (qg*4+2)*16 + l16] + redf[128 + (qg*4+3)*16 + l16];
  __syncthreads();                  // all lrq reads done before V staging clobbers
  const float lr_a = __shfl(lrq, ga_r);
  const float lr_b = __shfl(lrq, gb_r);

  // ---- PV: 8 chunks, V ping-pong + counted vmcnt; P single-buffered ----
  f32x4 oo0 = {0.f,0.f,0.f,0.f}, oo1 = oo0, oo2 = oo0, oo3 = oo0;
  stageV(0, 0);
#pragma unroll
  for (int sc = 0; sc < 8; ++sc){
    // write own P slice for chunk sc (Pc free: prior readers barrier'd)
#pragma unroll
    for (int step = 0; step < 2; ++step){
      const int slb = ws*32 + step*16 + l4*4;
      f16x4 pp;
#pragma unroll
      for (int j = 0; j < 4; ++j) pp[j] = (f16)acc[sc*2 + step][j];
      *reinterpret_cast<f16x4*>(
          &Pc[(qg*16 + l16)*128 + (((slb >> 3) ^ key) << 3) + (slb & 7)]) = pp;
    }
    if (sc < 7) stageV(sc+1, (sc+1)&1);
    if (sc < 7) asm volatile("s_waitcnt vmcnt(2) lgkmcnt(0)" ::: "memory");
    else        asm volatile("s_waitcnt vmcnt(0) lgkmcnt(0)" ::: "memory");
    __builtin_amdgcn_sched_barrier(0);
    __builtin_amdgcn_s_barrier();
    __builtin_amdgcn_sched_barrier(0);
    const int base = (sc&1)*8192;
    const int vrow = (ws*16 + l16)*128;
#pragma unroll
    for (int grp = 0; grp < 4; ++grp){
      const int ch = (grp*4 + l4) ^ key;
      const f16x8 pa = ld8(&Pc[(qg*16 + l16)*128 + (ch << 3)]);
      const f16x8 vb = ld8(&Sb[base + vrow + (ch << 3)]);
      if (grp == 0)      oo0 = MFMA16(pa, vb, oo0, 0,0,0);
      else if (grp == 1) oo1 = MFMA16(pa, vb, oo1, 0,0,0);
      else if (grp == 2) oo2 = MFMA16(pa, vb, oo2, 0,0,0);
      else               oo3 = MFMA16(pa, vb, oo3, 0,0,0);
    }
    // edge gather (own qg rows; plain per-head stores)
    if ((ga_id >> 7) == sc){
      const int r = qg*16 + ga_r;
      const int sl = ga_id & 127;
      const float pv = (float)Pc[r*128 + ((((sl >> 3) ^ (r & 7)) << 3) | (sl & 7))];
      gpart[((size_t)bh*T_ + t0 + r)*KN + ga_kk] = pv/lr_a*0.125f;
    }
    if (gb_id >= 0 && (gb_id >> 7) == sc){
      const int r = qg*16 + gb_r;
      const int sl = gb_id & 127;
      const float pv = (float)Pc[r*128 + ((((sl >> 3) ^ (r & 7)) << 3) | (sl & 7))];
      gpart[((size_t)bh*T_ + t0 + r)*KN + gb_kk] = pv/lr_b*0.125f;
    }
    __builtin_amdgcn_s_barrier();   // readers of Pc + V slot (sc&1) done
  }
  const f32x4 o = (oo0 + oo1) + (oo2 + oo3);

#pragma unroll
  for (int j = 0; j < 4; ++j){
    const float lr = __shfl(lrq, l4*4 + j);
    const int t = t0 + qg*16 + l4*4 + j;
    X2[((size_t)(bi*T_ + t))*640 + h*HD_ + ws*16 + l16] = (f16)(o[j]/lr);
  }
}

// ---------------- edge: weighted neighbor-embedding mean -------------------
// g[b,t,kk] = sum_h gpart[(b*H+h), t, kk]
__global__ __launch_bounds__(128) void edge_kernel(
    const float* __restrict__ gpart, const float* __restrict__ E, f16* __restrict__ X2)
{
  __shared__ float gl[KN];
  __shared__ float ginv;
  const int bt = blockIdx.x;          // b*T + t
  const int bi = bt >> 10, tt = bt & 1023;
  const int t = threadIdx.x;
  if (t < KN){
    float s = 0.f;
#pragma unroll
    for (int hh = 0; hh < H_; ++hh)
      s += gpart[((size_t)(bi*H_ + hh)*T_ + tt)*KN + t];
    gl[t] = s;
  }
  __syncthreads();
  if (t == 0){
    float s = 0.f;
#pragma unroll
    for (int i = 0; i < KN; ++i) s += gl[i];
    ginv = 1.0f/(s + 1e-6f);
  }
  __syncthreads();
  float acc = 0.f;
  const float* Ep = E + (size_t)bt*KN*ED_ + t;
#pragma unroll 5
  for (int kk = 0; kk < KN; ++kk) acc += gl[kk]*Ep[(size_t)kk*ED_];
  X2[(size_t)bt*640 + 512 + t] = (f16)(acc*ginv);
}

// ---------------- LayerNorm helpers ----------------------------------------
__device__ __forceinline__ float block_sum(float v, float* sbuf){
  for (int o = 32; o; o >>= 1) v += __shfl_down(v, o);
  __syncthreads();
  if ((threadIdx.x & 63) == 0) sbuf[threadIdx.x >> 6] = v;
  __syncthreads();
  return sbuf[0]+sbuf[1]+sbuf[2]+sbuf[3];
}

__global__ __launch_bounds__(256) void ln1_kernel(
    const float* __restrict__ hV, const float* __restrict__ hraw,
    const float* __restrict__ gn, const float* __restrict__ bn,
    float* __restrict__ hf, f16* __restrict__ hh)
{
  __shared__ float sbuf[4];
  const int r = blockIdx.x, t = threadIdx.x;
  const size_t base = (size_t)r*D_;
  float x0 = hV[base+t]     + hraw[base+t];
  float x1 = hV[base+t+256] + hraw[base+t+256];
  float s = block_sum(x0+x1, sbuf);
  const float mean = s*(1.f/512.f);
  float d0 = x0-mean, d1 = x1-mean;
  float vs = block_sum(d0*d0+d1*d1, sbuf);
  const float rstd = rsqrtf(vs*(1.f/512.f) + 1e-5f);
  float y0 = d0*rstd*gn[t]     + bn[t];
  float y1 = d1*rstd*gn[t+256] + bn[t+256];
  hf[base+t]     = y0;  hh[base+t]     = (f16)y0;
  hf[base+t+256] = y1;  hh[base+t+256] = (f16)y1;
}

__global__ __launch_bounds__(256) void final_kernel(
    const float* __restrict__ hf, const float* __restrict__ ffr,
    const float* __restrict__ gf, const float* __restrict__ bfv,
    const float* __restrict__ g2, const float* __restrict__ b2,
    float* __restrict__ out)
{
  __shared__ float sbuf[4];
  const int r = blockIdx.x, t = threadIdx.x;
  const size_t base = (size_t)r*D_;
  const float h0 = hf[base+t], h1 = hf[base+t+256];
  float x0 = h0 + ffr[base+t], x1 = h1 + ffr[base+t+256];
  float s = block_sum(x0+x1, sbuf);
  float mean = s*(1.f/512.f);
  float d0 = x0-mean, d1 = x1-mean;
  float vs = block_sum(d0*d0+d1*d1, sbuf);
  float rstd = rsqrtf(vs*(1.f/512.f) + 1e-6f);
  const float dh0 = d0*rstd*gf[t]     + bfv[t];
  const float dh1 = d1*rstd*gf[t+256] + bfv[t+256];
  const float y0 = h0 + dh0, y1 = h1 + dh1;
  s = block_sum(y0+y1, sbuf);
  mean = s*(1.f/512.f);
  d0 = y0-mean; d1 = y1-mean;
  vs = block_sum(d0*d0+d1*d1, sbuf);
  rstd = rsqrtf(vs*(1.f/512.f) + 1e-5f);
  out[base+t]     = d0*rstd*g2[t]     + b2[t];
  out[base+t+256] = d1*rstd*g2[t+256] + b2[t+256];
}

// ---------------------------------------------------------------------------
extern "C" void kernel_launch(void* const* d_in, const int* in_sizes, int n_in,
                              void* d_out, int out_size, void* d_ws, size_t ws_size,
                              hipStream_t stream)
{
  (void)in_sizes; (void)n_in; (void)out_size;
  const float* h_V  = (const float*)d_in[0];
  const float* kin  = (const float*)d_in[1];
  const float* vin  = (const float*)d_in[2];
  const float* E    = (const float*)d_in[3];
  const float* bias = (const float*)d_in[4];
  const float* Wq   = (const float*)d_in[5];
  const float* bq   = (const float*)d_in[6];
  const float* Wk   = (const float*)d_in[7];
  const float* bk   = (const float*)d_in[8];
  const float* Wv   = (const float*)d_in[9];
  const float* bv   = (const float*)d_in[10];
  const float* Wo   = (const float*)d_in[11];
  const float* bo   = (const float*)d_in[12];
  const float* tsc  = (const float*)d_in[13];
  const float* gn   = (const float*)d_in[14];
  const float* bn   = (const float*)d_in[15];
  const float* w1   = (const float*)d_in[16];
  const float* bw1  = (const float*)d_in[17];
  const float* w2   = (const float*)d_in[18];
  const float* bw2  = (const float*)d_in[19];
  const float* gf   = (const float*)d_in[20];
  const float* bfv  = (const float*)d_in[21];
  const float* g2   = (const float*)d_in[22];
  const float* b2   = (const float*)d_in[23];
  const int*   Eidx = (const int*)d_in[24];
  const int*   mask = (const int*)d_in[25];
  float* out = (float*)d_out;

  char* wsb = (char*)d_ws;
  size_t off = 0;
  auto alloc = [&](size_t bytes) -> void* {
    void* pp = wsb + off; off += (bytes + 255) & ~(size_t)255; return pp;
  };
  f16* hVb  = (f16*)alloc((size_t)M_*D_*2);
  f16* kbI  = (f16*)alloc((size_t)M_*D_*2);
  f16* vbI  = (f16*)alloc((size_t)M_*D_*2);
  f16* Wqb  = (f16*)alloc((size_t)D_*D_*2);
  f16* Wkb  = (f16*)alloc((size_t)D_*D_*2);
  f16* Wvb  = (f16*)alloc((size_t)D_*D_*2);
  f16* Wob  = (f16*)alloc((size_t)D_*(D_+ED_)*2);
  f16* w1b  = (f16*)alloc((size_t)DFF_*D_*2);
  f16* w2b  = (f16*)alloc((size_t)D_*DFF_*2);
  f16* qb   = (f16*)alloc((size_t)M_*D_*2);
  f16* kb   = (f16*)alloc((size_t)M_*D_*2);
  f16* vT   = (f16*)alloc((size_t)M_*D_*2);
  f16* biasT= (f16*)alloc((size_t)B_*T_*T_*2);
  f16* X2   = (f16*)alloc((size_t)M_*640*2);
  float* gpart = (float*)alloc((size_t)BH_*T_*KN*4);
  float* hraw = (float*)alloc((size_t)M_*D_*4);   // reused as ffraw
  float* hf   = (float*)alloc((size_t)M_*D_*4);
  f16*   hh   = (f16*)alloc((size_t)M_*D_*2);
  f16*   ff1  = (f16*)alloc((size_t)M_*DFF_*2);
  if (ws_size < off) return;  // scratch insufficient -> loud validation failure
  float* ffraw = hraw;

  // 1) converts fp32 -> f16 (one launch) + bias prep (fragment-tiled biasT)
  {
    CvtJobs J;
    const float* srcs[9] = {h_V, kin, vin, Wq, Wk, Wv, Wo, w1, w2};
    f16* dsts[9] = {hVb, kbI, vbI, Wqb, Wkb, Wvb, Wob, w1b, w2b};
    const int n4s[9] = {M_*D_/4, M_*D_/4, M_*D_/4, D_*D_/4, D_*D_/4, D_*D_/4,
                        D_*(D_+ED_)/4, DFF_*D_/4, D_*DFF_/4};
    int cum = 0;
    for (int i = 0; i < 9; ++i){
      J.s[i] = srcs[i]; J.d[i] = dsts[i]; J.start[i] = cum;
      cum += n4s[i]/256;
    }
    J.start[9] = cum;
    cvt9_kernel<<<cum,256,0,stream>>>(J);
  }
  biasprep_kernel<<<1024,256,0,stream>>>(bias, mask, tsc, biasT);

  // 2) batched q/k/v projections (q pre-scaled for exp2 softmax; v -> vT)
  qkv_tile<<<384,256,0,stream>>>(hVb, kbI, vbI, Wqb, Wkb, Wvb, bq, bk, bv, tsc, qb, kb, vT);

  // 3) fused attention (pipelined), QBLK=32, 512 thr
  attn_fused<<<1024,512,0,stream>>>(qb, kb, vT, biasT, Eidx, X2, gpart);

  // 4) edge embedding (sums 8 per-head partials)
  edge_kernel<<<M_,128,0,stream>>>(gpart, E, X2);

  // 5) out-proj (128x64 tiles, BK=64) + residual LN
  gemm_n64<2><<<256,256,0,stream>>>(X2, Wob, bo, hraw, D_+ED_, D_, 8);
  ln1_kernel<<<M_,256,0,stream>>>(h_V, hraw, gn, bn, hf, hh);

  // 6) FFN: FF1 128x128 BK=64 (512 blocks), FF2 128x64 BK=64 (256 blocks)
  gemm_tile<1><<<512,256,0,stream>>>(hh, w1b, bw1, ff1, D_, DFF_, 16);
  gemm_n64<2><<<256,256,0,stream>>>(ff1, w2b, bw2, ffraw, DFF_, D_, 8);

  // 7) final double-LN
  final_kernel<<<M_,256,0,stream>>>(hf, ffraw, gf, bfv, g2, b2, out);
}

// Round 14
// 162.304 us; speedup vs baseline: 1.6249x; 1.0354x over previous
//
#include <hip/hip_runtime.h>
#include <hip/hip_fp16.h>
#include <math.h>

#define B_ 4
#define T_ 1024
#define D_ 512
#define H_ 8
#define HD_ 64
#define KN 30
#define ED_ 128
#define DFF_ 2048
#define M_ 4096   // B*T
#define BH_ 32

typedef _Float16 f16;
typedef __attribute__((ext_vector_type(8))) _Float16 f16x8;
typedef __attribute__((ext_vector_type(4))) _Float16 f16x4;
typedef __attribute__((ext_vector_type(4))) float f32x4;

#define MFMA16 __builtin_amdgcn_mfma_f32_16x16x32_f16
#define LOG2E 1.44269504088896f

__device__ __forceinline__ f16x8 ld8(const f16* p){ return *reinterpret_cast<const f16x8*>(p); }

__device__ __forceinline__ void gld16(const void* g, void* l){
  __builtin_amdgcn_global_load_lds((const __attribute__((address_space(1))) void*)g,
                                   (__attribute__((address_space(3))) void*)l, 16, 0, 0);
}

// ---------------- combined fp32 -> fp16 convert (9 tensors, 1 launch) -------
struct CvtJobs {
  const float* s[9];
  f16* d[9];
  int start[10];   // cumulative block starts; each block = 256 float4s
};

__global__ __launch_bounds__(256) void cvt9_kernel(CvtJobs J){
  const int blk = blockIdx.x;
  int j = 0;
  while (j < 8 && blk >= J.start[j+1]) ++j;
  const int i = (blk - J.start[j])*256 + threadIdx.x;
  float4 v = reinterpret_cast<const float4*>(J.s[j])[i];
  union { f16 h[4]; ushort4 u; } o;
  o.h[0]=(f16)v.x; o.h[1]=(f16)v.y; o.h[2]=(f16)v.z; o.h[3]=(f16)v.w;
  reinterpret_cast<ushort4*>(J.d[j])[i] = o.u;
}

// ---------------- bias prep: per-lane f16x8 chunk fragments ----------------
// For (bi,tb,c,ws,qg,l16,l4): 8 f16 = [step0 j0..3 | step1 j0..3], where
// value(step,j) = scaled bias[t = tb*32+qg*16+l16][s = c*128+ws*32+step*16+l4*4+j].
// Flat offset = thread_index*8 -> attn reads one ld8 per chunk, preloaded.
__global__ __launch_bounds__(256) void biasprep_kernel(
    const float* __restrict__ bias, const int* __restrict__ mask,
    const float* __restrict__ tsc, f16* __restrict__ biasT)
{
  const int u = blockIdx.x*256 + threadIdx.x;    // 524288 threads
  const int l4 = u & 3, l16 = (u >> 2) & 15, qg = (u >> 6) & 1;
  const int ws = (u >> 7) & 3, c = (u >> 9) & 7, tb = (u >> 12) & 31, bi = u >> 17;
  const float s = exp2f(-2.0f*tanhf(tsc[0]))*LOG2E;  // log2e / 4^tanh(t)
  const int t  = tb*32 + qg*16 + l16;
  const int s0 = c*128 + ws*32 + l4*4;
  const float* bp = bias + ((size_t)bi*T_ + t)*T_ + s0;
  const int*   mp = mask + bi*T_ + s0;
  union { f16 h[8]; f16x8 v8; } o;
#pragma unroll
  for (int st = 0; st < 2; ++st){
    float4 v = *reinterpret_cast<const float4*>(bp + st*16);
    int4  mm = *reinterpret_cast<const int4*>(mp + st*16);
    float x[4] = {v.x,v.y,v.z,v.w};
    int  m4[4] = {mm.x,mm.y,mm.z,mm.w};
#pragma unroll
    for (int j = 0; j < 4; ++j){
      float tv = (x[j] + (m4[j] ? 0.f : -60000.f))*s;
      o.h[st*4 + j] = (f16)fmaxf(tv, -60000.f);
    }
  }
  *reinterpret_cast<f16x8*>(biasT + (size_t)u*8) = o.v8;
}

// =============== staged MFMA GEMM: C = X @ W.T, BK=64, XOR-swizzled =========
// EPI 1: f16 gelu(acc+bias). EPI 2: f16 acc+bias.
template<int EPI>
__global__ __launch_bounds__(256,2) void gemm_tile(
    const f16* __restrict__ X, const f16* __restrict__ W,
    const float* __restrict__ bias, void* __restrict__ outp,
    int Kd, int ldo, int nbN)
{
  __shared__ f16 As[128*64];
  __shared__ f16 Bs[128*64];
  const int nwg = gridDim.x;
  const int bid = blockIdx.x;
  const int swz = (bid & 7)*(nwg >> 3) + (bid >> 3);
  const int mb = swz / nbN, nb = swz - mb*nbN;
  const int rb = mb*128, cb = nb*128;
  const int tid = threadIdx.x;
  const int w = tid >> 6, lane = tid & 63;
  const int l16 = lane & 15, l4 = lane >> 4;
  const int wr = w >> 1, wc = w & 1;
  const int key = l16 & 7;

  f32x4 acc[4][4];
#pragma unroll
  for (int m = 0; m < 4; ++m)
#pragma unroll
    for (int n = 0; n < 4; ++n) acc[m][n] = (f32x4){0.f,0.f,0.f,0.f};

  for (int k0 = 0; k0 < Kd; k0 += 64){
#pragma unroll
    for (int i = 0; i < 4; ++i){
      const int cidx = i*256 + w*64 + lane;
      const int r = cidx >> 3, p = cidx & 7;
      gld16(X + (size_t)(rb + r)*Kd + k0 + ((p ^ (r & 7)) << 3),
            &As[(i*256 + w*64)*8]);
      gld16(W + (size_t)(cb + r)*Kd + k0 + ((p ^ (r & 7)) << 3),
            &Bs[(i*256 + w*64)*8]);
    }
    __syncthreads();
#pragma unroll
    for (int kk = 0; kk < 2; ++kk){
      f16x8 a[4], b[4];
#pragma unroll
      for (int m = 0; m < 4; ++m)
        a[m] = ld8(&As[(wr*64 + m*16 + l16)*64 + (((kk*4 + l4) ^ key) << 3)]);
#pragma unroll
      for (int n = 0; n < 4; ++n)
        b[n] = ld8(&Bs[(wc*64 + n*16 + l16)*64 + (((kk*4 + l4) ^ key) << 3)]);
#pragma unroll
      for (int m = 0; m < 4; ++m)
#pragma unroll
        for (int n = 0; n < 4; ++n)
          acc[m][n] = MFMA16(a[m], b[n], acc[m][n], 0,0,0);
    }
    __syncthreads();
  }

#pragma unroll
  for (int n = 0; n < 4; ++n){
    const int col = cb + wc*64 + n*16 + l16;
    const float bv = bias[col];
#pragma unroll
    for (int m = 0; m < 4; ++m){
#pragma unroll
      for (int j = 0; j < 4; ++j){
        const int row = rb + wr*64 + m*16 + l4*4 + j;
        float v = acc[m][n][j] + bv;
        if (EPI == 1) v = 0.5f*v*(1.0f + erff(v*0.70710678118654752f));
        ((f16*)outp)[(size_t)row*ldo + col] = (f16)v;
      }
    }
  }
}

// =============== 128x64-tile GEMM, BK=64, XOR-swizzled ======================
template<int EPI>
__global__ __launch_bounds__(256,2) void gemm_n64(
    const f16* __restrict__ X, const f16* __restrict__ W,
    const float* __restrict__ bias, void* __restrict__ outp,
    int Kd, int ldo, int nbN)
{
  __shared__ f16 As[128*64];
  __shared__ f16 Bs[64*64];
  const int nwg = gridDim.x;
  const int bid = blockIdx.x;
  const int swz = (bid & 7)*(nwg >> 3) + (bid >> 3);
  const int mb = swz / nbN, nb = swz - mb*nbN;
  const int rb = mb*128, cb = nb*64;
  const int tid = threadIdx.x;
  const int w = tid >> 6, lane = tid & 63;
  const int l16 = lane & 15, l4 = lane >> 4;
  const int wr = w >> 1, wc = w & 1;
  const int key = l16 & 7;

  f32x4 acc[4][2];
#pragma unroll
  for (int m = 0; m < 4; ++m)
#pragma unroll
    for (int n = 0; n < 2; ++n) acc[m][n] = (f32x4){0.f,0.f,0.f,0.f};

  for (int k0 = 0; k0 < Kd; k0 += 64){
#pragma unroll
    for (int i = 0; i < 4; ++i){
      const int cidx = i*256 + w*64 + lane;
      const int r = cidx >> 3, p = cidx & 7;
      gld16(X + (size_t)(rb + r)*Kd + k0 + ((p ^ (r & 7)) << 3),
            &As[(i*256 + w*64)*8]);
    }
#pragma unroll
    for (int i = 0; i < 2; ++i){
      const int cidx = i*256 + w*64 + lane;
      const int r = cidx >> 3, p = cidx & 7;
      gld16(W + (size_t)(cb + r)*Kd + k0 + ((p ^ (r & 7)) << 3),
            &Bs[(i*256 + w*64)*8]);
    }
    __syncthreads();
#pragma unroll
    for (int kk = 0; kk < 2; ++kk){
      f16x8 a[4], b[2];
#pragma unroll
      for (int m = 0; m < 4; ++m)
        a[m] = ld8(&As[(wr*64 + m*16 + l16)*64 + (((kk*4 + l4) ^ key) << 3)]);
#pragma unroll
      for (int n = 0; n < 2; ++n)
        b[n] = ld8(&Bs[(wc*32 + n*16 + l16)*64 + (((kk*4 + l4) ^ key) << 3)]);
#pragma unroll
      for (int m = 0; m < 4; ++m)
#pragma unroll
        for (int n = 0; n < 2; ++n)
          acc[m][n] = MFMA16(a[m], b[n], acc[m][n], 0,0,0);
    }
    __syncthreads();
  }

#pragma unroll
  for (int n = 0; n < 2; ++n){
    const int col = cb + wc*32 + n*16 + l16;
    const float bv = bias[col];
#pragma unroll
    for (int m = 0; m < 4; ++m){
#pragma unroll
      for (int j = 0; j < 4; ++j){
        const int row = rb + wr*64 + m*16 + l4*4 + j;
        float v = acc[m][n][j] + bv;
        if (EPI == 1) v = 0.5f*v*(1.0f + erff(v*0.70710678118654752f));
        ((f16*)outp)[(size_t)row*ldo + col] = (f16)v;
      }
    }
  }
}

// =============== batched QKV projection (one launch, 3 GEMMs) ===============
__global__ __launch_bounds__(256,2) void qkv_tile(
    const f16* __restrict__ hV, const f16* __restrict__ kI, const f16* __restrict__ vI,
    const f16* __restrict__ Wq, const f16* __restrict__ Wk, const f16* __restrict__ Wv,
    const float* __restrict__ bq, const float* __restrict__ bk, const float* __restrict__ bv,
    const float* __restrict__ tsc,
    f16* __restrict__ qo, f16* __restrict__ ko, f16* __restrict__ vT)
{
  __shared__ f16 As[128*32];
  __shared__ f16 Bs[128*32];
  const int bid = blockIdx.x;
  const int swz = (bid & 7)*48 + (bid >> 3);
  const int g = swz >> 7;
  const int r = swz & 127;
  const int mb = r >> 2, nb = r & 3;
  const f16* X  = (g == 0) ? hV : ((g == 1) ? kI : vI);
  const f16* W  = (g == 0) ? Wq : ((g == 1) ? Wk : Wv);
  const float* bias = (g == 0) ? bq : ((g == 1) ? bk : bv);
  const int rb = mb*128, cb = nb*128;
  const int tid = threadIdx.x;
  const int w = tid >> 6, lane = tid & 63;
  const int l16 = lane & 15, l4 = lane >> 4;
  const int wr = w >> 1, wc = w & 1;
  const int sr = lane >> 2, sc = (lane & 3)*8;
  const f16* Ax0 = X + (size_t)(rb + w*16 + sr)*D_ + sc;
  const f16* Ax1 = X + (size_t)(rb + 64 + w*16 + sr)*D_ + sc;
  const f16* Bx0 = W + (size_t)(cb + w*16 + sr)*D_ + sc;
  const f16* Bx1 = W + (size_t)(cb + 64 + w*16 + sr)*D_ + sc;
  f16* Ad0 = &As[(w*16)*32];
  f16* Ad1 = &As[(64 + w*16)*32];
  f16* Bd0 = &Bs[(w*16)*32];
  f16* Bd1 = &Bs[(64 + w*16)*32];

  f32x4 acc[4][4];
#pragma unroll
  for (int m = 0; m < 4; ++m)
#pragma unroll
    for (int n = 0; n < 4; ++n) acc[m][n] = (f32x4){0.f,0.f,0.f,0.f};

  for (int k0 = 0; k0 < D_; k0 += 32){
    gld16(Ax0 + k0, Ad0);
    gld16(Ax1 + k0, Ad1);
    gld16(Bx0 + k0, Bd0);
    gld16(Bx1 + k0, Bd1);
    __syncthreads();
    f16x8 a[4], b[4];
#pragma unroll
    for (int m = 0; m < 4; ++m) a[m] = ld8(&As[(wr*64 + m*16 + l16)*32 + l4*8]);
#pragma unroll
    for (int n = 0; n < 4; ++n) b[n] = ld8(&Bs[(wc*64 + n*16 + l16)*32 + l4*8]);
#pragma unroll
    for (int m = 0; m < 4; ++m)
#pragma unroll
      for (int n = 0; n < 4; ++n)
        acc[m][n] = MFMA16(a[m], b[n], acc[m][n], 0,0,0);
    __syncthreads();
  }

  const float qs = exp2f(-2.0f*tanhf(tsc[0]))*LOG2E*0.125f;
  const float scale = (g == 0) ? qs : 1.0f;
  f16* out = (g == 0) ? qo : ko;
#pragma unroll
  for (int n = 0; n < 4; ++n){
    const int col = cb + wc*64 + n*16 + l16;
    const float bv = bias[col];
#pragma unroll
    for (int m = 0; m < 4; ++m){
#pragma unroll
      for (int j = 0; j < 4; ++j){
        const int row = rb + wr*64 + m*16 + l4*4 + j;
        const float v = (acc[m][n][j] + bv)*scale;
        if (g < 2){
          out[(size_t)row*D_ + col] = (f16)v;
        } else {
          const int b = row >> 10, t = row & (T_-1);
          const int h = col >> 6,  dl = col & (HD_-1);
          vT[(((size_t)b*H_ + h)*HD_ + dl)*T_ + t] = (f16)v;
        }
      }
    }
  }
}

// =============== fused attention (pipelined; pure vmcnt stream) =============
// 8 waves: qg=w>>2 owns q-group, ws=w&3 owns s-subrange / d-cols.
// K/V double-buffered; counted s_waitcnt vmcnt(2) + raw s_barrier. The main
// loops contain ONLY gld16 VMEM ops: bias fragments preloaded to registers
// (8 x f16x8), edge-gather values captured in registers, stored after loop.
__global__ __launch_bounds__(512,4) void attn_fused(
    const f16* __restrict__ q, const f16* __restrict__ k, const f16* __restrict__ vT,
    const f16* __restrict__ biasT, const int* __restrict__ eidx,
    f16* __restrict__ X2, float* __restrict__ gpart)
{
  __shared__ f16 Sb[16384];       // 32 KB: K/V chunk double buffer (2 x 8192)
  __shared__ f16 Pc[32*128];      // 8 KB: P chunk [32 q][128 s]
  const int bid = blockIdx.x;
  const int swz = (bid & 7)*128 + (bid >> 3);   // XCD-contiguous
  const int bh = swz >> 5, tb = swz & 31;
  const int bi = bh >> 3, h = bh & 7;
  const int t0 = tb*32;
  const int tid = threadIdx.x, w = tid >> 6, lane = tid & 63;
  const int qg = w >> 2, ws = w & 3;
  const int l16 = lane & 15, l4 = lane >> 4;
  const int key = l16 & 7;

  // ---- Q fragments ----
  const f16* qp = q + (size_t)(bi*T_ + t0 + qg*16 + l16)*D_ + h*HD_ + l4*8;
  const f16x8 q0 = ld8(qp), q1 = ld8(qp + 32);
  // ---- bias fragments: one f16x8 per chunk, preloaded ----
  const f16* bb = biasT + (size_t)(bi*32 + tb)*32768 + ws*1024 + qg*512 + l16*32 + l4*8;
  f16x8 bfr[8];
#pragma unroll
  for (int c = 0; c < 8; ++c) bfr[c] = ld8(bb + c*4096);
  // ---- gather tuples: each tid handles items of its own qg half ----
  const int tl = tid & 255;
  int ga_r, ga_kk, ga_id, gb_r = 0, gb_kk = 0, gb_id = -1;
  ga_r = tl/KN; ga_kk = tl - ga_r*KN;
  ga_id = eidx[((size_t)(bi*T_ + t0 + qg*16 + ga_r))*KN + ga_kk];
  if (tl + 256 < 16*KN){
    gb_r = (tl+256)/KN; gb_kk = (tl+256) - gb_r*KN;
    gb_id = eidx[((size_t)(bi*T_ + t0 + qg*16 + gb_r))*KN + gb_kk];
  }

  const f16* kg = k + (size_t)(bi*T_)*D_ + h*HD_;
  const f16* vg = vT + (size_t)bh*HD_*T_;

  auto stageK = [&](int c, int slot){
#pragma unroll
    for (int i = 0; i < 2; ++i){
      const int cidx = i*512 + w*64 + lane;
      const int r = cidx >> 3, p = cidx & 7;
      gld16(kg + (size_t)(c*128 + r)*D_ + ((p ^ (r & 7)) << 3),
            &Sb[slot*8192 + (i*512 + w*64)*8]);
    }
  };
  auto stageV = [&](int sc, int slot){
#pragma unroll
    for (int i = 0; i < 2; ++i){
      const int cidx = i*512 + w*64 + lane;
      const int r = cidx >> 4, p = cidx & 15;
      gld16(vg + (size_t)r*T_ + sc*128 + ((p ^ (r & 7)) << 3),
            &Sb[slot*8192 + (i*512 + w*64)*8]);
    }
  };

  // ---- QK^T: 8 chunks of 128 s, ping-pong + counted vmcnt ----
  f32x4 acc[16];
  stageK(0, 0);
#pragma unroll
  for (int c = 0; c < 8; ++c){
    if (c < 7) stageK(c+1, (c+1)&1);
    if (c < 7) asm volatile("s_waitcnt vmcnt(2)" ::: "memory");
    else       asm volatile("s_waitcnt vmcnt(0)" ::: "memory");
    __builtin_amdgcn_sched_barrier(0);
    __builtin_amdgcn_s_barrier();
    __builtin_amdgcn_sched_barrier(0);
    const int base = (c&1)*8192;
#pragma unroll
    for (int step = 0; step < 2; ++step){
      const int rr = ws*32 + step*16 + l16;
      f32x4 a = {0.f,0.f,0.f,0.f};
      a = MFMA16(ld8(&Sb[base + rr*64 + ((l4 ^ key) << 3)]),       q0, a, 0,0,0);
      a = MFMA16(ld8(&Sb[base + rr*64 + (((4 + l4) ^ key) << 3)]), q1, a, 0,0,0);
#pragma unroll
      for (int j = 0; j < 4; ++j) a[j] += (float)bfr[c][step*4 + j];
      acc[c*2 + step] = a;
    }
    __builtin_amdgcn_s_barrier();   // readers of slot (c&1) done
  }

  // ---- softmax (stats overlay on idle Sb; sums redistributed via shfl) ----
  float* redf = (float*)Sb;         // [0..127]=max, [128..255]=sum
  float m = -3.4e38f;
#pragma unroll
  for (int c = 0; c < 16; ++c)
#pragma unroll
    for (int j = 0; j < 4; ++j) m = fmaxf(m, acc[c][j]);
  m = fmaxf(m, __shfl_xor(m, 16));
  m = fmaxf(m, __shfl_xor(m, 32));
  if (lane < 16) redf[(qg*4 + ws)*16 + lane] = m;
  __syncthreads();
  m = fmaxf(fmaxf(redf[(qg*4+0)*16 + l16], redf[(qg*4+1)*16 + l16]),
            fmaxf(redf[(qg*4+2)*16 + l16], redf[(qg*4+3)*16 + l16]));
  float l = 0.f;
#pragma unroll
  for (int c = 0; c < 16; ++c)
#pragma unroll
    for (int j = 0; j < 4; ++j){
      const float e = exp2f(acc[c][j] - m);
      l += e;
      acc[c][j] = e;                // acc now holds unnormalized P
    }
  l += __shfl_xor(l, 16);
  l += __shfl_xor(l, 32);
  if (lane < 16) redf[128 + (qg*4 + ws)*16 + lane] = l;
  __syncthreads();
  const float lrq = redf[128 + (qg*4+0)*16 + l16] + redf[128 + (qg*4+1)*16 + l16]
                  + redf[128 + (qg*4+2)*16 + l16] + redf[128 + (qg*4+3)*16 + l16];
  __syncthreads();                  // all lrq reads done before V staging clobbers
  const float lr_a = __shfl(lrq, ga_r);
  const float lr_b = __shfl(lrq, gb_r);

  // ---- PV: 8 chunks, V ping-pong + counted vmcnt; gather -> registers ----
  f32x4 oo0 = {0.f,0.f,0.f,0.f}, oo1 = oo0, oo2 = oo0, oo3 = oo0;
  float pva = 0.f, pvb = 0.f;
  stageV(0, 0);
#pragma unroll
  for (int sc = 0; sc < 8; ++sc){
    // write own P slice for chunk sc (Pc free: prior readers barrier'd)
#pragma unroll
    for (int step = 0; step < 2; ++step){
      const int slb = ws*32 + step*16 + l4*4;
      f16x4 pp;
#pragma unroll
      for (int j = 0; j < 4; ++j) pp[j] = (f16)acc[sc*2 + step][j];
      *reinterpret_cast<f16x4*>(
          &Pc[(qg*16 + l16)*128 + (((slb >> 3) ^ key) << 3) + (slb & 7)]) = pp;
    }
    if (sc < 7) stageV(sc+1, (sc+1)&1);
    if (sc < 7) asm volatile("s_waitcnt vmcnt(2) lgkmcnt(0)" ::: "memory");
    else        asm volatile("s_waitcnt vmcnt(0) lgkmcnt(0)" ::: "memory");
    __builtin_amdgcn_sched_barrier(0);
    __builtin_amdgcn_s_barrier();
    __builtin_amdgcn_sched_barrier(0);
    const int base = (sc&1)*8192;
    const int vrow = (ws*16 + l16)*128;
#pragma unroll
    for (int grp = 0; grp < 4; ++grp){
      const int ch = (grp*4 + l4) ^ key;
      const f16x8 pa = ld8(&Pc[(qg*16 + l16)*128 + (ch << 3)]);
      const f16x8 vb = ld8(&Sb[base + vrow + (ch << 3)]);
      if (grp == 0)      oo0 = MFMA16(pa, vb, oo0, 0,0,0);
      else if (grp == 1) oo1 = MFMA16(pa, vb, oo1, 0,0,0);
      else if (grp == 2) oo2 = MFMA16(pa, vb, oo2, 0,0,0);
      else               oo3 = MFMA16(pa, vb, oo3, 0,0,0);
    }
    // edge gather capture (no VMEM stores inside the loop)
    if ((ga_id >> 7) == sc){
      const int r = qg*16 + ga_r;
      const int sl = ga_id & 127;
      pva = (float)Pc[r*128 + ((((sl >> 3) ^ (r & 7)) << 3) | (sl & 7))];
    }
    if (gb_id >= 0 && (gb_id >> 7) == sc){
      const int r = qg*16 + gb_r;
      const int sl = gb_id & 127;
      pvb = (float)Pc[r*128 + ((((sl >> 3) ^ (r & 7)) << 3) | (sl & 7))];
    }
    __builtin_amdgcn_s_barrier();   // readers of Pc + V slot (sc&1) done
  }
  const f32x4 o = (oo0 + oo1) + (oo2 + oo3);

  // ---- deferred gather stores ----
  gpart[((size_t)bh*T_ + t0 + qg*16 + ga_r)*KN + ga_kk] = pva/lr_a*0.125f;
  if (gb_id >= 0)
    gpart[((size_t)bh*T_ + t0 + qg*16 + gb_r)*KN + gb_kk] = pvb/lr_b*0.125f;

#pragma unroll
  for (int j = 0; j < 4; ++j){
    const float lr = __shfl(lrq, l4*4 + j);
    const int t = t0 + qg*16 + l4*4 + j;
    X2[((size_t)(bi*T_ + t))*640 + h*HD_ + ws*16 + l16] = (f16)(o[j]/lr);
  }
}

// ---------------- edge: weighted neighbor-embedding mean -------------------
// g[b,t,kk] = sum_h gpart[(b*H+h), t, kk]
__global__ __launch_bounds__(128) void edge_kernel(
    const float* __restrict__ gpart, const float* __restrict__ E, f16* __restrict__ X2)
{
  __shared__ float gl[KN];
  __shared__ float ginv;
  const int bt = blockIdx.x;          // b*T + t
  const int bi = bt >> 10, tt = bt & 1023;
  const int t = threadIdx.x;
  if (t < KN){
    float s = 0.f;
#pragma unroll
    for (int hh = 0; hh < H_; ++hh)
      s += gpart[((size_t)(bi*H_ + hh)*T_ + tt)*KN + t];
    gl[t] = s;
  }
  __syncthreads();
  if (t == 0){
    float s = 0.f;
#pragma unroll
    for (int i = 0; i < KN; ++i) s += gl[i];
    ginv = 1.0f/(s + 1e-6f);
  }
  __syncthreads();
  float acc = 0.f;
  const float* Ep = E + (size_t)bt*KN*ED_ + t;
#pragma unroll 5
  for (int kk = 0; kk < KN; ++kk) acc += gl[kk]*Ep[(size_t)kk*ED_];
  X2[(size_t)bt*640 + 512 + t] = (f16)(acc*ginv);
}

// ---------------- LayerNorm helpers ----------------------------------------
__device__ __forceinline__ float block_sum(float v, float* sbuf){
  for (int o = 32; o; o >>= 1) v += __shfl_down(v, o);
  __syncthreads();
  if ((threadIdx.x & 63) == 0) sbuf[threadIdx.x >> 6] = v;
  __syncthreads();
  return sbuf[0]+sbuf[1]+sbuf[2]+sbuf[3];
}

__global__ __launch_bounds__(256) void ln1_kernel(
    const float* __restrict__ hV, const f16* __restrict__ hraw,
    const float* __restrict__ gn, const float* __restrict__ bn,
    f16* __restrict__ hh)
{
  __shared__ float sbuf[4];
  const int r = blockIdx.x, t = threadIdx.x;
  const size_t base = (size_t)r*D_;
  float x0 = hV[base+t]     + (float)hraw[base+t];
  float x1 = hV[base+t+256] + (float)hraw[base+t+256];
  float s = block_sum(x0+x1, sbuf);
  const float mean = s*(1.f/512.f);
  float d0 = x0-mean, d1 = x1-mean;
  float vs = block_sum(d0*d0+d1*d1, sbuf);
  const float rstd = rsqrtf(vs*(1.f/512.f) + 1e-5f);
  hh[base+t]     = (f16)(d0*rstd*gn[t]     + bn[t]);
  hh[base+t+256] = (f16)(d1*rstd*gn[t+256] + bn[t+256]);
}

__global__ __launch_bounds__(256) void final_kernel(
    const f16* __restrict__ hh, const f16* __restrict__ ffr,
    const float* __restrict__ gf, const float* __restrict__ bfv,
    const float* __restrict__ g2, const float* __restrict__ b2,
    float* __restrict__ out)
{
  __shared__ float sbuf[4];
  const int r = blockIdx.x, t = threadIdx.x;
  const size_t base = (size_t)r*D_;
  const float h0 = (float)hh[base+t], h1 = (float)hh[base+t+256];
  float x0 = h0 + (float)ffr[base+t], x1 = h1 + (float)ffr[base+t+256];
  float s = block_sum(x0+x1, sbuf);
  float mean = s*(1.f/512.f);
  float d0 = x0-mean, d1 = x1-mean;
  float vs = block_sum(d0*d0+d1*d1, sbuf);
  float rstd = rsqrtf(vs*(1.f/512.f) + 1e-6f);
  const float dh0 = d0*rstd*gf[t]     + bfv[t];
  const float dh1 = d1*rstd*gf[t+256] + bfv[t+256];
  const float y0 = h0 + dh0, y1 = h1 + dh1;
  s = block_sum(y0+y1, sbuf);
  mean = s*(1.f/512.f);
  d0 = y0-mean; d1 = y1-mean;
  vs = block_sum(d0*d0+d1*d1, sbuf);
  rstd = rsqrtf(vs*(1.f/512.f) + 1e-5f);
  out[base+t]     = d0*rstd*g2[t]     + b2[t];
  out[base+t+256] = d1*rstd*g2[t+256] + b2[t+256];
}

// ---------------------------------------------------------------------------
extern "C" void kernel_launch(void* const* d_in, const int* in_sizes, int n_in,
                              void* d_out, int out_size, void* d_ws, size_t ws_size,
                              hipStream_t stream)
{
  (void)in_sizes; (void)n_in; (void)out_size;
  const float* h_V  = (const float*)d_in[0];
  const float* kin  = (const float*)d_in[1];
  const float* vin  = (const float*)d_in[2];
  const float* E    = (const float*)d_in[3];
  const float* bias = (const float*)d_in[4];
  const float* Wq   = (const float*)d_in[5];
  const float* bq   = (const float*)d_in[6];
  const float* Wk   = (const float*)d_in[7];
  const float* bk   = (const float*)d_in[8];
  const float* Wv   = (const float*)d_in[9];
  const float* bv   = (const float*)d_in[10];
  const float* Wo   = (const float*)d_in[11];
  const float* bo   = (const float*)d_in[12];
  const float* tsc  = (const float*)d_in[13];
  const float* gn   = (const float*)d_in[14];
  const float* bn   = (const float*)d_in[15];
  const float* w1   = (const float*)d_in[16];
  const float* bw1  = (const float*)d_in[17];
  const float* w2   = (const float*)d_in[18];
  const float* bw2  = (const float*)d_in[19];
  const float* gf   = (const float*)d_in[20];
  const float* bfv  = (const float*)d_in[21];
  const float* g2   = (const float*)d_in[22];
  const float* b2   = (const float*)d_in[23];
  const int*   Eidx = (const int*)d_in[24];
  const int*   mask = (const int*)d_in[25];
  float* out = (float*)d_out;

  char* wsb = (char*)d_ws;
  size_t off = 0;
  auto alloc = [&](size_t bytes) -> void* {
    void* pp = wsb + off; off += (bytes + 255) & ~(size_t)255; return pp;
  };
  f16* hVb  = (f16*)alloc((size_t)M_*D_*2);
  f16* kbI  = (f16*)alloc((size_t)M_*D_*2);
  f16* vbI  = (f16*)alloc((size_t)M_*D_*2);
  f16* Wqb  = (f16*)alloc((size_t)D_*D_*2);
  f16* Wkb  = (f16*)alloc((size_t)D_*D_*2);
  f16* Wvb  = (f16*)alloc((size_t)D_*D_*2);
  f16* Wob  = (f16*)alloc((size_t)D_*(D_+ED_)*2);
  f16* w1b  = (f16*)alloc((size_t)DFF_*D_*2);
  f16* w2b  = (f16*)alloc((size_t)D_*DFF_*2);
  f16* qb   = (f16*)alloc((size_t)M_*D_*2);
  f16* kb   = (f16*)alloc((size_t)M_*D_*2);
  f16* vT   = (f16*)alloc((size_t)M_*D_*2);
  f16* biasT= (f16*)alloc((size_t)B_*T_*T_*2);
  f16* X2   = (f16*)alloc((size_t)M_*640*2);
  float* gpart = (float*)alloc((size_t)BH_*T_*KN*4);
  f16* hraw = (f16*)alloc((size_t)M_*D_*2);   // reused as ffraw (f16)
  f16* hh   = (f16*)alloc((size_t)M_*D_*2);
  f16* ff1  = (f16*)alloc((size_t)M_*DFF_*2);
  if (ws_size < off) return;  // scratch insufficient -> loud validation failure
  f16* ffraw = hraw;

  // 1) converts fp32 -> f16 (one launch) + bias prep (fragment-tiled biasT)
  {
    CvtJobs J;
    const float* srcs[9] = {h_V, kin, vin, Wq, Wk, Wv, Wo, w1, w2};
    f16* dsts[9] = {hVb, kbI, vbI, Wqb, Wkb, Wvb, Wob, w1b, w2b};
    const int n4s[9] = {M_*D_/4, M_*D_/4, M_*D_/4, D_*D_/4, D_*D_/4, D_*D_/4,
                        D_*(D_+ED_)/4, DFF_*D_/4, D_*DFF_/4};
    int cum = 0;
    for (int i = 0; i < 9; ++i){
      J.s[i] = srcs[i]; J.d[i] = dsts[i]; J.start[i] = cum;
      cum += n4s[i]/256;
    }
    J.start[9] = cum;
    cvt9_kernel<<<cum,256,0,stream>>>(J);
  }
  biasprep_kernel<<<2048,256,0,stream>>>(bias, mask, tsc, biasT);

  // 2) batched q/k/v projections (q pre-scaled for exp2 softmax; v -> vT)
  qkv_tile<<<384,256,0,stream>>>(hVb, kbI, vbI, Wqb, Wkb, Wvb, bq, bk, bv, tsc, qb, kb, vT);

  // 3) fused attention (pipelined, pure vmcnt stream), QBLK=32, 512 thr
  attn_fused<<<1024,512,0,stream>>>(qb, kb, vT, biasT, Eidx, X2, gpart);

  // 4) edge embedding (sums 8 per-head partials)
  edge_kernel<<<M_,128,0,stream>>>(gpart, E, X2);

  // 5) out-proj (f16 raw out) + residual LN
  gemm_n64<2><<<256,256,0,stream>>>(X2, Wob, bo, hraw, D_+ED_, D_, 8);
  ln1_kernel<<<M_,256,0,stream>>>(h_V, hraw, gn, bn, hh);

  // 6) FFN: FF1 gelu f16, FF2 raw f16
  gemm_tile<1><<<512,256,0,stream>>>(hh, w1b, bw1, ff1, D_, DFF_, 16);
  gemm_n64<2><<<256,256,0,stream>>>(ff1, w2b, bw2, ffraw, DFF_, D_, 8);

  // 7) final double-LN (f16 inputs)
  final_kernel<<<M_,256,0,stream>>>(hh, ffraw, gf, bfv, g2, b2, out);
}

// Round 15
// 159.268 us; speedup vs baseline: 1.6559x; 1.0191x over previous
//
#include <hip/hip_runtime.h>
#include <hip/hip_fp16.h>
#include <math.h>

#define B_ 4
#define T_ 1024
#define D_ 512
#define H_ 8
#define HD_ 64
#define KN 30
#define ED_ 128
#define DFF_ 2048
#define M_ 4096   // B*T
#define BH_ 32

typedef _Float16 f16;
typedef __attribute__((ext_vector_type(8))) _Float16 f16x8;
typedef __attribute__((ext_vector_type(4))) _Float16 f16x4;
typedef __attribute__((ext_vector_type(4))) float f32x4;

#define MFMA16 __builtin_amdgcn_mfma_f32_16x16x32_f16
#define LOG2E 1.44269504088896f

__device__ __forceinline__ f16x8 ld8(const f16* p){ return *reinterpret_cast<const f16x8*>(p); }

__device__ __forceinline__ void gld16(const void* g, void* l){
  __builtin_amdgcn_global_load_lds((const __attribute__((address_space(1))) void*)g,
                                   (__attribute__((address_space(3))) void*)l, 16, 0, 0);
}

// ---------------- fused prep: 9x fp32->f16 convert + bias prep --------------
struct CvtJobs {
  const float* s[9];
  f16* d[9];
  int start[10];   // cumulative block starts; each block = 256 float4s
};

// blocks [0, cvtBlocks): convert; blocks [cvtBlocks, +2048): biasprep.
// biasT layout: per-lane f16x8 chunk fragments — for (bi,tb,c,ws,qg,l16,l4):
// 8 f16 = [step0 j0..3 | step1 j0..3] of scaled
// bias[t=tb*32+qg*16+l16][s=c*128+ws*32+step*16+l4*4+j]; flat off = u*8.
__global__ __launch_bounds__(256) void prep_kernel(
    CvtJobs J, int cvtBlocks,
    const float* __restrict__ bias, const int* __restrict__ mask,
    const float* __restrict__ tsc, f16* __restrict__ biasT)
{
  if (blockIdx.x < cvtBlocks){
    const int blk = blockIdx.x;
    int j = 0;
    while (j < 8 && blk >= J.start[j+1]) ++j;
    const int i = (blk - J.start[j])*256 + threadIdx.x;
    float4 v = reinterpret_cast<const float4*>(J.s[j])[i];
    union { f16 h[4]; ushort4 u; } o;
    o.h[0]=(f16)v.x; o.h[1]=(f16)v.y; o.h[2]=(f16)v.z; o.h[3]=(f16)v.w;
    reinterpret_cast<ushort4*>(J.d[j])[i] = o.u;
    return;
  }
  const int u = (blockIdx.x - cvtBlocks)*256 + threadIdx.x;   // 524288 threads
  const int l4 = u & 3, l16 = (u >> 2) & 15, qg = (u >> 6) & 1;
  const int ws = (u >> 7) & 3, c = (u >> 9) & 7, tb = (u >> 12) & 31, bi = u >> 17;
  const float s = exp2f(-2.0f*tanhf(tsc[0]))*LOG2E;  // log2e / 4^tanh(t)
  const int t  = tb*32 + qg*16 + l16;
  const int s0 = c*128 + ws*32 + l4*4;
  const float* bp = bias + ((size_t)bi*T_ + t)*T_ + s0;
  const int*   mp = mask + bi*T_ + s0;
  union { f16 h[8]; f16x8 v8; } o;
#pragma unroll
  for (int st = 0; st < 2; ++st){
    float4 v = *reinterpret_cast<const float4*>(bp + st*16);
    int4  mm = *reinterpret_cast<const int4*>(mp + st*16);
    float x[4] = {v.x,v.y,v.z,v.w};
    int  m4[4] = {mm.x,mm.y,mm.z,mm.w};
#pragma unroll
    for (int j = 0; j < 4; ++j){
      float tv = (x[j] + (m4[j] ? 0.f : -60000.f))*s;
      o.h[st*4 + j] = (f16)fmaxf(tv, -60000.f);
    }
  }
  *reinterpret_cast<f16x8*>(biasT + (size_t)u*8) = o.v8;
}

// =============== staged MFMA GEMM: C = X @ W.T, BK=64, XOR-swizzled =========
// EPI 1: f16 gelu(acc+bias). EPI 2: f16 acc+bias.
template<int EPI>
__global__ __launch_bounds__(256,2) void gemm_tile(
    const f16* __restrict__ X, const f16* __restrict__ W,
    const float* __restrict__ bias, void* __restrict__ outp,
    int Kd, int ldo, int nbN)
{
  __shared__ f16 As[128*64];
  __shared__ f16 Bs[128*64];
  const int nwg = gridDim.x;
  const int bid = blockIdx.x;
  const int swz = (bid & 7)*(nwg >> 3) + (bid >> 3);
  const int mb = swz / nbN, nb = swz - mb*nbN;
  const int rb = mb*128, cb = nb*128;
  const int tid = threadIdx.x;
  const int w = tid >> 6, lane = tid & 63;
  const int l16 = lane & 15, l4 = lane >> 4;
  const int wr = w >> 1, wc = w & 1;
  const int key = l16 & 7;

  f32x4 acc[4][4];
#pragma unroll
  for (int m = 0; m < 4; ++m)
#pragma unroll
    for (int n = 0; n < 4; ++n) acc[m][n] = (f32x4){0.f,0.f,0.f,0.f};

  for (int k0 = 0; k0 < Kd; k0 += 64){
#pragma unroll
    for (int i = 0; i < 4; ++i){
      const int cidx = i*256 + w*64 + lane;
      const int r = cidx >> 3, p = cidx & 7;
      gld16(X + (size_t)(rb + r)*Kd + k0 + ((p ^ (r & 7)) << 3),
            &As[(i*256 + w*64)*8]);
      gld16(W + (size_t)(cb + r)*Kd + k0 + ((p ^ (r & 7)) << 3),
            &Bs[(i*256 + w*64)*8]);
    }
    __syncthreads();
#pragma unroll
    for (int kk = 0; kk < 2; ++kk){
      f16x8 a[4], b[4];
#pragma unroll
      for (int m = 0; m < 4; ++m)
        a[m] = ld8(&As[(wr*64 + m*16 + l16)*64 + (((kk*4 + l4) ^ key) << 3)]);
#pragma unroll
      for (int n = 0; n < 4; ++n)
        b[n] = ld8(&Bs[(wc*64 + n*16 + l16)*64 + (((kk*4 + l4) ^ key) << 3)]);
#pragma unroll
      for (int m = 0; m < 4; ++m)
#pragma unroll
        for (int n = 0; n < 4; ++n)
          acc[m][n] = MFMA16(a[m], b[n], acc[m][n], 0,0,0);
    }
    __syncthreads();
  }

#pragma unroll
  for (int n = 0; n < 4; ++n){
    const int col = cb + wc*64 + n*16 + l16;
    const float bv = bias[col];
#pragma unroll
    for (int m = 0; m < 4; ++m){
#pragma unroll
      for (int j = 0; j < 4; ++j){
        const int row = rb + wr*64 + m*16 + l4*4 + j;
        float v = acc[m][n][j] + bv;
        if (EPI == 1) v = 0.5f*v*(1.0f + erff(v*0.70710678118654752f));
        ((f16*)outp)[(size_t)row*ldo + col] = (f16)v;
      }
    }
  }
}

// =============== 128x64-tile GEMM, BK=64, XOR-swizzled ======================
template<int EPI>
__global__ __launch_bounds__(256,2) void gemm_n64(
    const f16* __restrict__ X, const f16* __restrict__ W,
    const float* __restrict__ bias, void* __restrict__ outp,
    int Kd, int ldo, int nbN)
{
  __shared__ f16 As[128*64];
  __shared__ f16 Bs[64*64];
  const int nwg = gridDim.x;
  const int bid = blockIdx.x;
  const int swz = (bid & 7)*(nwg >> 3) + (bid >> 3);
  const int mb = swz / nbN, nb = swz - mb*nbN;
  const int rb = mb*128, cb = nb*64;
  const int tid = threadIdx.x;
  const int w = tid >> 6, lane = tid & 63;
  const int l16 = lane & 15, l4 = lane >> 4;
  const int wr = w >> 1, wc = w & 1;
  const int key = l16 & 7;

  f32x4 acc[4][2];
#pragma unroll
  for (int m = 0; m < 4; ++m)
#pragma unroll
    for (int n = 0; n < 2; ++n) acc[m][n] = (f32x4){0.f,0.f,0.f,0.f};

  for (int k0 = 0; k0 < Kd; k0 += 64){
#pragma unroll
    for (int i = 0; i < 4; ++i){
      const int cidx = i*256 + w*64 + lane;
      const int r = cidx >> 3, p = cidx & 7;
      gld16(X + (size_t)(rb + r)*Kd + k0 + ((p ^ (r & 7)) << 3),
            &As[(i*256 + w*64)*8]);
    }
#pragma unroll
    for (int i = 0; i < 2; ++i){
      const int cidx = i*256 + w*64 + lane;
      const int r = cidx >> 3, p = cidx & 7;
      gld16(W + (size_t)(cb + r)*Kd + k0 + ((p ^ (r & 7)) << 3),
            &Bs[(i*256 + w*64)*8]);
    }
    __syncthreads();
#pragma unroll
    for (int kk = 0; kk < 2; ++kk){
      f16x8 a[4], b[2];
#pragma unroll
      for (int m = 0; m < 4; ++m)
        a[m] = ld8(&As[(wr*64 + m*16 + l16)*64 + (((kk*4 + l4) ^ key) << 3)]);
#pragma unroll
      for (int n = 0; n < 2; ++n)
        b[n] = ld8(&Bs[(wc*32 + n*16 + l16)*64 + (((kk*4 + l4) ^ key) << 3)]);
#pragma unroll
      for (int m = 0; m < 4; ++m)
#pragma unroll
        for (int n = 0; n < 2; ++n)
          acc[m][n] = MFMA16(a[m], b[n], acc[m][n], 0,0,0);
    }
    __syncthreads();
  }

#pragma unroll
  for (int n = 0; n < 2; ++n){
    const int col = cb + wc*32 + n*16 + l16;
    const float bv = bias[col];
#pragma unroll
    for (int m = 0; m < 4; ++m){
#pragma unroll
      for (int j = 0; j < 4; ++j){
        const int row = rb + wr*64 + m*16 + l4*4 + j;
        float v = acc[m][n][j] + bv;
        if (EPI == 1) v = 0.5f*v*(1.0f + erff(v*0.70710678118654752f));
        ((f16*)outp)[(size_t)row*ldo + col] = (f16)v;
      }
    }
  }
}

// =============== batched QKV projection, BK=64, XOR-swizzled ===============
// grid 384: gemm g in {q,k,v}, 128 blocks each. q folds 0.125*rtemp*log2e;
// v written pre-transposed vT[(b*H+h)*HD+dl][t].
__global__ __launch_bounds__(256,2) void qkv_tile(
    const f16* __restrict__ hV, const f16* __restrict__ kI, const f16* __restrict__ vI,
    const f16* __restrict__ Wq, const f16* __restrict__ Wk, const f16* __restrict__ Wv,
    const float* __restrict__ bq, const float* __restrict__ bk, const float* __restrict__ bv,
    const float* __restrict__ tsc,
    f16* __restrict__ qo, f16* __restrict__ ko, f16* __restrict__ vT)
{
  __shared__ f16 As[128*64];
  __shared__ f16 Bs[128*64];
  const int bid = blockIdx.x;
  const int swz = (bid & 7)*48 + (bid >> 3);
  const int g = swz >> 7;
  const int r = swz & 127;
  const int mb = r >> 2, nb = r & 3;
  const f16* X  = (g == 0) ? hV : ((g == 1) ? kI : vI);
  const f16* W  = (g == 0) ? Wq : ((g == 1) ? Wk : Wv);
  const float* bias = (g == 0) ? bq : ((g == 1) ? bk : bv);
  const int rb = mb*128, cb = nb*128;
  const int tid = threadIdx.x;
  const int w = tid >> 6, lane = tid & 63;
  const int l16 = lane & 15, l4 = lane >> 4;
  const int wr = w >> 1, wc = w & 1;
  const int key = l16 & 7;

  f32x4 acc[4][4];
#pragma unroll
  for (int m = 0; m < 4; ++m)
#pragma unroll
    for (int n = 0; n < 4; ++n) acc[m][n] = (f32x4){0.f,0.f,0.f,0.f};

  for (int k0 = 0; k0 < D_; k0 += 64){
#pragma unroll
    for (int i = 0; i < 4; ++i){
      const int cidx = i*256 + w*64 + lane;
      const int rr = cidx >> 3, p = cidx & 7;
      gld16(X + (size_t)(rb + rr)*D_ + k0 + ((p ^ (rr & 7)) << 3),
            &As[(i*256 + w*64)*8]);
      gld16(W + (size_t)(cb + rr)*D_ + k0 + ((p ^ (rr & 7)) << 3),
            &Bs[(i*256 + w*64)*8]);
    }
    __syncthreads();
#pragma unroll
    for (int kk = 0; kk < 2; ++kk){
      f16x8 a[4], b[4];
#pragma unroll
      for (int m = 0; m < 4; ++m)
        a[m] = ld8(&As[(wr*64 + m*16 + l16)*64 + (((kk*4 + l4) ^ key) << 3)]);
#pragma unroll
      for (int n = 0; n < 4; ++n)
        b[n] = ld8(&Bs[(wc*64 + n*16 + l16)*64 + (((kk*4 + l4) ^ key) << 3)]);
#pragma unroll
      for (int m = 0; m < 4; ++m)
#pragma unroll
        for (int n = 0; n < 4; ++n)
          acc[m][n] = MFMA16(a[m], b[n], acc[m][n], 0,0,0);
    }
    __syncthreads();
  }

  const float qs = exp2f(-2.0f*tanhf(tsc[0]))*LOG2E*0.125f;
  const float scale = (g == 0) ? qs : 1.0f;
  f16* out = (g == 0) ? qo : ko;
#pragma unroll
  for (int n = 0; n < 4; ++n){
    const int col = cb + wc*64 + n*16 + l16;
    const float bv = bias[col];
#pragma unroll
    for (int m = 0; m < 4; ++m){
#pragma unroll
      for (int j = 0; j < 4; ++j){
        const int row = rb + wr*64 + m*16 + l4*4 + j;
        const float v = (acc[m][n][j] + bv)*scale;
        if (g < 2){
          out[(size_t)row*D_ + col] = (f16)v;
        } else {
          const int b = row >> 10, t = row & (T_-1);
          const int h = col >> 6,  dl = col & (HD_-1);
          vT[(((size_t)b*H_ + h)*HD_ + dl)*T_ + t] = (f16)v;
        }
      }
    }
  }
}

// =============== fused attention (pipelined; pure vmcnt stream) =============
// 8 waves: qg=w>>2 owns q-group, ws=w&3 owns s-subrange / d-cols.
// K/V double-buffered; counted s_waitcnt vmcnt(2) + raw s_barrier. The main
// loops contain ONLY gld16 VMEM ops: bias fragments preloaded to registers
// (8 x f16x8), edge-gather values captured in registers, stored after loop.
__global__ __launch_bounds__(512,4) void attn_fused(
    const f16* __restrict__ q, const f16* __restrict__ k, const f16* __restrict__ vT,
    const f16* __restrict__ biasT, const int* __restrict__ eidx,
    f16* __restrict__ X2, float* __restrict__ gpart)
{
  __shared__ f16 Sb[16384];       // 32 KB: K/V chunk double buffer (2 x 8192)
  __shared__ f16 Pc[32*128];      // 8 KB: P chunk [32 q][128 s]
  const int bid = blockIdx.x;
  const int swz = (bid & 7)*128 + (bid >> 3);   // XCD-contiguous
  const int bh = swz >> 5, tb = swz & 31;
  const int bi = bh >> 3, h = bh & 7;
  const int t0 = tb*32;
  const int tid = threadIdx.x, w = tid >> 6, lane = tid & 63;
  const int qg = w >> 2, ws = w & 3;
  const int l16 = lane & 15, l4 = lane >> 4;
  const int key = l16 & 7;

  // ---- Q fragments ----
  const f16* qp = q + (size_t)(bi*T_ + t0 + qg*16 + l16)*D_ + h*HD_ + l4*8;
  const f16x8 q0 = ld8(qp), q1 = ld8(qp + 32);
  // ---- bias fragments: one f16x8 per chunk, preloaded ----
  const f16* bb = biasT + (size_t)(bi*32 + tb)*32768 + ws*1024 + qg*512 + l16*32 + l4*8;
  f16x8 bfr[8];
#pragma unroll
  for (int c = 0; c < 8; ++c) bfr[c] = ld8(bb + c*4096);
  // ---- gather tuples: each tid handles items of its own qg half ----
  const int tl = tid & 255;
  int ga_r, ga_kk, ga_id, gb_r = 0, gb_kk = 0, gb_id = -1;
  ga_r = tl/KN; ga_kk = tl - ga_r*KN;
  ga_id = eidx[((size_t)(bi*T_ + t0 + qg*16 + ga_r))*KN + ga_kk];
  if (tl + 256 < 16*KN){
    gb_r = (tl+256)/KN; gb_kk = (tl+256) - gb_r*KN;
    gb_id = eidx[((size_t)(bi*T_ + t0 + qg*16 + gb_r))*KN + gb_kk];
  }

  const f16* kg = k + (size_t)(bi*T_)*D_ + h*HD_;
  const f16* vg = vT + (size_t)bh*HD_*T_;

  auto stageK = [&](int c, int slot){
#pragma unroll
    for (int i = 0; i < 2; ++i){
      const int cidx = i*512 + w*64 + lane;
      const int r = cidx >> 3, p = cidx & 7;
      gld16(kg + (size_t)(c*128 + r)*D_ + ((p ^ (r & 7)) << 3),
            &Sb[slot*8192 + (i*512 + w*64)*8]);
    }
  };
  auto stageV = [&](int sc, int slot){
#pragma unroll
    for (int i = 0; i < 2; ++i){
      const int cidx = i*512 + w*64 + lane;
      const int r = cidx >> 4, p = cidx & 15;
      gld16(vg + (size_t)r*T_ + sc*128 + ((p ^ (r & 7)) << 3),
            &Sb[slot*8192 + (i*512 + w*64)*8]);
    }
  };

  // ---- QK^T: 8 chunks of 128 s, ping-pong + counted vmcnt ----
  f32x4 acc[16];
  stageK(0, 0);
#pragma unroll
  for (int c = 0; c < 8; ++c){
    if (c < 7) stageK(c+1, (c+1)&1);
    if (c < 7) asm volatile("s_waitcnt vmcnt(2)" ::: "memory");
    else       asm volatile("s_waitcnt vmcnt(0)" ::: "memory");
    __builtin_amdgcn_sched_barrier(0);
    __builtin_amdgcn_s_barrier();
    __builtin_amdgcn_sched_barrier(0);
    const int base = (c&1)*8192;
#pragma unroll
    for (int step = 0; step < 2; ++step){
      const int rr = ws*32 + step*16 + l16;
      f32x4 a = {0.f,0.f,0.f,0.f};
      a = MFMA16(ld8(&Sb[base + rr*64 + ((l4 ^ key) << 3)]),       q0, a, 0,0,0);
      a = MFMA16(ld8(&Sb[base + rr*64 + (((4 + l4) ^ key) << 3)]), q1, a, 0,0,0);
#pragma unroll
      for (int j = 0; j < 4; ++j) a[j] += (float)bfr[c][step*4 + j];
      acc[c*2 + step] = a;
    }
    __builtin_amdgcn_s_barrier();   // readers of slot (c&1) done
  }

  // ---- softmax (stats overlay on idle Sb; sums redistributed via shfl) ----
  float* redf = (float*)Sb;         // [0..127]=max, [128..255]=sum
  float m = -3.4e38f;
#pragma unroll
  for (int c = 0; c < 16; ++c)
#pragma unroll
    for (int j = 0; j < 4; ++j) m = fmaxf(m, acc[c][j]);
  m = fmaxf(m, __shfl_xor(m, 16));
  m = fmaxf(m, __shfl_xor(m, 32));
  if (lane < 16) redf[(qg*4 + ws)*16 + lane] = m;
  __syncthreads();
  m = fmaxf(fmaxf(redf[(qg*4+0)*16 + l16], redf[(qg*4+1)*16 + l16]),
            fmaxf(redf[(qg*4+2)*16 + l16], redf[(qg*4+3)*16 + l16]));
  float l = 0.f;
#pragma unroll
  for (int c = 0; c < 16; ++c)
#pragma unroll
    for (int j = 0; j < 4; ++j){
      const float e = exp2f(acc[c][j] - m);
      l += e;
      acc[c][j] = e;                // acc now holds unnormalized P
    }
  l += __shfl_xor(l, 16);
  l += __shfl_xor(l, 32);
  if (lane < 16) redf[128 + (qg*4 + ws)*16 + lane] = l;
  __syncthreads();
  const float lrq = redf[128 + (qg*4+0)*16 + l16] + redf[128 + (qg*4+1)*16 + l16]
                  + redf[128 + (qg*4+2)*16 + l16] + redf[128 + (qg*4+3)*16 + l16];
  __syncthreads();                  // all lrq reads done before V staging clobbers
  const float lr_a = __shfl(lrq, ga_r);
  const float lr_b = __shfl(lrq, gb_r);

  // ---- PV: 8 chunks, V ping-pong + counted vmcnt; gather -> registers ----
  f32x4 oo0 = {0.f,0.f,0.f,0.f}, oo1 = oo0, oo2 = oo0, oo3 = oo0;
  float pva = 0.f, pvb = 0.f;
  stageV(0, 0);
#pragma unroll
  for (int sc = 0; sc < 8; ++sc){
    // write own P slice for chunk sc (Pc free: prior readers barrier'd)
#pragma unroll
    for (int step = 0; step < 2; ++step){
      const int slb = ws*32 + step*16 + l4*4;
      f16x4 pp;
#pragma unroll
      for (int j = 0; j < 4; ++j) pp[j] = (f16)acc[sc*2 + step][j];
      *reinterpret_cast<f16x4*>(
          &Pc[(qg*16 + l16)*128 + (((slb >> 3) ^ key) << 3) + (slb & 7)]) = pp;
    }
    if (sc < 7) stageV(sc+1, (sc+1)&1);
    if (sc < 7) asm volatile("s_waitcnt vmcnt(2) lgkmcnt(0)" ::: "memory");
    else        asm volatile("s_waitcnt vmcnt(0) lgkmcnt(0)" ::: "memory");
    __builtin_amdgcn_sched_barrier(0);
    __builtin_amdgcn_s_barrier();
    __builtin_amdgcn_sched_barrier(0);
    const int base = (sc&1)*8192;
    const int vrow = (ws*16 + l16)*128;
#pragma unroll
    for (int grp = 0; grp < 4; ++grp){
      const int ch = (grp*4 + l4) ^ key;
      const f16x8 pa = ld8(&Pc[(qg*16 + l16)*128 + (ch << 3)]);
      const f16x8 vb = ld8(&Sb[base + vrow + (ch << 3)]);
      if (grp == 0)      oo0 = MFMA16(pa, vb, oo0, 0,0,0);
      else if (grp == 1) oo1 = MFMA16(pa, vb, oo1, 0,0,0);
      else if (grp == 2) oo2 = MFMA16(pa, vb, oo2, 0,0,0);
      else               oo3 = MFMA16(pa, vb, oo3, 0,0,0);
    }
    // edge gather capture (no VMEM stores inside the loop)
    if ((ga_id >> 7) == sc){
      const int r = qg*16 + ga_r;
      const int sl = ga_id & 127;
      pva = (float)Pc[r*128 + ((((sl >> 3) ^ (r & 7)) << 3) | (sl & 7))];
    }
    if (gb_id >= 0 && (gb_id >> 7) == sc){
      const int r = qg*16 + gb_r;
      const int sl = gb_id & 127;
      pvb = (float)Pc[r*128 + ((((sl >> 3) ^ (r & 7)) << 3) | (sl & 7))];
    }
    __builtin_amdgcn_s_barrier();   // readers of Pc + V slot (sc&1) done
  }
  const f32x4 o = (oo0 + oo1) + (oo2 + oo3);

  // ---- deferred gather stores ----
  gpart[((size_t)bh*T_ + t0 + qg*16 + ga_r)*KN + ga_kk] = pva/lr_a*0.125f;
  if (gb_id >= 0)
    gpart[((size_t)bh*T_ + t0 + qg*16 + gb_r)*KN + gb_kk] = pvb/lr_b*0.125f;

#pragma unroll
  for (int j = 0; j < 4; ++j){
    const float lr = __shfl(lrq, l4*4 + j);
    const int t = t0 + qg*16 + l4*4 + j;
    X2[((size_t)(bi*T_ + t))*640 + h*HD_ + ws*16 + l16] = (f16)(o[j]/lr);
  }
}

// ---------------- edge: weighted neighbor-embedding mean -------------------
// g[b,t,kk] = sum_h gpart[(b*H+h), t, kk]
__global__ __launch_bounds__(128) void edge_kernel(
    const float* __restrict__ gpart, const float* __restrict__ E, f16* __restrict__ X2)
{
  __shared__ float gl[KN];
  __shared__ float ginv;
  const int bt = blockIdx.x;          // b*T + t
  const int bi = bt >> 10, tt = bt & 1023;
  const int t = threadIdx.x;
  if (t < KN){
    float s = 0.f;
#pragma unroll
    for (int hh = 0; hh < H_; ++hh)
      s += gpart[((size_t)(bi*H_ + hh)*T_ + tt)*KN + t];
    gl[t] = s;
  }
  __syncthreads();
  if (t == 0){
    float s = 0.f;
#pragma unroll
    for (int i = 0; i < KN; ++i) s += gl[i];
    ginv = 1.0f/(s + 1e-6f);
  }
  __syncthreads();
  float acc = 0.f;
  const float* Ep = E + (size_t)bt*KN*ED_ + t;
#pragma unroll 5
  for (int kk = 0; kk < KN; ++kk) acc += gl[kk]*Ep[(size_t)kk*ED_];
  X2[(size_t)bt*640 + 512 + t] = (f16)(acc*ginv);
}

// ---------------- LayerNorm helpers ----------------------------------------
__device__ __forceinline__ float block_sum(float v, float* sbuf){
  for (int o = 32; o; o >>= 1) v += __shfl_down(v, o);
  __syncthreads();
  if ((threadIdx.x & 63) == 0) sbuf[threadIdx.x >> 6] = v;
  __syncthreads();
  return sbuf[0]+sbuf[1]+sbuf[2]+sbuf[3];
}

__global__ __launch_bounds__(256) void ln1_kernel(
    const float* __restrict__ hV, const f16* __restrict__ hraw,
    const float* __restrict__ gn, const float* __restrict__ bn,
    f16* __restrict__ hh)
{
  __shared__ float sbuf[4];
  const int r = blockIdx.x, t = threadIdx.x;
  const size_t base = (size_t)r*D_;
  float x0 = hV[base+t]     + (float)hraw[base+t];
  float x1 = hV[base+t+256] + (float)hraw[base+t+256];
  float s = block_sum(x0+x1, sbuf);
  const float mean = s*(1.f/512.f);
  float d0 = x0-mean, d1 = x1-mean;
  float vs = block_sum(d0*d0+d1*d1, sbuf);
  const float rstd = rsqrtf(vs*(1.f/512.f) + 1e-5f);
  hh[base+t]     = (f16)(d0*rstd*gn[t]     + bn[t]);
  hh[base+t+256] = (f16)(d1*rstd*gn[t+256] + bn[t+256]);
}

__global__ __launch_bounds__(256) void final_kernel(
    const f16* __restrict__ hh, const f16* __restrict__ ffr,
    const float* __restrict__ gf, const float* __restrict__ bfv,
    const float* __restrict__ g2, const float* __restrict__ b2,
    float* __restrict__ out)
{
  __shared__ float sbuf[4];
  const int r = blockIdx.x, t = threadIdx.x;
  const size_t base = (size_t)r*D_;
  const float h0 = (float)hh[base+t], h1 = (float)hh[base+t+256];
  float x0 = h0 + (float)ffr[base+t], x1 = h1 + (float)ffr[base+t+256];
  float s = block_sum(x0+x1, sbuf);
  float mean = s*(1.f/512.f);
  float d0 = x0-mean, d1 = x1-mean;
  float vs = block_sum(d0*d0+d1*d1, sbuf);
  float rstd = rsqrtf(vs*(1.f/512.f) + 1e-6f);
  const float dh0 = d0*rstd*gf[t]     + bfv[t];
  const float dh1 = d1*rstd*gf[t+256] + bfv[t+256];
  const float y0 = h0 + dh0, y1 = h1 + dh1;
  s = block_sum(y0+y1, sbuf);
  mean = s*(1.f/512.f);
  d0 = y0-mean; d1 = y1-mean;
  vs = block_sum(d0*d0+d1*d1, sbuf);
  rstd = rsqrtf(vs*(1.f/512.f) + 1e-5f);
  out[base+t]     = d0*rstd*g2[t]     + b2[t];
  out[base+t+256] = d1*rstd*g2[t+256] + b2[t+256];
}

// ---------------------------------------------------------------------------
extern "C" void kernel_launch(void* const* d_in, const int* in_sizes, int n_in,
                              void* d_out, int out_size, void* d_ws, size_t ws_size,
                              hipStream_t stream)
{
  (void)in_sizes; (void)n_in; (void)out_size;
  const float* h_V  = (const float*)d_in[0];
  const float* kin  = (const float*)d_in[1];
  const float* vin  = (const float*)d_in[2];
  const float* E    = (const float*)d_in[3];
  const float* bias = (const float*)d_in[4];
  const float* Wq   = (const float*)d_in[5];
  const float* bq   = (const float*)d_in[6];
  const float* Wk   = (const float*)d_in[7];
  const float* bk   = (const float*)d_in[8];
  const float* Wv   = (const float*)d_in[9];
  const float* bv   = (const float*)d_in[10];
  const float* Wo   = (const float*)d_in[11];
  const float* bo   = (const float*)d_in[12];
  const float* tsc  = (const float*)d_in[13];
  const float* gn   = (const float*)d_in[14];
  const float* bn   = (const float*)d_in[15];
  const float* w1   = (const float*)d_in[16];
  const float* bw1  = (const float*)d_in[17];
  const float* w2   = (const float*)d_in[18];
  const float* bw2  = (const float*)d_in[19];
  const float* gf   = (const float*)d_in[20];
  const float* bfv  = (const float*)d_in[21];
  const float* g2   = (const float*)d_in[22];
  const float* b2   = (const float*)d_in[23];
  const int*   Eidx = (const int*)d_in[24];
  const int*   mask = (const int*)d_in[25];
  float* out = (float*)d_out;

  char* wsb = (char*)d_ws;
  size_t off = 0;
  auto alloc = [&](size_t bytes) -> void* {
    void* pp = wsb + off; off += (bytes + 255) & ~(size_t)255; return pp;
  };
  f16* hVb  = (f16*)alloc((size_t)M_*D_*2);
  f16* kbI  = (f16*)alloc((size_t)M_*D_*2);
  f16* vbI  = (f16*)alloc((size_t)M_*D_*2);
  f16* Wqb  = (f16*)alloc((size_t)D_*D_*2);
  f16* Wkb  = (f16*)alloc((size_t)D_*D_*2);
  f16* Wvb  = (f16*)alloc((size_t)D_*D_*2);
  f16* Wob  = (f16*)alloc((size_t)D_*(D_+ED_)*2);
  f16* w1b  = (f16*)alloc((size_t)DFF_*D_*2);
  f16* w2b  = (f16*)alloc((size_t)D_*DFF_*2);
  f16* qb   = (f16*)alloc((size_t)M_*D_*2);
  f16* kb   = (f16*)alloc((size_t)M_*D_*2);
  f16* vT   = (f16*)alloc((size_t)M_*D_*2);
  f16* biasT= (f16*)alloc((size_t)B_*T_*T_*2);
  f16* X2   = (f16*)alloc((size_t)M_*640*2);
  float* gpart = (float*)alloc((size_t)BH_*T_*KN*4);
  f16* hraw = (f16*)alloc((size_t)M_*D_*2);   // reused as ffraw (f16)
  f16* hh   = (f16*)alloc((size_t)M_*D_*2);
  f16* ff1  = (f16*)alloc((size_t)M_*DFF_*2);
  if (ws_size < off) return;  // scratch insufficient -> loud validation failure
  f16* ffraw = hraw;

  // 1) fused prep: 9x fp32->f16 convert + fragment-tiled biasT (one launch)
  {
    CvtJobs J;
    const float* srcs[9] = {h_V, kin, vin, Wq, Wk, Wv, Wo, w1, w2};
    f16* dsts[9] = {hVb, kbI, vbI, Wqb, Wkb, Wvb, Wob, w1b, w2b};
    const int n4s[9] = {M_*D_/4, M_*D_/4, M_*D_/4, D_*D_/4, D_*D_/4, D_*D_/4,
                        D_*(D_+ED_)/4, DFF_*D_/4, D_*DFF_/4};
    int cum = 0;
    for (int i = 0; i < 9; ++i){
      J.s[i] = srcs[i]; J.d[i] = dsts[i]; J.start[i] = cum;
      cum += n4s[i]/256;
    }
    J.start[9] = cum;
    prep_kernel<<<cum + 2048,256,0,stream>>>(J, cum, bias, mask, tsc, biasT);
  }

  // 2) batched q/k/v projections, BK=64 (q pre-scaled; v -> vT)
  qkv_tile<<<384,256,0,stream>>>(hVb, kbI, vbI, Wqb, Wkb, Wvb, bq, bk, bv, tsc, qb, kb, vT);

  // 3) fused attention (pipelined, pure vmcnt stream), QBLK=32, 512 thr
  attn_fused<<<1024,512,0,stream>>>(qb, kb, vT, biasT, Eidx, X2, gpart);

  // 4) edge embedding (sums 8 per-head partials)
  edge_kernel<<<M_,128,0,stream>>>(gpart, E, X2);

  // 5) out-proj (f16 raw out) + residual LN
  gemm_n64<2><<<256,256,0,stream>>>(X2, Wob, bo, hraw, D_+ED_, D_, 8);
  ln1_kernel<<<M_,256,0,stream>>>(h_V, hraw, gn, bn, hh);

  // 6) FFN: FF1 gelu f16, FF2 raw f16
  gemm_tile<1><<<512,256,0,stream>>>(hh, w1b, bw1, ff1, D_, DFF_, 16);
  gemm_n64<2><<<256,256,0,stream>>>(ff1, w2b, bw2, ffraw, DFF_, D_, 8);

  // 7) final double-LN (f16 inputs)
  final_kernel<<<M_,256,0,stream>>>(hh, ffraw, gf, bfv, g2, b2, out);
}